// Round 11
// baseline (985.634 us; speedup 1.0000x reference)
//
#include <hip/hip_runtime.h>
#include <math.h>

#define NN 50000
#define NE 400000
#define NG 512
#define EPS 1e-5f
#define NSLOT 256  // stats replica slots (atomic contention spreading)

typedef unsigned int u32;
typedef unsigned short u16;

typedef __attribute__((ext_vector_type(8))) short s16x8;  // 8 bf16 (4 VGPRs)
typedef __attribute__((ext_vector_type(4))) float f32x4;

__device__ __forceinline__ float b2f(u16 h) { return __uint_as_float(((u32)h) << 16); }
__device__ __forceinline__ u16 f2b(float f) {
    u32 x = __float_as_uint(f);
    u32 r = x + 0x7fffu + ((x >> 16) & 1u);
    return (u16)(r >> 16);
}
struct alignas(16) U16x8 { u16 s[8]; };
struct alignas(8) U16x4 { u16 s[4]; };
struct alignas(4) U16x2 { u16 s[2]; };

__device__ __forceinline__ void f4add(float4& a, const float4 b) {
    a.x += b.x; a.y += b.y; a.z += b.z; a.w += b.w;
}

// ---------------- setup: fold rotation matrices into ee_W1 (fp32) ----------------
__global__ void setup_kernel(const float* __restrict__ ang_rot, const float* __restrict__ ang_ref,
                             const float* __restrict__ W1, float* __restrict__ RWrot,
                             float* __restrict__ RWref) {
    int c = threadIdx.x;  // 64
    for (int which = 0; which < 2; ++which) {
        const float* a = which ? ang_ref : ang_rot;
        float t = a[0], p = a[1], q = a[2];
        float ct = cosf(t), st = sinf(t);
        float cp = cosf(p), sp = sinf(p);
        float cq = cosf(q), sq = sinf(q);
        float Rt[3][3] = {{ct, -st, 0.f}, {st, ct, 0.f}, {0.f, 0.f, 1.f}};
        float Rp[3][3] = {{cp, 0.f, -sp}, {0.f, 1.f, 0.f}, {sp, 0.f, cp}};
        float Rq[3][3] = {{1.f, 0.f, 0.f}, {0.f, cq, -sq}, {0.f, sq, cq}};
        float Rtp[3][3], R[3][3];
        for (int i = 0; i < 3; ++i)
            for (int j = 0; j < 3; ++j) {
                float s = 0.f;
                for (int k = 0; k < 3; ++k) s += Rt[i][k] * Rp[k][j];
                Rtp[i][j] = s;
            }
        for (int i = 0; i < 3; ++i)
            for (int j = 0; j < 3; ++j) {
                float s = 0.f;
                for (int k = 0; k < 3; ++k) s += Rtp[i][k] * Rq[k][j];
                R[i][j] = s;
            }
        float sgn = which ? -1.f : 1.f;  // R_ref = -rotmat(angles_ref)
        float* RW = which ? RWref : RWrot;
        if (c < 64) {
            for (int j = 0; j < 3; ++j) {
                float s = 0.f;
                for (int m = 0; m < 3; ++m) s += sgn * R[j][m] * W1[m * 64 + c];
                RW[j * 64 + c] = s;  // RW = R @ W1  (3 x 64)
            }
        }
    }
}

// ---------------- batched weight transpose: W [K][C] fp32 -> WT [C][K] bf16 ----------------
#define NWT 17
struct WtJobs {
    const float* W[NWT];
    u16* WT[NWT];
    int K[NWT];
    int C[NWT];
};
__global__ __launch_bounds__(256) void wt_all_kernel(WtJobs jobs) {
    int job = blockIdx.x >> 5;
    int idx = ((blockIdx.x & 31) << 8) + threadIdx.x;
    int K = jobs.K[job], C = jobs.C[job];
    if (idx >= K * C) return;
    int k = idx / C, c = idx - k * C;
    jobs.WT[job][c * K + k] = f2b(jobs.W[job][idx]);
}

// ---------------- CSR build: degree hist -> 3-phase scan -> fill ----------------
__global__ __launch_bounds__(256) void hist_kernel(const int* __restrict__ dst, int E,
                                                   int* __restrict__ deg) {
    int e = blockIdx.x * 256 + threadIdx.x;
    if (e < E) atomicAdd(&deg[dst[e]], 1);
}

__global__ __launch_bounds__(256) void scan_part_kernel(const int* __restrict__ deg,
                                                        int* __restrict__ bsum, int n) {
    int i = blockIdx.x * 256 + threadIdx.x;
    int v = (i < n) ? deg[i] : 0;
#pragma unroll
    for (int off = 1; off < 64; off <<= 1) v += __shfl_xor(v, off, 64);
    __shared__ int ws[4];
    if ((threadIdx.x & 63) == 0) ws[threadIdx.x >> 6] = v;
    __syncthreads();
    if (threadIdx.x == 0) bsum[blockIdx.x] = ws[0] + ws[1] + ws[2] + ws[3];
}

__global__ __launch_bounds__(256) void scan_top_kernel(int* __restrict__ bsum, int nb,
                                                       int* __restrict__ rowptr, int n,
                                                       int total) {
    __shared__ int s[256];
    int tid = threadIdx.x;
    s[tid] = (tid < nb) ? bsum[tid] : 0;
    __syncthreads();
    for (int off = 1; off < 256; off <<= 1) {
        int v = (tid >= off) ? s[tid - off] : 0;
        __syncthreads();
        s[tid] += v;
        __syncthreads();
    }
    if (tid < nb) bsum[tid] = (tid == 0) ? 0 : s[tid - 1];
    if (tid == 0) rowptr[n] = total;
}

__global__ __launch_bounds__(256) void scan_fill_kernel(const int* __restrict__ deg,
                                                        const int* __restrict__ bsum,
                                                        int* __restrict__ rowptr,
                                                        int* __restrict__ curs, int n) {
    __shared__ int s[256];
    int tid = threadIdx.x;
    int i = blockIdx.x * 256 + tid;
    int v = (i < n) ? deg[i] : 0;
    s[tid] = v;
    __syncthreads();
    for (int off = 1; off < 256; off <<= 1) {
        int t = (tid >= off) ? s[tid - off] : 0;
        __syncthreads();
        s[tid] += t;
        __syncthreads();
    }
    if (i < n) {
        int excl = s[tid] - v + bsum[blockIdx.x];
        rowptr[i] = excl;
        curs[i] = excl;
    }
}

// fill: scatter edges into CSR slots; emit permuted src/dst/efeats (CSR order everywhere after)
__global__ __launch_bounds__(256) void fill_kernel(const int* __restrict__ src,
                                                   const int* __restrict__ dst,
                                                   const float* __restrict__ ef, int E,
                                                   int* __restrict__ curs,
                                                   int* __restrict__ esrc,
                                                   int* __restrict__ dsts,
                                                   float* __restrict__ efp) {
    int e = blockIdx.x * 256 + threadIdx.x;
    if (e >= E) return;
    int d = dst[e];
    int pos = atomicAdd(&curs[d], 1);
    esrc[pos] = src[e];
    dsts[pos] = d;
    efp[(long)pos * 3 + 0] = ef[(long)e * 3 + 0];
    efp[(long)pos * 3 + 1] = ef[(long)e * 3 + 1];
    efp[(long)pos * 3 + 2] = ef[(long)e * 3 + 2];
}

// ---------------- embedding gather: fp32 table -> bf16 out ----------------
__global__ __launch_bounds__(256) void gather_emb_kernel(const int* __restrict__ ntype,
                                                         const float* __restrict__ emb,
                                                         u16* __restrict__ out, int n) {
    long i = (long)blockIdx.x * 256 + threadIdx.x;  // over n*8
    long e = i >> 3;
    if (e >= n) return;
    int c0 = (int)(i & 7) * 8;
    int t = ntype[e];
    float4 a = *(const float4*)&emb[(long)t * 64 + c0];
    float4 b = *(const float4*)&emb[(long)t * 64 + c0 + 4];
    U16x8 o;
    o.s[0] = f2b(a.x); o.s[1] = f2b(a.y); o.s[2] = f2b(a.z); o.s[3] = f2b(a.w);
    o.s[4] = f2b(b.x); o.s[5] = f2b(b.y); o.s[6] = f2b(b.z); o.s[7] = f2b(b.w);
    *(U16x8*)&out[e * 64 + c0] = o;
}

// ---------------- efeats second moments: 9 scalars -> replica slots ----------------
__global__ __launch_bounds__(256) void efstats_kernel(const float* __restrict__ ef, int E,
                                                      float* __restrict__ raw) {
    int tid = threadIdx.x;
    float a[9];
#pragma unroll
    for (int j = 0; j < 9; ++j) a[j] = 0.f;
    for (long e = (long)blockIdx.x * 256 + tid; e < E; e += (long)gridDim.x * 256) {
        float f0 = ef[e * 3 + 0], f1 = ef[e * 3 + 1], f2 = ef[e * 3 + 2];
        a[0] += f0; a[1] += f1; a[2] += f2;
        a[3] += f0 * f0; a[4] += f1 * f1; a[5] += f2 * f2;
        a[6] += f0 * f1; a[7] += f0 * f2; a[8] += f1 * f2;
    }
#pragma unroll
    for (int off = 1; off < 64; off <<= 1)
#pragma unroll
        for (int j = 0; j < 9; ++j) a[j] += __shfl_xor(a[j], off, 64);
    __shared__ float sred[4][9];
    int wv = tid >> 6, ln = tid & 63;
    if (ln == 0)
#pragma unroll
        for (int j = 0; j < 9; ++j) sred[wv][j] = a[j];
    __syncthreads();
    if (tid < 9) {
        float v = sred[0][tid] + sred[1][tid] + sred[2][tid] + sred[3][tid];
        atomicAdd(&raw[(size_t)(blockIdx.x & (NSLOT - 1)) * 16 + tid], v);
    }
}

// ---------------- analytic T1 column stats for both branches ----------------
__global__ void ee_stats_kernel(const float* __restrict__ efraw, const float* __restrict__ RWrot,
                                const float* __restrict__ RWref, const float* __restrict__ b1,
                                float* __restrict__ S_rot, float* __restrict__ S_ref, int E) {
    __shared__ float m[9];
    int t = threadIdx.x;  // 128
    if (t < 9) {
        float s = 0.f;
        for (int r = 0; r < NSLOT; ++r) s += efraw[r * 16 + t];
        m[t] = s;
    }
    __syncthreads();
    int br = t >> 6, c = t & 63;
    const float* RW = br ? RWref : RWrot;
    float* S = br ? S_ref : S_rot;
    float w0 = RW[c], w1 = RW[64 + c], w2 = RW[128 + c];
    float bb = b1[c];
    float mw = m[0] * w0 + m[1] * w1 + m[2] * w2;
    float sum = mw + (float)E * bb;
    float quad = m[3] * w0 * w0 + m[4] * w1 * w1 + m[5] * w2 * w2 +
                 2.f * (m[6] * w0 * w1 + m[7] * w0 * w2 + m[8] * w1 * w2);
    float ss = quad + 2.f * bb * mw + (float)E * bb * bb;
    S[c] = sum;
    S[64 + c] = ss;
}

// ---------------- column stats (bf16 input) -> replicated raw accumulators ----------------
template <int COLS>
__global__ __launch_bounds__(256) void colstats_kernel(const u16* __restrict__ xv, int rows,
                                                       float* __restrict__ raw) {
    constexpr int TPR = COLS / 8;
    constexpr int RPB = 256 / TPR;
    __shared__ float4 sA[256], sB[256], sC[256], sD[256];
    int tid = threadIdx.x;
    int c8 = tid % TPR;
    int rl = tid / TPR;
    float s[8], q[8];
#pragma unroll
    for (int j = 0; j < 8; ++j) { s[j] = 0.f; q[j] = 0.f; }
    const long stride = (long)gridDim.x * RPB;
    for (long r = (long)blockIdx.x * RPB + rl; r < rows; r += stride) {
        U16x8 t = *(const U16x8*)&xv[r * COLS + c8 * 8];
#pragma unroll
        for (int j = 0; j < 8; ++j) {
            float v = b2f(t.s[j]);
            s[j] += v;
            q[j] += v * v;
        }
    }
    sA[tid] = make_float4(s[0], s[1], s[2], s[3]);
    sB[tid] = make_float4(s[4], s[5], s[6], s[7]);
    sC[tid] = make_float4(q[0], q[1], q[2], q[3]);
    sD[tid] = make_float4(q[4], q[5], q[6], q[7]);
    __syncthreads();
    for (int off = 128; off >= TPR; off >>= 1) {
        if (tid < off) {
            f4add(sA[tid], sA[tid + off]); f4add(sB[tid], sB[tid + off]);
            f4add(sC[tid], sC[tid + off]); f4add(sD[tid], sD[tid + off]);
        }
        __syncthreads();
    }
    if (tid < TPR) {
        float* slot = raw + (size_t)(blockIdx.x & (NSLOT - 1)) * 256;
        int c = tid * 8;
        float4 a = sA[tid], b = sB[tid], cq = sC[tid], d = sD[tid];
        atomicAdd(&slot[c + 0], a.x); atomicAdd(&slot[c + 1], a.y);
        atomicAdd(&slot[c + 2], a.z); atomicAdd(&slot[c + 3], a.w);
        atomicAdd(&slot[c + 4], b.x); atomicAdd(&slot[c + 5], b.y);
        atomicAdd(&slot[c + 6], b.z); atomicAdd(&slot[c + 7], b.w);
        atomicAdd(&slot[COLS + c + 0], cq.x); atomicAdd(&slot[COLS + c + 1], cq.y);
        atomicAdd(&slot[COLS + c + 2], cq.z); atomicAdd(&slot[COLS + c + 3], cq.w);
        atomicAdd(&slot[COLS + c + 4], d.x); atomicAdd(&slot[COLS + c + 5], d.y);
        atomicAdd(&slot[COLS + c + 6], d.z); atomicAdd(&slot[COLS + c + 7], d.w);
    }
}

// ---------------- reduce NSLOT replica slots -> final stats ----------------
__global__ __launch_bounds__(256) void finalize_stats_kernel(const float* __restrict__ raw,
                                                             float* __restrict__ stats, int n) {
    int i = threadIdx.x;
    if (i >= n) return;
    float s = 0.f;
    for (int r = 0; r < NSLOT; ++r) s += raw[r * 256 + i];
    stats[i] = s;
}

// ---------------- y = relu(bn(x)), bf16 (node-enc bn2) ----------------
__global__ __launch_bounds__(256) void bn_act_kernel(const u16* __restrict__ x,
                                                     u16* __restrict__ y, long rows, int cols,
                                                     const float* __restrict__ acc,
                                                     const float* __restrict__ g,
                                                     const float* __restrict__ b,
                                                     float inv_rows) {
    long i = (long)blockIdx.x * 256 + threadIdx.x;
    long total8 = rows * (long)cols / 8;
    if (i >= total8) return;
    long base = i * 8;
    int c0 = (int)(base % cols);
    U16x8 xv = *(const U16x8*)&x[base];
    U16x8 o;
#pragma unroll
    for (int j = 0; j < 8; ++j) {
        int c = c0 + j;
        float mu = acc[c] * inv_rows;
        float var = acc[cols + c] * inv_rows - mu * mu;
        float al = g[c] * rsqrtf(fmaxf(var, 0.f) + EPS);
        float be = b[c] - mu * al;
        o.s[j] = f2b(fmaxf(al * b2f(xv.s[j]) + be, 0.f));
    }
    *(U16x8*)&y[base] = o;
}

// ================= MFMA kernels =================
// Fragment layout (guide §3, m89/m91/m92 verified):
//   A: lane l holds A[row=l&15][k=(l>>4)*8+j]
//   B: lane l holds B[k=(l>>4)*8+j][col=l&15]  (8 contiguous bf16 from W^T row)
//   D: lane l reg r holds D[row=(l>>4)*4+r][col=l&15]
// Block = 4 waves = 64 rows. NE%64==0; NN%16==0 (tail waves skip).

// ---- generic: Y = preop(X) @ W (+bias)(+res), optional fused col-stats ----
template <int K, int COLS, bool XBF, bool RBF, bool OBF, bool SOUT>
__global__ __launch_bounds__(256) void mfma_mm_kernel(
    const void* __restrict__ Xv, const u16* __restrict__ WT, const float* __restrict__ bias,
    const void* __restrict__ resv, void* __restrict__ Yv, int rows, int preop,
    const float* __restrict__ stats, const float* __restrict__ g, const float* __restrict__ b,
    float inv_rows, const float* __restrict__ prelu, int prelu_idx, float* __restrict__ raw) {
    constexpr int NCT = COLS / 16;
    constexpr int NKK = K / 32;
    __shared__ float al[K], be[K];
    __shared__ float ssum[SOUT ? COLS : 1], ssq[SOUT ? COLS : 1];
    const int tid = threadIdx.x;
    if (preop) {
        for (int k = tid; k < K; k += 256) {
            float mu = stats[k] * inv_rows;
            float var = stats[K + k] * inv_rows - mu * mu;
            float a = g[k] * rsqrtf(fmaxf(var, 0.f) + EPS);
            al[k] = a;
            be[k] = b[k] - mu * a;
        }
    }
    if (SOUT) {
        for (int i = tid; i < COLS; i += 256) { ssum[i] = 0.f; ssq[i] = 0.f; }
    }
    __syncthreads();
    const int lane = tid & 63, wv = tid >> 6;
    const int q = lane >> 4, rr = lane & 15;
    const long r0 = ((long)blockIdx.x * 4 + wv) * 16;
    const bool act = r0 < rows;
    const float pa = (preop == 3) ? prelu[prelu_idx] : 0.f;
    s16x8 afr[NKK];
    if (act) {
#pragma unroll
        for (int kk = 0; kk < NKK; ++kk) {
            float v[8];
            if (XBF) {
                U16x8 t = *(const U16x8*)((const u16*)Xv + (r0 + rr) * K + kk * 32 + q * 8);
#pragma unroll
                for (int j = 0; j < 8; ++j) v[j] = b2f(t.s[j]);
            } else {
                const float* xp = (const float*)Xv + (r0 + rr) * K + kk * 32 + q * 8;
                float4 t0 = *(const float4*)xp;
                float4 t1 = *(const float4*)(xp + 4);
                v[0] = t0.x; v[1] = t0.y; v[2] = t0.z; v[3] = t0.w;
                v[4] = t1.x; v[5] = t1.y; v[6] = t1.z; v[7] = t1.w;
            }
            union { u16 u[8]; s16x8 s; } o;
#pragma unroll
            for (int j = 0; j < 8; ++j) {
                float xx = v[j];
                if (preop) {
                    int k = kk * 32 + q * 8 + j;
                    xx = al[k] * xx + be[k];
                    if (preop == 2) xx = fmaxf(xx, 0.f);
                    else if (preop == 3) xx = (xx >= 0.f) ? xx : pa * xx;
                }
                o.u[j] = f2b(xx);
            }
            afr[kk] = o.s;
        }
#pragma unroll
        for (int ct = 0; ct < NCT; ++ct) {
            f32x4 acc = (f32x4){0.f, 0.f, 0.f, 0.f};
#pragma unroll
            for (int kk = 0; kk < NKK; ++kk) {
                s16x8 bfr = *(const s16x8*)&WT[(size_t)(ct * 16 + rr) * K + kk * 32 + q * 8];
                acc = __builtin_amdgcn_mfma_f32_16x16x32_bf16(afr[kk], bfr, acc, 0, 0, 0);
            }
            int col = ct * 16 + rr;
            float bb = bias ? bias[col] : 0.f;
            float fs = 0.f, fq = 0.f;
#pragma unroll
            for (int r = 0; r < 4; ++r) {
                long orr = r0 + q * 4 + r;
                float vv = acc[r] + bb;
                if (resv) {
                    if (RBF) vv += b2f(((const u16*)resv)[orr * COLS + col]);
                    else vv += ((const float*)resv)[orr * COLS + col];
                }
                if (OBF) ((u16*)Yv)[orr * COLS + col] = f2b(vv);
                else ((float*)Yv)[orr * COLS + col] = vv;
                if (SOUT) { fs += vv; fq += vv * vv; }
            }
            if (SOUT) {
                fs += __shfl_xor(fs, 16, 64); fs += __shfl_xor(fs, 32, 64);
                fq += __shfl_xor(fq, 16, 64); fq += __shfl_xor(fq, 32, 64);
                if (q == 0) {
                    atomicAdd(&ssum[col], fs);
                    atomicAdd(&ssq[col], fq);
                }
            }
        }
    }
    if (SOUT) {
        __syncthreads();
        float* slot = raw + (size_t)(blockIdx.x & (NSLOT - 1)) * 256;
        for (int i = tid; i < COLS; i += 256) {
            atomicAdd(&slot[i], ssum[i]);
            atomicAdd(&slot[COLS + i], ssq[i]);
        }
    }
}

// ---- 3 matmuls sharing the A operand: Y0 = X@W0, Y1 = X@W1, Y2 = X@W2 + bias2 ----
template <int COLS, bool XBF>
__global__ __launch_bounds__(256) void mfma_mm3_kernel(
    const void* __restrict__ Xv, const u16* __restrict__ WT0, const u16* __restrict__ WT1,
    const u16* __restrict__ WT2, const float* __restrict__ bias2, u16* __restrict__ Y0,
    u16* __restrict__ Y1, u16* __restrict__ Y2, int rows) {
    constexpr int NCT = COLS / 16;
    const int tid = threadIdx.x;
    const int lane = tid & 63, wv = tid >> 6;
    const int q = lane >> 4, rr = lane & 15;
    const long r0 = ((long)blockIdx.x * 4 + wv) * 16;
    if (r0 >= rows) return;
    s16x8 afr[2];
#pragma unroll
    for (int kk = 0; kk < 2; ++kk) {
        if (XBF) {
            afr[kk] = *(const s16x8*)((const u16*)Xv + (r0 + rr) * 64 + kk * 32 + q * 8);
        } else {
            const float* xp = (const float*)Xv + (r0 + rr) * 64 + kk * 32 + q * 8;
            float4 t0 = *(const float4*)xp;
            float4 t1 = *(const float4*)(xp + 4);
            union { u16 u[8]; s16x8 s; } o;
            o.u[0] = f2b(t0.x); o.u[1] = f2b(t0.y); o.u[2] = f2b(t0.z); o.u[3] = f2b(t0.w);
            o.u[4] = f2b(t1.x); o.u[5] = f2b(t1.y); o.u[6] = f2b(t1.z); o.u[7] = f2b(t1.w);
            afr[kk] = o.s;
        }
    }
    const u16* wts[3] = {WT0, WT1, WT2};
    u16* ys[3] = {Y0, Y1, Y2};
#pragma unroll
    for (int m = 0; m < 3; ++m) {
#pragma unroll
        for (int ct = 0; ct < NCT; ++ct) {
            f32x4 acc = (f32x4){0.f, 0.f, 0.f, 0.f};
#pragma unroll
            for (int kk = 0; kk < 2; ++kk) {
                s16x8 bfr = *(const s16x8*)&wts[m][(size_t)(ct * 16 + rr) * 64 + kk * 32 + q * 8];
                acc = __builtin_amdgcn_mfma_f32_16x16x32_bf16(afr[kk], bfr, acc, 0, 0, 0);
            }
            int col = ct * 16 + rr;
            float bb = (m == 2) ? bias2[col] : 0.f;
#pragma unroll
            for (int r = 0; r < 4; ++r) {
                long orr = r0 + q * 4 + r;
                ys[m][orr * COLS + col] = f2b(acc[r] + bb);
            }
        }
    }
}

// ---- edge encoder, both branches, in-register from 3 floats/row ----
// STORE=false: emit T2 col-stats only (rawA/rawB). STORE=true: EH = relu(bn2a(T2a)) + relu(bn2b(T2b)).
template <bool STORE>
__global__ __launch_bounds__(256) void mfma_ee2_kernel(
    const float* __restrict__ efp, const float* __restrict__ RWrot,
    const float* __restrict__ RWref, const float* __restrict__ b1v, const u16* __restrict__ W2T,
    const float* __restrict__ b2, const float* __restrict__ S1r, const float* __restrict__ S1f,
    const float* __restrict__ S2r, const float* __restrict__ S2f, const float* __restrict__ g1,
    const float* __restrict__ bn1b, const float* __restrict__ g2, const float* __restrict__ bn2b,
    u16* __restrict__ EH, int E, float inv_rows, float* __restrict__ rawA,
    float* __restrict__ rawB) {
    constexpr int ESTR = 72;  // padded u16 stride for EH staging
    __shared__ float rws[2][192];
    __shared__ float al1[2][64], be1[2][64];
    __shared__ float al2[2][64], be2[2][64];
    __shared__ float ssum[2][64], ssq[2][64];
    __shared__ u16 ets[STORE ? 64 * ESTR : 1];
    const int tid = threadIdx.x;
    if (tid < 192) {
        rws[0][tid] = RWrot[tid];
        rws[1][tid] = RWref[tid];
    }
    if (tid < 128) {
        int br = tid >> 6, k = tid & 63;
        const float* S1 = br ? S1f : S1r;
        float mu = S1[k] * inv_rows;
        float var = S1[64 + k] * inv_rows - mu * mu;
        float a = g1[k] * rsqrtf(fmaxf(var, 0.f) + EPS);
        al1[br][k] = a;
        be1[br][k] = bn1b[k] - mu * a + a * b1v[k];  // fold b1
        if (STORE) {
            const float* S2 = br ? S2f : S2r;
            mu = S2[k] * inv_rows;
            var = S2[64 + k] * inv_rows - mu * mu;
            a = g2[k] * rsqrtf(fmaxf(var, 0.f) + EPS);
            al2[br][k] = a;
            be2[br][k] = bn2b[k] - mu * a + a * b2[k];  // fold b2
        } else {
            ssum[br][k] = 0.f;
            ssq[br][k] = 0.f;
        }
    }
    __syncthreads();
    const int lane = tid & 63, wv = tid >> 6;
    const int q = lane >> 4, rr = lane & 15;
    const long r0 = ((long)blockIdx.x * 4 + wv) * 16;
    const long ar = r0 + rr;
    float e0 = efp[ar * 3], e1 = efp[ar * 3 + 1], e2 = efp[ar * 3 + 2];
    float v0[4][4];  // branch-0 post-bn2 values (STORE path)
#pragma unroll
    for (int br = 0; br < 2; ++br) {
        s16x8 afr[2];
#pragma unroll
        for (int kk = 0; kk < 2; ++kk) {
            union { u16 u[8]; s16x8 v; } t;
#pragma unroll
            for (int j = 0; j < 8; ++j) {
                int k = kk * 32 + q * 8 + j;
                float tv = e0 * rws[br][k] + e1 * rws[br][64 + k] + e2 * rws[br][128 + k];
                t.u[j] = f2b(fmaxf(al1[br][k] * tv + be1[br][k], 0.f));
            }
            afr[kk] = t.v;
        }
#pragma unroll
        for (int ct = 0; ct < 4; ++ct) {
            f32x4 acc = (f32x4){0.f, 0.f, 0.f, 0.f};
#pragma unroll
            for (int kk = 0; kk < 2; ++kk) {
                s16x8 bfr = *(const s16x8*)&W2T[(size_t)(ct * 16 + rr) * 64 + kk * 32 + q * 8];
                acc = __builtin_amdgcn_mfma_f32_16x16x32_bf16(afr[kk], bfr, acc, 0, 0, 0);
            }
            int col = ct * 16 + rr;
            if (STORE) {
#pragma unroll
                for (int r = 0; r < 4; ++r) {
                    float v = fmaxf(al2[br][col] * acc[r] + be2[br][col], 0.f);
                    if (br == 0) {
                        v0[ct][r] = v;
                    } else {
                        ets[(wv * 16 + q * 4 + r) * ESTR + col] = f2b(v0[ct][r] + v);
                    }
                }
            } else {
                float bb = b2[col];
                float s = 0.f, qq = 0.f;
#pragma unroll
                for (int r = 0; r < 4; ++r) {
                    float v = acc[r] + bb;
                    s += v;
                    qq += v * v;
                }
                s += __shfl_xor(s, 16, 64); s += __shfl_xor(s, 32, 64);
                qq += __shfl_xor(qq, 16, 64); qq += __shfl_xor(qq, 32, 64);
                if (q == 0) {
                    atomicAdd(&ssum[br][col], s);
                    atomicAdd(&ssq[br][col], qq);
                }
            }
        }
    }
    __syncthreads();
    if (STORE) {
        const long rb = (long)blockIdx.x * 64;
        for (int i = tid; i < 64 * 8; i += 256) {
            int row = i >> 3, c8 = i & 7;
            U16x8 v = *(const U16x8*)&ets[row * ESTR + c8 * 8];
            *(U16x8*)&EH[(rb + row) * 64 + c8 * 8] = v;
        }
    } else {
        if (tid < 128) {
            int br = tid >> 6, k = tid & 63;
            float* slot = (br ? rawB : rawA) + (size_t)(blockIdx.x & (NSLOT - 1)) * 256;
            atomicAdd(&slot[k], ssum[br][k]);
            atomicAdd(&slot[64 + k], ssq[br][k]);
        }
    }
}

// ---- f = leaky(EH@Wfij + NI[src] + NJ[dst]); att scores (CSR order) ----
// Two-phase: MFMA -> LDS tile; then row-major coalesced gathers + epilogue.
template <int COLS, bool WRITE_F, bool SOUT>
__global__ __launch_bounds__(256) void mfma_egat_kernel(
    const u16* __restrict__ EH, const u16* __restrict__ WT, const u16* __restrict__ NI,
    const u16* __restrict__ NJ, const int* __restrict__ srcs, const int* __restrict__ dsts,
    const float* __restrict__ attn, u16* __restrict__ Fout, float* __restrict__ eatt, int E,
    float* __restrict__ raw) {
    constexpr int H = COLS / 64;
    constexpr int NCT = COLS / 16;
    constexpr int FSTR = COLS + 8;   // padded LDS row stride (u16)
    constexpr int CH = COLS / 8;     // 8-u16 chunks per row
    constexpr int RPG = 256 / CH;    // rows covered per group iteration
    __shared__ u16 fts[64 * FSTR];
    __shared__ float rowsum[64 * 2];
    __shared__ float ssum[SOUT ? COLS : 1];
    __shared__ float ssq[SOUT ? COLS : 1];
    const int tid = threadIdx.x;
    if (tid < 128) rowsum[tid] = 0.f;
    if (SOUT) {
        for (int i = tid; i < COLS; i += 256) { ssum[i] = 0.f; ssq[i] = 0.f; }
    }
    const int lane = tid & 63, wv = tid >> 6;
    const int q = lane >> 4, rr = lane & 15;
    const long r0 = ((long)blockIdx.x * 4 + wv) * 16;
    // ---- phase 1: MFMA, raw acc -> LDS ----
    s16x8 afr[2];
#pragma unroll
    for (int kk = 0; kk < 2; ++kk)
        afr[kk] = *(const s16x8*)&EH[(r0 + rr) * 64 + kk * 32 + q * 8];
#pragma unroll
    for (int ct = 0; ct < NCT; ++ct) {
        f32x4 acc = (f32x4){0.f, 0.f, 0.f, 0.f};
#pragma unroll
        for (int kk = 0; kk < 2; ++kk) {
            s16x8 bfr = *(const s16x8*)&WT[(size_t)(ct * 16 + rr) * 64 + kk * 32 + q * 8];
            acc = __builtin_amdgcn_mfma_f32_16x16x32_bf16(afr[kk], bfr, acc, 0, 0, 0);
        }
        int col = ct * 16 + rr;
#pragma unroll
        for (int r = 0; r < 4; ++r)
            fts[(wv * 16 + q * 4 + r) * FSTR + col] = f2b(acc[r]);
    }
    __syncthreads();
    // ---- phase 2: row-major coalesced gathers, leaky, attn dot, F store, stats ----
    const long rb = (long)blockIdx.x * 64;
    const int c8 = tid % CH;
    const int rloc = tid / CH;
    float av[8];
    {
        float4 a0 = *(const float4*)&attn[c8 * 8];
        float4 a1 = *(const float4*)&attn[c8 * 8 + 4];
        av[0] = a0.x; av[1] = a0.y; av[2] = a0.z; av[3] = a0.w;
        av[4] = a1.x; av[5] = a1.y; av[6] = a1.z; av[7] = a1.w;
    }
    const int h = (H == 2) ? (c8 >> 3) : 0;
    float fs[8], fq[8];
#pragma unroll
    for (int j = 0; j < 8; ++j) { fs[j] = 0.f; fq[j] = 0.f; }
#pragma unroll
    for (int g = 0; g < 64 / RPG; ++g) {
        int row = g * RPG + rloc;
        int s = srcs[rb + row];
        int d = dsts[rb + row];
        U16x8 ni = *(const U16x8*)&NI[(size_t)s * COLS + c8 * 8];
        U16x8 nj = *(const U16x8*)&NJ[(size_t)d * COLS + c8 * 8];
        U16x8 ft = *(const U16x8*)&fts[row * FSTR + c8 * 8];
        float part = 0.f;
        U16x8 fo;
#pragma unroll
        for (int j = 0; j < 8; ++j) {
            float f = b2f(ft.s[j]) + b2f(ni.s[j]) + b2f(nj.s[j]);
            f = (f >= 0.f) ? f : 0.01f * f;
            fo.s[j] = f2b(f);
            part += f * av[j];
            if (SOUT) { fs[j] += f; fq[j] += f * f; }
        }
        if (WRITE_F) *(U16x8*)&Fout[(rb + row) * COLS + c8 * 8] = fo;
        atomicAdd(&rowsum[row * 2 + h], part);
    }
    if (SOUT) {
#pragma unroll
        for (int j = 0; j < 8; ++j) {
            atomicAdd(&ssum[c8 * 8 + j], fs[j]);
            atomicAdd(&ssq[c8 * 8 + j], fq[j]);
        }
    }
    __syncthreads();
    if (tid < 64) {
        long pos = rb + tid;
        if (H == 2) {
            eatt[pos * 2 + 0] = rowsum[tid * 2 + 0];
            eatt[pos * 2 + 1] = rowsum[tid * 2 + 1];
        } else {
            eatt[pos] = rowsum[tid * 2 + 0];
        }
    }
    if (SOUT) {
        float* slot = raw + (size_t)(blockIdx.x & (NSLOT - 1)) * 256;
        for (int i = tid; i < COLS; i += 256) {
            atomicAdd(&slot[i], ssum[i]);
            atomicAdd(&slot[COLS + i], ssq[i]);
        }
    }
}

// ---- EH = bn(F128)@Wpe + bpe + EH (K=128, streaming; coalesced residual epilogue) ----
__global__ __launch_bounds__(256) void mfma_pe_kernel(
    const u16* __restrict__ X, const u16* __restrict__ WT, const float* __restrict__ bias,
    u16* __restrict__ EHio, int E, const float* __restrict__ stats, const float* __restrict__ g,
    const float* __restrict__ b, float inv_rows) {
    constexpr int ESTR = 72;
    __shared__ float al[128], be[128];
    __shared__ u16 ets[64 * ESTR];
    const int tid = threadIdx.x;
    if (tid < 128) {
        float mu = stats[tid] * inv_rows;
        float var = stats[128 + tid] * inv_rows - mu * mu;
        float a = g[tid] * rsqrtf(fmaxf(var, 0.f) + EPS);
        al[tid] = a;
        be[tid] = b[tid] - mu * a;
    }
    __syncthreads();
    const int lane = tid & 63, wv = tid >> 6;
    const int q = lane >> 4, rr = lane & 15;
    const long r0 = ((long)blockIdx.x * 4 + wv) * 16;
    s16x8 afr[4];
#pragma unroll
    for (int kk = 0; kk < 4; ++kk) {
        U16x8 t = *(const U16x8*)&X[(r0 + rr) * 128 + kk * 32 + q * 8];
        union { u16 u[8]; s16x8 v; } o;
#pragma unroll
        for (int j = 0; j < 8; ++j) {
            int k = kk * 32 + q * 8 + j;
            o.u[j] = f2b(al[k] * b2f(t.s[j]) + be[k]);
        }
        afr[kk] = o.v;
    }
#pragma unroll
    for (int ct = 0; ct < 4; ++ct) {
        f32x4 acc = (f32x4){0.f, 0.f, 0.f, 0.f};
#pragma unroll
        for (int kk = 0; kk < 4; ++kk) {
            s16x8 bfr = *(const s16x8*)&WT[(size_t)(ct * 16 + rr) * 128 + kk * 32 + q * 8];
            acc = __builtin_amdgcn_mfma_f32_16x16x32_bf16(afr[kk], bfr, acc, 0, 0, 0);
        }
        int col = ct * 16 + rr;
        float bb = bias[col];
#pragma unroll
        for (int r = 0; r < 4; ++r)
            ets[(wv * 16 + q * 4 + r) * ESTR + col] = f2b(acc[r] + bb);
    }
    __syncthreads();
    const long rb = (long)blockIdx.x * 64;
#pragma unroll
    for (int g = 0; g < 2; ++g) {
        int i = g * 256 + tid;
        int row = i >> 3, c8 = i & 7;
        U16x8 st = *(const U16x8*)&ets[row * ESTR + c8 * 8];
        U16x8 old = *(const U16x8*)&EHio[(rb + row) * 64 + c8 * 8];
        U16x8 o;
#pragma unroll
        for (int j = 0; j < 8; ++j) o.s[j] = f2b(b2f(st.s[j]) + b2f(old.s[j]));
        *(U16x8*)&EHio[(rb + row) * 64 + c8 * 8] = o;
    }
}

// ---------------- CSR gather aggregate: per-node softmax + weighted sum (+col-stats) ----------------
template <int COLS, bool SOUT>
__global__ __launch_bounds__(256) void csr_aggregate_kernel(
    const int* __restrict__ rowptr, const int* __restrict__ esrc,
    const float* __restrict__ eatt, const u16* __restrict__ nodeh, float* __restrict__ hout,
    int n, float* __restrict__ raw) {
    constexpr int H = COLS / 64;
    constexpr int TPN = COLS / 2;
    constexpr int NPB = 256 / TPN;
    __shared__ float ssum[SOUT ? COLS : 1];
    __shared__ float ssq[SOUT ? COLS : 1];
    int tid = threadIdx.x;
    if (SOUT) {
        for (int i = tid; i < COLS; i += 256) { ssum[i] = 0.f; ssq[i] = 0.f; }
        __syncthreads();
    }
    int node = blockIdx.x * NPB + tid / TPN;
    bool act = node < n;
    int c = (tid % TPN) * 2;
    float a0 = 0.f, a1 = 0.f;
    if (act) {
        int h = (H == 2) ? (c >> 6) : 0;
        int p0 = rowptr[node], p1 = rowptr[node + 1];
        float m = -INFINITY, s = 0.f;
        for (int p = p0; p < p1; ++p) {
            float v = eatt[(long)p * H + h];
            float mn = fmaxf(m, v);
            s = s * expf(m - mn) + expf(v - mn);
            m = mn;
        }
        float inv = (s > 0.f) ? 1.f / s : 0.f;
        for (int p = p0; p < p1; ++p) {
            float w = expf(eatt[(long)p * H + h] - m) * inv;
            U16x2 v = *(const U16x2*)&nodeh[(long)esrc[p] * COLS + c];
            a0 += b2f(v.s[0]) * w;
            a1 += b2f(v.s[1]) * w;
        }
        *(float2*)&hout[(long)node * COLS + c] = make_float2(a0, a1);
    }
    if (SOUT) {
        if (act) {
            atomicAdd(&ssum[c], a0);
            atomicAdd(&ssum[c + 1], a1);
            atomicAdd(&ssq[c], a0 * a0);
            atomicAdd(&ssq[c + 1], a1 * a1);
        }
        __syncthreads();
        float* slot = raw + (size_t)(blockIdx.x & (NSLOT - 1)) * 256;
        for (int i = tid; i < COLS; i += 256) {
            atomicAdd(&slot[i], ssum[i]);
            atomicAdd(&slot[COLS + i], ssq[i]);
        }
    }
}

// ---------------- decoder tail: prelu(bn(t3)) @ Wout + bout -> pool by graph ----------------
__global__ __launch_bounds__(256) void decoder_out_kernel(
    const u16* __restrict__ t3, const float* __restrict__ stats, const float* __restrict__ g,
    const float* __restrict__ b, const float* __restrict__ prelu, const float* __restrict__ Wout,
    const float* __restrict__ bout, const int* __restrict__ gid, float* __restrict__ pool,
    int rows, float inv_rows) {
    int tid = threadIdx.x;
    long r = (long)blockIdx.x * 4 + (tid >> 6);
    if (r >= rows) return;
    int k = tid & 63;
    float mu = stats[k] * inv_rows;
    float var = stats[64 + k] * inv_rows - mu * mu;
    float al = g[k] * rsqrtf(fmaxf(var, 0.f) + EPS);
    float be = b[k] - mu * al;
    float a = prelu[3];
    float v = al * b2f(t3[r * 64 + k]) + be;
    v = (v >= 0.f) ? v : a * v;
    v *= Wout[k];
#pragma unroll
    for (int off = 1; off < 64; off <<= 1) v += __shfl_xor(v, off, 64);
    if (k == 0) atomicAdd(&pool[gid[r]], v + bout[0]);
}

// =====================================================================================
extern "C" void kernel_launch(void* const* d_in, const int* in_sizes, int n_in, void* d_out,
                              int out_size, void* d_ws, size_t ws_size, hipStream_t stream) {
    if (n_in < 57) return;
    const int* ntype = (const int*)d_in[0];
    const int* src = (const int*)d_in[1];
    const int* dst = (const int*)d_in[2];
    const int* gid = (const int*)d_in[3];
    const float* ang_rot = (const float*)d_in[4];
    const float* ang_ref = (const float*)d_in[5];
    const float* efeats = (const float*)d_in[6];
    const float* emb = (const float*)d_in[7];
    const float* enc_W = (const float*)d_in[8];
    const float* enc_b = (const float*)d_in[9];
    const float* ee_W1 = (const float*)d_in[10];
    const float* ee_b1 = (const float*)d_in[11];
    const float* ee_W2 = (const float*)d_in[12];
    const float* ee_b2 = (const float*)d_in[13];
    const float* enc_bn1_g = (const float*)d_in[14];
    const float* enc_bn1_b = (const float*)d_in[15];
    const float* enc_bn2_g = (const float*)d_in[16];
    const float* enc_bn2_b = (const float*)d_in[17];
    const float* ee_bn1_g = (const float*)d_in[18];
    const float* ee_bn1_b = (const float*)d_in[19];
    const float* ee_bn2_g = (const float*)d_in[20];
    const float* ee_bn2_b = (const float*)d_in[21];
    const float* l0_Wnode = (const float*)d_in[22];
    const float* l0_bnode = (const float*)d_in[23];
    const float* l0_Wni = (const float*)d_in[24];
    const float* l0_Wnj = (const float*)d_in[25];
    const float* l0_Wfij = (const float*)d_in[26];
    const float* l0_attn = (const float*)d_in[27];
    const float* l0_bnn_g = (const float*)d_in[28];
    const float* l0_bnn_b = (const float*)d_in[29];
    const float* l0_bne_g = (const float*)d_in[30];
    const float* l0_bne_b = (const float*)d_in[31];
    const float* l0_Wpn = (const float*)d_in[32];
    const float* l0_bpn = (const float*)d_in[33];
    const float* l0_Wpe = (const float*)d_in[34];
    const float* l0_bpe = (const float*)d_in[35];
    const float* l1_Wnode = (const float*)d_in[36];
    const float* l1_bnode = (const float*)d_in[37];
    const float* l1_Wni = (const float*)d_in[38];
    const float* l1_Wnj = (const float*)d_in[39];
    const float* l1_Wfij = (const float*)d_in[40];
    const float* l1_attn = (const float*)d_in[41];
    const float* l1_bnn_g = (const float*)d_in[42];
    const float* l1_bnn_b = (const float*)d_in[43];
    const float* l1_Wpn = (const float*)d_in[46];
    const float* l1_bpn = (const float*)d_in[47];
    const float* dec_W = (const float*)d_in[50];
    const float* dec_b = (const float*)d_in[51];
    const float* dec_bn_g = (const float*)d_in[52];
    const float* dec_bn_b = (const float*)d_in[53];
    const float* dec_prelu = (const float*)d_in[54];
    const float* dec_Wout = (const float*)d_in[55];
    const float* dec_bout = (const float*)d_in[56];

    float* out = (float*)d_out;
    float* H1 = out;                     // N x 64 (fp32)
    float* H2 = out + (long)NN * 64;     // N x 64 (fp32)
    float* POOL = out + (long)NN * 128;  // G x 1 (fp32)

    char* base = (char*)d_ws;
    size_t off = 0;
    auto alloc = [&](size_t bytes) -> void* {
        off = (off + 255) & ~(size_t)255;
        void* p = base + off;
        off += bytes;
        return p;
    };
    u16* EH = (u16*)alloc((size_t)NE * 64 * 2);
    u16* F128 = (u16*)alloc((size_t)NE * 128 * 2);  // also node-enc temps
    float* EATT = (float*)alloc((size_t)NE * 2 * 4);
    u16* NX = (u16*)alloc((size_t)NN * 64 * 2);
    u16* NI = (u16*)alloc((size_t)NN * 128 * 2);
    u16* NJ = (u16*)alloc((size_t)NN * 128 * 2);
    u16* NHH = (u16*)alloc((size_t)NN * 128 * 2);
    float* HOUT0 = (float*)alloc((size_t)NN * 128 * 4);
    float* HOUT1 = (float*)alloc((size_t)NN * 64 * 4);
    int* ROWPTR = (int*)alloc((size_t)(NN + 1) * 4);
    int* CURS = (int*)alloc((size_t)NN * 4);
    int* ESRC = (int*)alloc((size_t)NE * 4);
    int* DSTS = (int*)alloc((size_t)NE * 4);
    float* EFP = (float*)alloc((size_t)NE * 3 * 4);
    int* BSUM = (int*)alloc((size_t)256 * 4);
    float* RWrot = (float*)alloc(256 * 4);
    float* RWref = (float*)alloc(256 * 4);
    u16* EncWT = (u16*)alloc(4096 * 2);
    u16* W2T = (u16*)alloc(4096 * 2);
    u16* Wni0T = (u16*)alloc(8192 * 2);
    u16* Wnj0T = (u16*)alloc(8192 * 2);
    u16* Wnd0T = (u16*)alloc(8192 * 2);
    u16* WfijT0 = (u16*)alloc(8192 * 2);
    u16* Wpn0T = (u16*)alloc(8192 * 2);
    u16* WpeT = (u16*)alloc(8192 * 2);
    u16* Wni1T = (u16*)alloc(4096 * 2);
    u16* Wnj1T = (u16*)alloc(4096 * 2);
    u16* Wnd1T = (u16*)alloc(4096 * 2);
    u16* WfijT1 = (u16*)alloc(4096 * 2);
    u16* Wpn1T = (u16*)alloc(4096 * 2);
    u16* DecT0 = (u16*)alloc(4096 * 2);
    u16* DecT1 = (u16*)alloc(4096 * 2);
    u16* DecT2 = (u16*)alloc(4096 * 2);
    u16* DecT3 = (u16*)alloc(4096 * 2);
    float* STATS = (float*)alloc((size_t)13 * 256 * 4);
    char* zstart = base + ((off + 255) & ~(size_t)255);
    int* DEG = (int*)alloc((size_t)NN * 4);
    float* STATS_RAW = (float*)alloc((size_t)13 * NSLOT * 256 * 4);
    float* RAWEF = (float*)alloc((size_t)NSLOT * 16 * 4);
    char* zend = base + off;
    if (ws_size < off) return;

    u16* NX0 = F128;                    // NN x 64 bf16 (node-enc temp; before layer 0)
    u16* NT = F128 + (size_t)NN * 64;   // NN x 64 bf16 (node-enc temp)
    u16* DT0 = NI;
    u16* DT1 = NJ;

    auto RAW = [&](int idx) { return STATS_RAW + (size_t)idx * NSLOT * 256; };
    float* S_enc1 = STATS + 0 * 256;
    float* S_enc2 = STATS + 1 * 256;
    float* S_ee1r = STATS + 2 * 256;
    float* S_ee2r = STATS + 3 * 256;
    float* S_ee1f = STATS + 4 * 256;
    float* S_ee2f = STATS + 5 * 256;
    float* S_bnn0 = STATS + 6 * 256;
    float* S_bne0 = STATS + 7 * 256;
    float* S_bnn1 = STATS + 8 * 256;
    float* S_d0 = STATS + 9 * 256;
    float* S_d1 = STATS + 10 * 256;
    float* S_d2 = STATS + 11 * 256;
    float* S_d3 = STATS + 12 * 256;

    const float invN = 1.f / (float)NN;
    const float invE = 1.f / (float)NE;
    const int GS = 640;
    const int MFB = NE / 64;          // 6250 (exact)
    const int NNB = (NN + 63) / 64;   // 782 (tail waves skip)
    const int NB = (NN + 255) / 256;  // scan blocks

    hipMemsetAsync(zstart, 0, (size_t)(zend - zstart), stream);
    hipMemsetAsync(POOL, 0, (size_t)NG * 4, stream);

    setup_kernel<<<1, 64, 0, stream>>>(ang_rot, ang_ref, ee_W1, RWrot, RWref);
    {
        WtJobs j;
        const float* Ws[NWT] = {enc_W,  ee_W2,  l0_Wni, l0_Wnj, l0_Wnode, l0_Wfij,
                                l0_Wpn, l0_Wpe, l1_Wni, l1_Wnj, l1_Wnode, l1_Wfij,
                                l1_Wpn, dec_W,  dec_W + 4096, dec_W + 8192, dec_W + 12288};
        u16* Ts[NWT] = {EncWT, W2T, Wni0T, Wnj0T, Wnd0T, WfijT0, Wpn0T, WpeT, Wni1T,
                        Wnj1T, Wnd1T, WfijT1, Wpn1T, DecT0, DecT1, DecT2, DecT3};
        int Ks[NWT] = {64, 64, 64, 64, 64, 64, 128, 128, 64, 64, 64, 64, 64, 64, 64, 64, 64};
        int Cs[NWT] = {64, 64, 128, 128, 128, 128, 64, 64, 64, 64, 64, 64, 64, 64, 64, 64, 64};
        for (int i = 0; i < NWT; ++i) { j.W[i] = Ws[i]; j.WT[i] = Ts[i]; j.K[i] = Ks[i]; j.C[i] = Cs[i]; }
        wt_all_kernel<<<NWT * 32, 256, 0, stream>>>(j);
    }

    // ---- CSR build (+ edge permutation into CSR order) ----
    hist_kernel<<<(NE + 255) / 256, 256, 0, stream>>>(dst, NE, DEG);
    scan_part_kernel<<<NB, 256, 0, stream>>>(DEG, BSUM, NN);
    scan_top_kernel<<<1, 256, 0, stream>>>(BSUM, NB, ROWPTR, NN, NE);
    scan_fill_kernel<<<NB, 256, 0, stream>>>(DEG, BSUM, ROWPTR, CURS, NN);
    fill_kernel<<<(NE + 255) / 256, 256, 0, stream>>>(src, dst, efeats, NE, CURS, ESRC, DSTS,
                                                      EFP);

    // ---- node encoder ----
    gather_emb_kernel<<<(NN * 8 + 255) / 256, 256, 0, stream>>>(ntype, emb, NX0, NN);
    colstats_kernel<64><<<GS, 256, 0, stream>>>(NX0, NN, RAW(0));
    finalize_stats_kernel<<<1, 256, 0, stream>>>(RAW(0), S_enc1, 128);
    mfma_mm_kernel<64, 64, true, false, true, true><<<NNB, 256, 0, stream>>>(
        NX0, EncWT, enc_b, nullptr, NT, NN, 2, S_enc1, enc_bn1_g, enc_bn1_b, invN, nullptr, 0,
        RAW(1));
    finalize_stats_kernel<<<1, 256, 0, stream>>>(RAW(1), S_enc2, 128);
    bn_act_kernel<<<(NN * 8 + 255) / 256, 256, 0, stream>>>(NT, NX, NN, 64, S_enc2, enc_bn2_g,
                                                            enc_bn2_b, invN);

    // ---- edge encoder (CSR order): analytic T1 stats, recompute-stats, recompute-merge ----
    efstats_kernel<<<256, 256, 0, stream>>>(efeats, NE, RAWEF);
    ee_stats_kernel<<<1, 128, 0, stream>>>(RAWEF, RWrot, RWref, ee_b1, S_ee1r, S_ee1f, NE);
    mfma_ee2_kernel<false><<<MFB, 256, 0, stream>>>(
        EFP, RWrot, RWref, ee_b1, W2T, ee_b2, S_ee1r, S_ee1f, nullptr, nullptr, ee_bn1_g,
        ee_bn1_b, nullptr, nullptr, nullptr, NE, invE, RAW(3), RAW(5));
    finalize_stats_kernel<<<1, 256, 0, stream>>>(RAW(3), S_ee2r, 128);
    finalize_stats_kernel<<<1, 256, 0, stream>>>(RAW(5), S_ee2f, 128);
    mfma_ee2_kernel<true><<<MFB, 256, 0, stream>>>(
        EFP, RWrot, RWref, ee_b1, W2T, ee_b2, S_ee1r, S_ee1f, S_ee2r, S_ee2f, ee_bn1_g, ee_bn1_b,
        ee_bn2_g, ee_bn2_b, EH, NE, invE, nullptr, nullptr);

    // ---- layer 0 (H=2) ----
    mfma_mm3_kernel<128, true><<<NNB, 256, 0, stream>>>(NX, Wni0T, Wnj0T, Wnd0T, l0_bnode, NI,
                                                        NJ, NHH, NN);
    mfma_egat_kernel<128, true, true><<<MFB, 256, 0, stream>>>(
        EH, WfijT0, NI, NJ, ESRC, DSTS, l0_attn, F128, EATT, NE, RAW(7));
    finalize_stats_kernel<<<1, 256, 0, stream>>>(RAW(7), S_bne0, 256);
    csr_aggregate_kernel<128, true><<<(NN + 3) / 4, 256, 0, stream>>>(ROWPTR, ESRC, EATT, NHH,
                                                                      HOUT0, NN, RAW(6));
    finalize_stats_kernel<<<1, 256, 0, stream>>>(RAW(6), S_bnn0, 256);
    mfma_mm_kernel<128, 64, false, true, false, false><<<NNB, 256, 0, stream>>>(
        HOUT0, Wpn0T, l0_bpn, NX, H1, NN, 1, S_bnn0, l0_bnn_g, l0_bnn_b, invN, nullptr, 0,
        nullptr);
    mfma_pe_kernel<<<MFB, 256, 0, stream>>>(F128, WpeT, l0_bpe, EH, NE, S_bne0, l0_bne_g,
                                            l0_bne_b, invE);

    // ---- layer 1 (H=1; edge output dead -> skipped) ----
    mfma_mm3_kernel<64, false><<<NNB, 256, 0, stream>>>(H1, Wni1T, Wnj1T, Wnd1T, l1_bnode, NI,
                                                        NJ, NHH, NN);
    mfma_egat_kernel<64, false, false><<<MFB, 256, 0, stream>>>(
        EH, WfijT1, NI, NJ, ESRC, DSTS, l1_attn, nullptr, EATT, NE, nullptr);
    csr_aggregate_kernel<64, true><<<(NN + 7) / 8, 256, 0, stream>>>(ROWPTR, ESRC, EATT, NHH,
                                                                     HOUT1, NN, RAW(8));
    finalize_stats_kernel<<<1, 256, 0, stream>>>(RAW(8), S_bnn1, 128);
    mfma_mm_kernel<64, 64, false, false, false, false><<<NNB, 256, 0, stream>>>(
        HOUT1, Wpn1T, l1_bpn, H1, H2, NN, 1, S_bnn1, l1_bnn_g, l1_bnn_b, invN, nullptr, 0,
        nullptr);

    // ---- decoder ----
    mfma_mm_kernel<64, 64, false, false, true, true><<<NNB, 256, 0, stream>>>(
        H2, DecT0, dec_b, nullptr, DT0, NN, 0, nullptr, nullptr, nullptr, 0.f, nullptr, 0,
        RAW(9));
    finalize_stats_kernel<<<1, 256, 0, stream>>>(RAW(9), S_d0, 128);
    mfma_mm_kernel<64, 64, true, false, true, true><<<NNB, 256, 0, stream>>>(
        DT0, DecT1, dec_b + 64, nullptr, DT1, NN, 3, S_d0, dec_bn_g, dec_bn_b, invN, dec_prelu,
        0, RAW(10));
    finalize_stats_kernel<<<1, 256, 0, stream>>>(RAW(10), S_d1, 128);
    mfma_mm_kernel<64, 64, true, false, true, true><<<NNB, 256, 0, stream>>>(
        DT1, DecT2, dec_b + 128, nullptr, DT0, NN, 3, S_d1, dec_bn_g + 64, dec_bn_b + 64, invN,
        dec_prelu, 1, RAW(11));
    finalize_stats_kernel<<<1, 256, 0, stream>>>(RAW(11), S_d2, 128);
    mfma_mm_kernel<64, 64, true, false, true, true><<<NNB, 256, 0, stream>>>(
        DT0, DecT3, dec_b + 192, nullptr, DT1, NN, 3, S_d2, dec_bn_g + 128, dec_bn_b + 128,
        invN, dec_prelu, 2, RAW(12));
    finalize_stats_kernel<<<1, 256, 0, stream>>>(RAW(12), S_d3, 128);
    decoder_out_kernel<<<(NN + 3) / 4, 256, 0, stream>>>(DT1, S_d3, dec_bn_g + 192,
                                                         dec_bn_b + 192, dec_prelu, dec_Wout,
                                                         dec_bout, gid, POOL, NN, invN);
}

// Round 12
// 864.454 us; speedup vs baseline: 1.1402x; 1.1402x over previous
//
#include <hip/hip_runtime.h>
#include <math.h>

#define NN 50000
#define NE 400000
#define NG 512
#define EPS 1e-5f
#define NSLOT 256  // stats replica slots (atomic contention spreading)

typedef unsigned int u32;
typedef unsigned short u16;

typedef __attribute__((ext_vector_type(8))) short s16x8;  // 8 bf16 (4 VGPRs)
typedef __attribute__((ext_vector_type(4))) float f32x4;

__device__ __forceinline__ float b2f(u16 h) { return __uint_as_float(((u32)h) << 16); }
__device__ __forceinline__ u16 f2b(float f) {
    u32 x = __float_as_uint(f);
    u32 r = x + 0x7fffu + ((x >> 16) & 1u);
    return (u16)(r >> 16);
}
struct alignas(16) U16x8 { u16 s[8]; };
struct alignas(8) U16x4 { u16 s[4]; };
struct alignas(4) U16x2 { u16 s[2]; };

__device__ __forceinline__ void f4add(float4& a, const float4 b) {
    a.x += b.x; a.y += b.y; a.z += b.z; a.w += b.w;
}

// bijective XCD swizzle (guide T1, m204): works for any nwg
__device__ __forceinline__ int xcd_swizzle(int orig, int nwg) {
    int xcd = orig & 7;
    int q = nwg >> 3, r = nwg & 7;
    return (xcd < r ? xcd * (q + 1) : r * (q + 1) + (xcd - r) * q) + (orig >> 3);
}

// ---------------- setup: fold rotation matrices into ee_W1 (fp32) ----------------
__global__ void setup_kernel(const float* __restrict__ ang_rot, const float* __restrict__ ang_ref,
                             const float* __restrict__ W1, float* __restrict__ RWrot,
                             float* __restrict__ RWref) {
    int c = threadIdx.x;  // 64
    for (int which = 0; which < 2; ++which) {
        const float* a = which ? ang_ref : ang_rot;
        float t = a[0], p = a[1], q = a[2];
        float ct = cosf(t), st = sinf(t);
        float cp = cosf(p), sp = sinf(p);
        float cq = cosf(q), sq = sinf(q);
        float Rt[3][3] = {{ct, -st, 0.f}, {st, ct, 0.f}, {0.f, 0.f, 1.f}};
        float Rp[3][3] = {{cp, 0.f, -sp}, {0.f, 1.f, 0.f}, {sp, 0.f, cp}};
        float Rq[3][3] = {{1.f, 0.f, 0.f}, {0.f, cq, -sq}, {0.f, sq, cq}};
        float Rtp[3][3], R[3][3];
        for (int i = 0; i < 3; ++i)
            for (int j = 0; j < 3; ++j) {
                float s = 0.f;
                for (int k = 0; k < 3; ++k) s += Rt[i][k] * Rp[k][j];
                Rtp[i][j] = s;
            }
        for (int i = 0; i < 3; ++i)
            for (int j = 0; j < 3; ++j) {
                float s = 0.f;
                for (int k = 0; k < 3; ++k) s += Rtp[i][k] * Rq[k][j];
                R[i][j] = s;
            }
        float sgn = which ? -1.f : 1.f;  // R_ref = -rotmat(angles_ref)
        float* RW = which ? RWref : RWrot;
        if (c < 64) {
            for (int j = 0; j < 3; ++j) {
                float s = 0.f;
                for (int m = 0; m < 3; ++m) s += sgn * R[j][m] * W1[m * 64 + c];
                RW[j * 64 + c] = s;  // RW = R @ W1  (3 x 64)
            }
        }
    }
}

// ---------------- batched weight transpose: W [K][C] fp32 -> WT [C][K] bf16 ----------------
#define NWT 17
struct WtJobs {
    const float* W[NWT];
    u16* WT[NWT];
    int K[NWT];
    int C[NWT];
};
__global__ __launch_bounds__(256) void wt_all_kernel(WtJobs jobs) {
    int job = blockIdx.x >> 5;
    int idx = ((blockIdx.x & 31) << 8) + threadIdx.x;
    int K = jobs.K[job], C = jobs.C[job];
    if (idx >= K * C) return;
    int k = idx / C, c = idx - k * C;
    jobs.WT[job][c * K + k] = f2b(jobs.W[job][idx]);
}

// ---------------- CSR build: degree hist -> 3-phase scan -> fill ----------------
__global__ __launch_bounds__(256) void hist_kernel(const int* __restrict__ dst, int E,
                                                   int* __restrict__ deg) {
    int e = blockIdx.x * 256 + threadIdx.x;
    if (e < E) atomicAdd(&deg[dst[e]], 1);
}

__global__ __launch_bounds__(256) void scan_part_kernel(const int* __restrict__ deg,
                                                        int* __restrict__ bsum, int n) {
    int i = blockIdx.x * 256 + threadIdx.x;
    int v = (i < n) ? deg[i] : 0;
#pragma unroll
    for (int off = 1; off < 64; off <<= 1) v += __shfl_xor(v, off, 64);
    __shared__ int ws[4];
    if ((threadIdx.x & 63) == 0) ws[threadIdx.x >> 6] = v;
    __syncthreads();
    if (threadIdx.x == 0) bsum[blockIdx.x] = ws[0] + ws[1] + ws[2] + ws[3];
}

__global__ __launch_bounds__(256) void scan_top_kernel(int* __restrict__ bsum, int nb,
                                                       int* __restrict__ rowptr, int n,
                                                       int total) {
    __shared__ int s[256];
    int tid = threadIdx.x;
    s[tid] = (tid < nb) ? bsum[tid] : 0;
    __syncthreads();
    for (int off = 1; off < 256; off <<= 1) {
        int v = (tid >= off) ? s[tid - off] : 0;
        __syncthreads();
        s[tid] += v;
        __syncthreads();
    }
    if (tid < nb) bsum[tid] = (tid == 0) ? 0 : s[tid - 1];
    if (tid == 0) rowptr[n] = total;
}

__global__ __launch_bounds__(256) void scan_fill_kernel(const int* __restrict__ deg,
                                                        const int* __restrict__ bsum,
                                                        int* __restrict__ rowptr,
                                                        int* __restrict__ curs, int n) {
    __shared__ int s[256];
    int tid = threadIdx.x;
    int i = blockIdx.x * 256 + tid;
    int v = (i < n) ? deg[i] : 0;
    s[tid] = v;
    __syncthreads();
    for (int off = 1; off < 256; off <<= 1) {
        int t = (tid >= off) ? s[tid - off] : 0;
        __syncthreads();
        s[tid] += t;
        __syncthreads();
    }
    if (i < n) {
        int excl = s[tid] - v + bsum[blockIdx.x];
        rowptr[i] = excl;
        curs[i] = excl;
    }
}

// fill: scatter edges into CSR slots; emit permuted src/dst/efeats (CSR order everywhere after)
__global__ __launch_bounds__(256) void fill_kernel(const int* __restrict__ src,
                                                   const int* __restrict__ dst,
                                                   const float* __restrict__ ef, int E,
                                                   int* __restrict__ curs,
                                                   int* __restrict__ esrc,
                                                   int* __restrict__ dsts,
                                                   float* __restrict__ efp) {
    int e = blockIdx.x * 256 + threadIdx.x;
    if (e >= E) return;
    int d = dst[e];
    int pos = atomicAdd(&curs[d], 1);
    esrc[pos] = src[e];
    dsts[pos] = d;
    efp[(long)pos * 3 + 0] = ef[(long)e * 3 + 0];
    efp[(long)pos * 3 + 1] = ef[(long)e * 3 + 1];
    efp[(long)pos * 3 + 2] = ef[(long)e * 3 + 2];
}

// ---------------- embedding gather: fp32 table -> bf16 out ----------------
__global__ __launch_bounds__(256) void gather_emb_kernel(const int* __restrict__ ntype,
                                                         const float* __restrict__ emb,
                                                         u16* __restrict__ out, int n) {
    long i = (long)blockIdx.x * 256 + threadIdx.x;  // over n*8
    long e = i >> 3;
    if (e >= n) return;
    int c0 = (int)(i & 7) * 8;
    int t = ntype[e];
    float4 a = *(const float4*)&emb[(long)t * 64 + c0];
    float4 b = *(const float4*)&emb[(long)t * 64 + c0 + 4];
    U16x8 o;
    o.s[0] = f2b(a.x); o.s[1] = f2b(a.y); o.s[2] = f2b(a.z); o.s[3] = f2b(a.w);
    o.s[4] = f2b(b.x); o.s[5] = f2b(b.y); o.s[6] = f2b(b.z); o.s[7] = f2b(b.w);
    *(U16x8*)&out[e * 64 + c0] = o;
}

// ---------------- efeats second moments: 9 scalars -> replica slots ----------------
__global__ __launch_bounds__(256) void efstats_kernel(const float* __restrict__ ef, int E,
                                                      float* __restrict__ raw) {
    int tid = threadIdx.x;
    float a[9];
#pragma unroll
    for (int j = 0; j < 9; ++j) a[j] = 0.f;
    for (long e = (long)blockIdx.x * 256 + tid; e < E; e += (long)gridDim.x * 256) {
        float f0 = ef[e * 3 + 0], f1 = ef[e * 3 + 1], f2 = ef[e * 3 + 2];
        a[0] += f0; a[1] += f1; a[2] += f2;
        a[3] += f0 * f0; a[4] += f1 * f1; a[5] += f2 * f2;
        a[6] += f0 * f1; a[7] += f0 * f2; a[8] += f1 * f2;
    }
#pragma unroll
    for (int off = 1; off < 64; off <<= 1)
#pragma unroll
        for (int j = 0; j < 9; ++j) a[j] += __shfl_xor(a[j], off, 64);
    __shared__ float sred[4][9];
    int wv = tid >> 6, ln = tid & 63;
    if (ln == 0)
#pragma unroll
        for (int j = 0; j < 9; ++j) sred[wv][j] = a[j];
    __syncthreads();
    if (tid < 9) {
        float v = sred[0][tid] + sred[1][tid] + sred[2][tid] + sred[3][tid];
        atomicAdd(&raw[(size_t)(blockIdx.x & (NSLOT - 1)) * 16 + tid], v);
    }
}

// ---------------- analytic T1 column stats for both branches ----------------
__global__ void ee_stats_kernel(const float* __restrict__ efraw, const float* __restrict__ RWrot,
                                const float* __restrict__ RWref, const float* __restrict__ b1,
                                float* __restrict__ S_rot, float* __restrict__ S_ref, int E) {
    __shared__ float m[9];
    int t = threadIdx.x;  // 128
    if (t < 9) {
        float s = 0.f;
        for (int r = 0; r < NSLOT; ++r) s += efraw[r * 16 + t];
        m[t] = s;
    }
    __syncthreads();
    int br = t >> 6, c = t & 63;
    const float* RW = br ? RWref : RWrot;
    float* S = br ? S_ref : S_rot;
    float w0 = RW[c], w1 = RW[64 + c], w2 = RW[128 + c];
    float bb = b1[c];
    float mw = m[0] * w0 + m[1] * w1 + m[2] * w2;
    float sum = mw + (float)E * bb;
    float quad = m[3] * w0 * w0 + m[4] * w1 * w1 + m[5] * w2 * w2 +
                 2.f * (m[6] * w0 * w1 + m[7] * w0 * w2 + m[8] * w1 * w2);
    float ss = quad + 2.f * bb * mw + (float)E * bb * bb;
    S[c] = sum;
    S[64 + c] = ss;
}

// ---------------- column stats (bf16 input) -> replicated raw accumulators ----------------
template <int COLS>
__global__ __launch_bounds__(256) void colstats_kernel(const u16* __restrict__ xv, int rows,
                                                       float* __restrict__ raw) {
    constexpr int TPR = COLS / 8;
    constexpr int RPB = 256 / TPR;
    __shared__ float4 sA[256], sB[256], sC[256], sD[256];
    int tid = threadIdx.x;
    int c8 = tid % TPR;
    int rl = tid / TPR;
    float s[8], q[8];
#pragma unroll
    for (int j = 0; j < 8; ++j) { s[j] = 0.f; q[j] = 0.f; }
    const long stride = (long)gridDim.x * RPB;
    for (long r = (long)blockIdx.x * RPB + rl; r < rows; r += stride) {
        U16x8 t = *(const U16x8*)&xv[r * COLS + c8 * 8];
#pragma unroll
        for (int j = 0; j < 8; ++j) {
            float v = b2f(t.s[j]);
            s[j] += v;
            q[j] += v * v;
        }
    }
    sA[tid] = make_float4(s[0], s[1], s[2], s[3]);
    sB[tid] = make_float4(s[4], s[5], s[6], s[7]);
    sC[tid] = make_float4(q[0], q[1], q[2], q[3]);
    sD[tid] = make_float4(q[4], q[5], q[6], q[7]);
    __syncthreads();
    for (int off = 128; off >= TPR; off >>= 1) {
        if (tid < off) {
            f4add(sA[tid], sA[tid + off]); f4add(sB[tid], sB[tid + off]);
            f4add(sC[tid], sC[tid + off]); f4add(sD[tid], sD[tid + off]);
        }
        __syncthreads();
    }
    if (tid < TPR) {
        float* slot = raw + (size_t)(blockIdx.x & (NSLOT - 1)) * 256;
        int c = tid * 8;
        float4 a = sA[tid], b = sB[tid], cq = sC[tid], d = sD[tid];
        atomicAdd(&slot[c + 0], a.x); atomicAdd(&slot[c + 1], a.y);
        atomicAdd(&slot[c + 2], a.z); atomicAdd(&slot[c + 3], a.w);
        atomicAdd(&slot[c + 4], b.x); atomicAdd(&slot[c + 5], b.y);
        atomicAdd(&slot[c + 6], b.z); atomicAdd(&slot[c + 7], b.w);
        atomicAdd(&slot[COLS + c + 0], cq.x); atomicAdd(&slot[COLS + c + 1], cq.y);
        atomicAdd(&slot[COLS + c + 2], cq.z); atomicAdd(&slot[COLS + c + 3], cq.w);
        atomicAdd(&slot[COLS + c + 4], d.x); atomicAdd(&slot[COLS + c + 5], d.y);
        atomicAdd(&slot[COLS + c + 6], d.z); atomicAdd(&slot[COLS + c + 7], d.w);
    }
}

// ---------------- reduce NSLOT replica slots -> final stats ----------------
__global__ __launch_bounds__(256) void finalize_stats_kernel(const float* __restrict__ raw,
                                                             float* __restrict__ stats, int n) {
    int i = threadIdx.x;
    if (i >= n) return;
    float s = 0.f;
    for (int r = 0; r < NSLOT; ++r) s += raw[r * 256 + i];
    stats[i] = s;
}

// ---------------- y = relu(bn(x)), bf16 (node-enc bn2) ----------------
__global__ __launch_bounds__(256) void bn_act_kernel(const u16* __restrict__ x,
                                                     u16* __restrict__ y, long rows, int cols,
                                                     const float* __restrict__ acc,
                                                     const float* __restrict__ g,
                                                     const float* __restrict__ b,
                                                     float inv_rows) {
    long i = (long)blockIdx.x * 256 + threadIdx.x;
    long total8 = rows * (long)cols / 8;
    if (i >= total8) return;
    long base = i * 8;
    int c0 = (int)(base % cols);
    U16x8 xv = *(const U16x8*)&x[base];
    U16x8 o;
#pragma unroll
    for (int j = 0; j < 8; ++j) {
        int c = c0 + j;
        float mu = acc[c] * inv_rows;
        float var = acc[cols + c] * inv_rows - mu * mu;
        float al = g[c] * rsqrtf(fmaxf(var, 0.f) + EPS);
        float be = b[c] - mu * al;
        o.s[j] = f2b(fmaxf(al * b2f(xv.s[j]) + be, 0.f));
    }
    *(U16x8*)&y[base] = o;
}

// ================= MFMA kernels =================
// Fragment layout (guide §3, m89/m91/m92 verified):
//   A: lane l holds A[row=l&15][k=(l>>4)*8+j]
//   B: lane l holds B[k=(l>>4)*8+j][col=l&15]  (8 contiguous bf16 from W^T row)
//   D: lane l reg r holds D[row=(l>>4)*4+r][col=l&15]
// Block = 4 waves = 64 rows. NE%64==0; NN%16==0 (tail waves skip).

// ---- generic: Y = preop(X) @ W (+bias)(+res), optional fused col-stats ----
template <int K, int COLS, bool XBF, bool RBF, bool OBF, bool SOUT>
__global__ __launch_bounds__(256) void mfma_mm_kernel(
    const void* __restrict__ Xv, const u16* __restrict__ WT, const float* __restrict__ bias,
    const void* __restrict__ resv, void* __restrict__ Yv, int rows, int preop,
    const float* __restrict__ stats, const float* __restrict__ g, const float* __restrict__ b,
    float inv_rows, const float* __restrict__ prelu, int prelu_idx, float* __restrict__ raw) {
    constexpr int NCT = COLS / 16;
    constexpr int NKK = K / 32;
    __shared__ float al[K], be[K];
    __shared__ float ssum[SOUT ? COLS : 1], ssq[SOUT ? COLS : 1];
    const int tid = threadIdx.x;
    if (preop) {
        for (int k = tid; k < K; k += 256) {
            float mu = stats[k] * inv_rows;
            float var = stats[K + k] * inv_rows - mu * mu;
            float a = g[k] * rsqrtf(fmaxf(var, 0.f) + EPS);
            al[k] = a;
            be[k] = b[k] - mu * a;
        }
    }
    if (SOUT) {
        for (int i = tid; i < COLS; i += 256) { ssum[i] = 0.f; ssq[i] = 0.f; }
    }
    __syncthreads();
    const int lane = tid & 63, wv = tid >> 6;
    const int q = lane >> 4, rr = lane & 15;
    const long r0 = ((long)blockIdx.x * 4 + wv) * 16;
    const bool act = r0 < rows;
    const float pa = (preop == 3) ? prelu[prelu_idx] : 0.f;
    s16x8 afr[NKK];
    if (act) {
#pragma unroll
        for (int kk = 0; kk < NKK; ++kk) {
            float v[8];
            if (XBF) {
                U16x8 t = *(const U16x8*)((const u16*)Xv + (r0 + rr) * K + kk * 32 + q * 8);
#pragma unroll
                for (int j = 0; j < 8; ++j) v[j] = b2f(t.s[j]);
            } else {
                const float* xp = (const float*)Xv + (r0 + rr) * K + kk * 32 + q * 8;
                float4 t0 = *(const float4*)xp;
                float4 t1 = *(const float4*)(xp + 4);
                v[0] = t0.x; v[1] = t0.y; v[2] = t0.z; v[3] = t0.w;
                v[4] = t1.x; v[5] = t1.y; v[6] = t1.z; v[7] = t1.w;
            }
            union { u16 u[8]; s16x8 s; } o;
#pragma unroll
            for (int j = 0; j < 8; ++j) {
                float xx = v[j];
                if (preop) {
                    int k = kk * 32 + q * 8 + j;
                    xx = al[k] * xx + be[k];
                    if (preop == 2) xx = fmaxf(xx, 0.f);
                    else if (preop == 3) xx = (xx >= 0.f) ? xx : pa * xx;
                }
                o.u[j] = f2b(xx);
            }
            afr[kk] = o.s;
        }
#pragma unroll
        for (int ct = 0; ct < NCT; ++ct) {
            f32x4 acc = (f32x4){0.f, 0.f, 0.f, 0.f};
#pragma unroll
            for (int kk = 0; kk < NKK; ++kk) {
                s16x8 bfr = *(const s16x8*)&WT[(size_t)(ct * 16 + rr) * K + kk * 32 + q * 8];
                acc = __builtin_amdgcn_mfma_f32_16x16x32_bf16(afr[kk], bfr, acc, 0, 0, 0);
            }
            int col = ct * 16 + rr;
            float bb = bias ? bias[col] : 0.f;
            float fs = 0.f, fq = 0.f;
#pragma unroll
            for (int r = 0; r < 4; ++r) {
                long orr = r0 + q * 4 + r;
                float vv = acc[r] + bb;
                if (resv) {
                    if (RBF) vv += b2f(((const u16*)resv)[orr * COLS + col]);
                    else vv += ((const float*)resv)[orr * COLS + col];
                }
                if (OBF) ((u16*)Yv)[orr * COLS + col] = f2b(vv);
                else ((float*)Yv)[orr * COLS + col] = vv;
                if (SOUT) { fs += vv; fq += vv * vv; }
            }
            if (SOUT) {
                fs += __shfl_xor(fs, 16, 64); fs += __shfl_xor(fs, 32, 64);
                fq += __shfl_xor(fq, 16, 64); fq += __shfl_xor(fq, 32, 64);
                if (q == 0) {
                    atomicAdd(&ssum[col], fs);
                    atomicAdd(&ssq[col], fq);
                }
            }
        }
    }
    if (SOUT) {
        __syncthreads();
        float* slot = raw + (size_t)(blockIdx.x & (NSLOT - 1)) * 256;
        for (int i = tid; i < COLS; i += 256) {
            atomicAdd(&slot[i], ssum[i]);
            atomicAdd(&slot[COLS + i], ssq[i]);
        }
    }
}

// ---- 3 matmuls sharing the A operand: Y0 = X@W0, Y1 = X@W1, Y2 = X@W2 + bias2 ----
template <int COLS, bool XBF>
__global__ __launch_bounds__(256) void mfma_mm3_kernel(
    const void* __restrict__ Xv, const u16* __restrict__ WT0, const u16* __restrict__ WT1,
    const u16* __restrict__ WT2, const float* __restrict__ bias2, u16* __restrict__ Y0,
    u16* __restrict__ Y1, u16* __restrict__ Y2, int rows) {
    constexpr int NCT = COLS / 16;
    const int tid = threadIdx.x;
    const int lane = tid & 63, wv = tid >> 6;
    const int q = lane >> 4, rr = lane & 15;
    const long r0 = ((long)blockIdx.x * 4 + wv) * 16;
    if (r0 >= rows) return;
    s16x8 afr[2];
#pragma unroll
    for (int kk = 0; kk < 2; ++kk) {
        if (XBF) {
            afr[kk] = *(const s16x8*)((const u16*)Xv + (r0 + rr) * 64 + kk * 32 + q * 8);
        } else {
            const float* xp = (const float*)Xv + (r0 + rr) * 64 + kk * 32 + q * 8;
            float4 t0 = *(const float4*)xp;
            float4 t1 = *(const float4*)(xp + 4);
            union { u16 u[8]; s16x8 s; } o;
            o.u[0] = f2b(t0.x); o.u[1] = f2b(t0.y); o.u[2] = f2b(t0.z); o.u[3] = f2b(t0.w);
            o.u[4] = f2b(t1.x); o.u[5] = f2b(t1.y); o.u[6] = f2b(t1.z); o.u[7] = f2b(t1.w);
            afr[kk] = o.s;
        }
    }
    const u16* wts[3] = {WT0, WT1, WT2};
    u16* ys[3] = {Y0, Y1, Y2};
#pragma unroll
    for (int m = 0; m < 3; ++m) {
#pragma unroll
        for (int ct = 0; ct < NCT; ++ct) {
            f32x4 acc = (f32x4){0.f, 0.f, 0.f, 0.f};
#pragma unroll
            for (int kk = 0; kk < 2; ++kk) {
                s16x8 bfr = *(const s16x8*)&wts[m][(size_t)(ct * 16 + rr) * 64 + kk * 32 + q * 8];
                acc = __builtin_amdgcn_mfma_f32_16x16x32_bf16(afr[kk], bfr, acc, 0, 0, 0);
            }
            int col = ct * 16 + rr;
            float bb = (m == 2) ? bias2[col] : 0.f;
#pragma unroll
            for (int r = 0; r < 4; ++r) {
                long orr = r0 + q * 4 + r;
                ys[m][orr * COLS + col] = f2b(acc[r] + bb);
            }
        }
    }
}

// ---- edge encoder, both branches, in-register from 3 floats/row ----
// STORE=false: emit T2 col-stats only (rawA/rawB). STORE=true: EH = relu(bn2a(T2a)) + relu(bn2b(T2b)).
template <bool STORE>
__global__ __launch_bounds__(256) void mfma_ee2_kernel(
    const float* __restrict__ efp, const float* __restrict__ RWrot,
    const float* __restrict__ RWref, const float* __restrict__ b1v, const u16* __restrict__ W2T,
    const float* __restrict__ b2, const float* __restrict__ S1r, const float* __restrict__ S1f,
    const float* __restrict__ S2r, const float* __restrict__ S2f, const float* __restrict__ g1,
    const float* __restrict__ bn1b, const float* __restrict__ g2, const float* __restrict__ bn2b,
    u16* __restrict__ EH, int E, float inv_rows, float* __restrict__ rawA,
    float* __restrict__ rawB) {
    constexpr int ESTR = 72;  // padded u16 stride for EH staging
    __shared__ float rws[2][192];
    __shared__ float al1[2][64], be1[2][64];
    __shared__ float al2[2][64], be2[2][64];
    __shared__ float ssum[2][64], ssq[2][64];
    __shared__ u16 ets[STORE ? 64 * ESTR : 1];
    const int tid = threadIdx.x;
    if (tid < 192) {
        rws[0][tid] = RWrot[tid];
        rws[1][tid] = RWref[tid];
    }
    if (tid < 128) {
        int br = tid >> 6, k = tid & 63;
        const float* S1 = br ? S1f : S1r;
        float mu = S1[k] * inv_rows;
        float var = S1[64 + k] * inv_rows - mu * mu;
        float a = g1[k] * rsqrtf(fmaxf(var, 0.f) + EPS);
        al1[br][k] = a;
        be1[br][k] = bn1b[k] - mu * a + a * b1v[k];  // fold b1
        if (STORE) {
            const float* S2 = br ? S2f : S2r;
            mu = S2[k] * inv_rows;
            var = S2[64 + k] * inv_rows - mu * mu;
            a = g2[k] * rsqrtf(fmaxf(var, 0.f) + EPS);
            al2[br][k] = a;
            be2[br][k] = bn2b[k] - mu * a + a * b2[k];  // fold b2
        } else {
            ssum[br][k] = 0.f;
            ssq[br][k] = 0.f;
        }
    }
    __syncthreads();
    const int lane = tid & 63, wv = tid >> 6;
    const int q = lane >> 4, rr = lane & 15;
    const long r0 = ((long)blockIdx.x * 4 + wv) * 16;
    const long ar = r0 + rr;
    float e0 = efp[ar * 3], e1 = efp[ar * 3 + 1], e2 = efp[ar * 3 + 2];
    float v0[4][4];  // branch-0 post-bn2 values (STORE path)
#pragma unroll
    for (int br = 0; br < 2; ++br) {
        s16x8 afr[2];
#pragma unroll
        for (int kk = 0; kk < 2; ++kk) {
            union { u16 u[8]; s16x8 v; } t;
#pragma unroll
            for (int j = 0; j < 8; ++j) {
                int k = kk * 32 + q * 8 + j;
                float tv = e0 * rws[br][k] + e1 * rws[br][64 + k] + e2 * rws[br][128 + k];
                t.u[j] = f2b(fmaxf(al1[br][k] * tv + be1[br][k], 0.f));
            }
            afr[kk] = t.v;
        }
#pragma unroll
        for (int ct = 0; ct < 4; ++ct) {
            f32x4 acc = (f32x4){0.f, 0.f, 0.f, 0.f};
#pragma unroll
            for (int kk = 0; kk < 2; ++kk) {
                s16x8 bfr = *(const s16x8*)&W2T[(size_t)(ct * 16 + rr) * 64 + kk * 32 + q * 8];
                acc = __builtin_amdgcn_mfma_f32_16x16x32_bf16(afr[kk], bfr, acc, 0, 0, 0);
            }
            int col = ct * 16 + rr;
            if (STORE) {
#pragma unroll
                for (int r = 0; r < 4; ++r) {
                    float v = fmaxf(al2[br][col] * acc[r] + be2[br][col], 0.f);
                    if (br == 0) {
                        v0[ct][r] = v;
                    } else {
                        ets[(wv * 16 + q * 4 + r) * ESTR + col] = f2b(v0[ct][r] + v);
                    }
                }
            } else {
                float bb = b2[col];
                float s = 0.f, qq = 0.f;
#pragma unroll
                for (int r = 0; r < 4; ++r) {
                    float v = acc[r] + bb;
                    s += v;
                    qq += v * v;
                }
                s += __shfl_xor(s, 16, 64); s += __shfl_xor(s, 32, 64);
                qq += __shfl_xor(qq, 16, 64); qq += __shfl_xor(qq, 32, 64);
                if (q == 0) {
                    atomicAdd(&ssum[br][col], s);
                    atomicAdd(&ssq[br][col], qq);
                }
            }
        }
    }
    __syncthreads();
    if (STORE) {
        const long rb = (long)blockIdx.x * 64;
        for (int i = tid; i < 64 * 8; i += 256) {
            int row = i >> 3, c8 = i & 7;
            U16x8 v = *(const U16x8*)&ets[row * ESTR + c8 * 8];
            *(U16x8*)&EH[(rb + row) * 64 + c8 * 8] = v;
        }
    } else {
        if (tid < 128) {
            int br = tid >> 6, k = tid & 63;
            float* slot = (br ? rawB : rawA) + (size_t)(blockIdx.x & (NSLOT - 1)) * 256;
            atomicAdd(&slot[k], ssum[br][k]);
            atomicAdd(&slot[64 + k], ssq[br][k]);
        }
    }
}

// ---- f = leaky(EH@Wfij + NI[src] + NJ[dst]); att scores (CSR order); opt F store + col-stats ----
// Single-phase (high-MLP scalar gathers) + bijective XCD swizzle for NJ L2 locality.
template <int COLS, bool WRITE_F, bool SOUT>
__global__ __launch_bounds__(256) void mfma_egat_kernel(
    const u16* __restrict__ EH, const u16* __restrict__ WT, const u16* __restrict__ NI,
    const u16* __restrict__ NJ, const int* __restrict__ srcs, const int* __restrict__ dsts,
    const float* __restrict__ attn, u16* __restrict__ Fout, float* __restrict__ eatt, int E,
    float* __restrict__ raw) {
    constexpr int H = COLS / 64;
    constexpr int NCT = COLS / 16;
    constexpr int FSTR = COLS + 8;  // padded LDS row stride
    __shared__ float ssum[SOUT ? COLS : 1];
    __shared__ float ssq[SOUT ? COLS : 1];
    __shared__ u16 fts[WRITE_F ? 64 * FSTR : 1];
    const int tid = threadIdx.x;
    if (SOUT) {
        for (int i = tid; i < COLS; i += 256) { ssum[i] = 0.f; ssq[i] = 0.f; }
        __syncthreads();
    }
    const int bid = xcd_swizzle(blockIdx.x, gridDim.x);
    const int lane = tid & 63, wv = tid >> 6;
    const int q = lane >> 4, rr = lane & 15;
    const long r0 = ((long)bid * 4 + wv) * 16;
    s16x8 afr[2];
#pragma unroll
    for (int kk = 0; kk < 2; ++kk)
        afr[kk] = *(const s16x8*)&EH[(r0 + rr) * 64 + kk * 32 + q * 8];
    int sidx[4], didx[4];
#pragma unroll
    for (int r = 0; r < 4; ++r) {
        long orr = r0 + q * 4 + r;
        sidx[r] = srcs[orr];
        didx[r] = dsts[orr];
    }
    f32x4 acc[NCT];
#pragma unroll
    for (int ct = 0; ct < NCT; ++ct) {
        acc[ct] = (f32x4){0.f, 0.f, 0.f, 0.f};
#pragma unroll
        for (int kk = 0; kk < 2; ++kk) {
            s16x8 bfr = *(const s16x8*)&WT[(size_t)(ct * 16 + rr) * 64 + kk * 32 + q * 8];
            acc[ct] = __builtin_amdgcn_mfma_f32_16x16x32_bf16(afr[kk], bfr, acc[ct], 0, 0, 0);
        }
    }
    float part[H][4];
#pragma unroll
    for (int h = 0; h < H; ++h)
#pragma unroll
        for (int r = 0; r < 4; ++r) part[h][r] = 0.f;
#pragma unroll
    for (int ct = 0; ct < NCT; ++ct) {
        int col = ct * 16 + rr;
        float av = attn[col];
        const int h = (H == 2) ? (ct >> 2) : 0;
        float fs = 0.f, fq = 0.f;
#pragma unroll
        for (int r = 0; r < 4; ++r) {
            float f = acc[ct][r] + b2f(NI[(size_t)sidx[r] * COLS + col]) +
                      b2f(NJ[(size_t)didx[r] * COLS + col]);
            f = (f >= 0.f) ? f : 0.01f * f;
            if (WRITE_F) fts[(wv * 16 + q * 4 + r) * FSTR + col] = f2b(f);
            part[h][r] += f * av;
            if (SOUT) { fs += f; fq += f * f; }
        }
        if (SOUT) {
            fs += __shfl_xor(fs, 16, 64); fs += __shfl_xor(fs, 32, 64);
            fq += __shfl_xor(fq, 16, 64); fq += __shfl_xor(fq, 32, 64);
            if (q == 0) {
                atomicAdd(&ssum[col], fs);
                atomicAdd(&ssq[col], fq);
            }
        }
    }
#pragma unroll
    for (int h = 0; h < H; ++h)
#pragma unroll
        for (int r = 0; r < 4; ++r) {
            float p = part[h][r];
            p += __shfl_xor(p, 1, 64);
            p += __shfl_xor(p, 2, 64);
            p += __shfl_xor(p, 4, 64);
            p += __shfl_xor(p, 8, 64);
            part[h][r] = p;
        }
    if (rr == 0) {
#pragma unroll
        for (int r = 0; r < 4; ++r) {
            long pos = r0 + q * 4 + r;
            if (H == 2) {
                eatt[pos * 2 + 0] = part[0][r];
                eatt[pos * 2 + 1] = part[1][r];
            } else {
                eatt[pos] = part[0][r];
            }
        }
    }
    if (WRITE_F) {
        __syncthreads();
        const long rb = (long)bid * 64;
        constexpr int CH = COLS / 8;
        for (int i = tid; i < 64 * CH; i += 256) {
            int row = i / CH, c8 = i % CH;
            U16x8 v = *(const U16x8*)&fts[row * FSTR + c8 * 8];
            *(U16x8*)&Fout[(rb + row) * COLS + c8 * 8] = v;
        }
    }
    if (SOUT) {
        __syncthreads();
        float* slot = raw + (size_t)(blockIdx.x & (NSLOT - 1)) * 256;
        for (int i = tid; i < COLS; i += 256) {
            atomicAdd(&slot[i], ssum[i]);
            atomicAdd(&slot[COLS + i], ssq[i]);
        }
    }
}

// ---- EH = bn(F128)@Wpe + bpe + EH (K=128, streaming; coalesced residual epilogue) ----
__global__ __launch_bounds__(256) void mfma_pe_kernel(
    const u16* __restrict__ X, const u16* __restrict__ WT, const float* __restrict__ bias,
    u16* __restrict__ EHio, int E, const float* __restrict__ stats, const float* __restrict__ g,
    const float* __restrict__ b, float inv_rows) {
    constexpr int ESTR = 72;
    __shared__ float al[128], be[128];
    __shared__ u16 ets[64 * ESTR];
    const int tid = threadIdx.x;
    if (tid < 128) {
        float mu = stats[tid] * inv_rows;
        float var = stats[128 + tid] * inv_rows - mu * mu;
        float a = g[tid] * rsqrtf(fmaxf(var, 0.f) + EPS);
        al[tid] = a;
        be[tid] = b[tid] - mu * a;
    }
    __syncthreads();
    const int lane = tid & 63, wv = tid >> 6;
    const int q = lane >> 4, rr = lane & 15;
    const long r0 = ((long)blockIdx.x * 4 + wv) * 16;
    s16x8 afr[4];
#pragma unroll
    for (int kk = 0; kk < 4; ++kk) {
        U16x8 t = *(const U16x8*)&X[(r0 + rr) * 128 + kk * 32 + q * 8];
        union { u16 u[8]; s16x8 v; } o;
#pragma unroll
        for (int j = 0; j < 8; ++j) {
            int k = kk * 32 + q * 8 + j;
            o.u[j] = f2b(al[k] * b2f(t.s[j]) + be[k]);
        }
        afr[kk] = o.v;
    }
#pragma unroll
    for (int ct = 0; ct < 4; ++ct) {
        f32x4 acc = (f32x4){0.f, 0.f, 0.f, 0.f};
#pragma unroll
        for (int kk = 0; kk < 4; ++kk) {
            s16x8 bfr = *(const s16x8*)&WT[(size_t)(ct * 16 + rr) * 128 + kk * 32 + q * 8];
            acc = __builtin_amdgcn_mfma_f32_16x16x32_bf16(afr[kk], bfr, acc, 0, 0, 0);
        }
        int col = ct * 16 + rr;
        float bb = bias[col];
#pragma unroll
        for (int r = 0; r < 4; ++r)
            ets[(wv * 16 + q * 4 + r) * ESTR + col] = f2b(acc[r] + bb);
    }
    __syncthreads();
    const long rb = (long)blockIdx.x * 64;
#pragma unroll
    for (int g2 = 0; g2 < 2; ++g2) {
        int i = g2 * 256 + tid;
        int row = i >> 3, c8 = i & 7;
        U16x8 st = *(const U16x8*)&ets[row * ESTR + c8 * 8];
        U16x8 old = *(const U16x8*)&EHio[(rb + row) * 64 + c8 * 8];
        U16x8 o;
#pragma unroll
        for (int j = 0; j < 8; ++j) o.s[j] = f2b(b2f(st.s[j]) + b2f(old.s[j]));
        *(U16x8*)&EHio[(rb + row) * 64 + c8 * 8] = o;
    }
}

// ---------------- CSR gather aggregate: per-node softmax + weighted sum (+col-stats) ----------------
template <int COLS, bool SOUT>
__global__ __launch_bounds__(256) void csr_aggregate_kernel(
    const int* __restrict__ rowptr, const int* __restrict__ esrc,
    const float* __restrict__ eatt, const u16* __restrict__ nodeh, float* __restrict__ hout,
    int n, float* __restrict__ raw) {
    constexpr int H = COLS / 64;
    constexpr int TPN = COLS / 2;
    constexpr int NPB = 256 / TPN;
    __shared__ float ssum[SOUT ? COLS : 1];
    __shared__ float ssq[SOUT ? COLS : 1];
    int tid = threadIdx.x;
    if (SOUT) {
        for (int i = tid; i < COLS; i += 256) { ssum[i] = 0.f; ssq[i] = 0.f; }
        __syncthreads();
    }
    int node = blockIdx.x * NPB + tid / TPN;
    bool act = node < n;
    int c = (tid % TPN) * 2;
    float a0 = 0.f, a1 = 0.f;
    if (act) {
        int h = (H == 2) ? (c >> 6) : 0;
        int p0 = rowptr[node], p1 = rowptr[node + 1];
        float m = -INFINITY, s = 0.f;
        for (int p = p0; p < p1; ++p) {
            float v = eatt[(long)p * H + h];
            float mn = fmaxf(m, v);
            s = s * expf(m - mn) + expf(v - mn);
            m = mn;
        }
        float inv = (s > 0.f) ? 1.f / s : 0.f;
        for (int p = p0; p < p1; ++p) {
            float w = expf(eatt[(long)p * H + h] - m) * inv;
            U16x2 v = *(const U16x2*)&nodeh[(long)esrc[p] * COLS + c];
            a0 += b2f(v.s[0]) * w;
            a1 += b2f(v.s[1]) * w;
        }
        *(float2*)&hout[(long)node * COLS + c] = make_float2(a0, a1);
    }
    if (SOUT) {
        if (act) {
            atomicAdd(&ssum[c], a0);
            atomicAdd(&ssum[c + 1], a1);
            atomicAdd(&ssq[c], a0 * a0);
            atomicAdd(&ssq[c + 1], a1 * a1);
        }
        __syncthreads();
        float* slot = raw + (size_t)(blockIdx.x & (NSLOT - 1)) * 256;
        for (int i = tid; i < COLS; i += 256) {
            atomicAdd(&slot[i], ssum[i]);
            atomicAdd(&slot[COLS + i], ssq[i]);
        }
    }
}

// ---------------- decoder tail: prelu(bn(t3)) @ Wout + bout -> pool by graph ----------------
__global__ __launch_bounds__(256) void decoder_out_kernel(
    const u16* __restrict__ t3, const float* __restrict__ stats, const float* __restrict__ g,
    const float* __restrict__ b, const float* __restrict__ prelu, const float* __restrict__ Wout,
    const float* __restrict__ bout, const int* __restrict__ gid, float* __restrict__ pool,
    int rows, float inv_rows) {
    int tid = threadIdx.x;
    long r = (long)blockIdx.x * 4 + (tid >> 6);
    if (r >= rows) return;
    int k = tid & 63;
    float mu = stats[k] * inv_rows;
    float var = stats[64 + k] * inv_rows - mu * mu;
    float al = g[k] * rsqrtf(fmaxf(var, 0.f) + EPS);
    float be = b[k] - mu * al;
    float a = prelu[3];
    float v = al * b2f(t3[r * 64 + k]) + be;
    v = (v >= 0.f) ? v : a * v;
    v *= Wout[k];
#pragma unroll
    for (int off = 1; off < 64; off <<= 1) v += __shfl_xor(v, off, 64);
    if (k == 0) atomicAdd(&pool[gid[r]], v + bout[0]);
}

// =====================================================================================
extern "C" void kernel_launch(void* const* d_in, const int* in_sizes, int n_in, void* d_out,
                              int out_size, void* d_ws, size_t ws_size, hipStream_t stream) {
    if (n_in < 57) return;
    const int* ntype = (const int*)d_in[0];
    const int* src = (const int*)d_in[1];
    const int* dst = (const int*)d_in[2];
    const int* gid = (const int*)d_in[3];
    const float* ang_rot = (const float*)d_in[4];
    const float* ang_ref = (const float*)d_in[5];
    const float* efeats = (const float*)d_in[6];
    const float* emb = (const float*)d_in[7];
    const float* enc_W = (const float*)d_in[8];
    const float* enc_b = (const float*)d_in[9];
    const float* ee_W1 = (const float*)d_in[10];
    const float* ee_b1 = (const float*)d_in[11];
    const float* ee_W2 = (const float*)d_in[12];
    const float* ee_b2 = (const float*)d_in[13];
    const float* enc_bn1_g = (const float*)d_in[14];
    const float* enc_bn1_b = (const float*)d_in[15];
    const float* enc_bn2_g = (const float*)d_in[16];
    const float* enc_bn2_b = (const float*)d_in[17];
    const float* ee_bn1_g = (const float*)d_in[18];
    const float* ee_bn1_b = (const float*)d_in[19];
    const float* ee_bn2_g = (const float*)d_in[20];
    const float* ee_bn2_b = (const float*)d_in[21];
    const float* l0_Wnode = (const float*)d_in[22];
    const float* l0_bnode = (const float*)d_in[23];
    const float* l0_Wni = (const float*)d_in[24];
    const float* l0_Wnj = (const float*)d_in[25];
    const float* l0_Wfij = (const float*)d_in[26];
    const float* l0_attn = (const float*)d_in[27];
    const float* l0_bnn_g = (const float*)d_in[28];
    const float* l0_bnn_b = (const float*)d_in[29];
    const float* l0_bne_g = (const float*)d_in[30];
    const float* l0_bne_b = (const float*)d_in[31];
    const float* l0_Wpn = (const float*)d_in[32];
    const float* l0_bpn = (const float*)d_in[33];
    const float* l0_Wpe = (const float*)d_in[34];
    const float* l0_bpe = (const float*)d_in[35];
    const float* l1_Wnode = (const float*)d_in[36];
    const float* l1_bnode = (const float*)d_in[37];
    const float* l1_Wni = (const float*)d_in[38];
    const float* l1_Wnj = (const float*)d_in[39];
    const float* l1_Wfij = (const float*)d_in[40];
    const float* l1_attn = (const float*)d_in[41];
    const float* l1_bnn_g = (const float*)d_in[42];
    const float* l1_bnn_b = (const float*)d_in[43];
    const float* l1_Wpn = (const float*)d_in[46];
    const float* l1_bpn = (const float*)d_in[47];
    const float* dec_W = (const float*)d_in[50];
    const float* dec_b = (const float*)d_in[51];
    const float* dec_bn_g = (const float*)d_in[52];
    const float* dec_bn_b = (const float*)d_in[53];
    const float* dec_prelu = (const float*)d_in[54];
    const float* dec_Wout = (const float*)d_in[55];
    const float* dec_bout = (const float*)d_in[56];

    float* out = (float*)d_out;
    float* H1 = out;                     // N x 64 (fp32)
    float* H2 = out + (long)NN * 64;     // N x 64 (fp32)
    float* POOL = out + (long)NN * 128;  // G x 1 (fp32)

    char* base = (char*)d_ws;
    size_t off = 0;
    auto alloc = [&](size_t bytes) -> void* {
        off = (off + 255) & ~(size_t)255;
        void* p = base + off;
        off += bytes;
        return p;
    };
    u16* EH = (u16*)alloc((size_t)NE * 64 * 2);
    u16* F128 = (u16*)alloc((size_t)NE * 128 * 2);  // also node-enc temps
    float* EATT = (float*)alloc((size_t)NE * 2 * 4);
    u16* NX = (u16*)alloc((size_t)NN * 64 * 2);
    u16* NI = (u16*)alloc((size_t)NN * 128 * 2);
    u16* NJ = (u16*)alloc((size_t)NN * 128 * 2);
    u16* NHH = (u16*)alloc((size_t)NN * 128 * 2);
    float* HOUT0 = (float*)alloc((size_t)NN * 128 * 4);
    float* HOUT1 = (float*)alloc((size_t)NN * 64 * 4);
    int* ROWPTR = (int*)alloc((size_t)(NN + 1) * 4);
    int* CURS = (int*)alloc((size_t)NN * 4);
    int* ESRC = (int*)alloc((size_t)NE * 4);
    int* DSTS = (int*)alloc((size_t)NE * 4);
    float* EFP = (float*)alloc((size_t)NE * 3 * 4);
    int* BSUM = (int*)alloc((size_t)256 * 4);
    float* RWrot = (float*)alloc(256 * 4);
    float* RWref = (float*)alloc(256 * 4);
    u16* EncWT = (u16*)alloc(4096 * 2);
    u16* W2T = (u16*)alloc(4096 * 2);
    u16* Wni0T = (u16*)alloc(8192 * 2);
    u16* Wnj0T = (u16*)alloc(8192 * 2);
    u16* Wnd0T = (u16*)alloc(8192 * 2);
    u16* WfijT0 = (u16*)alloc(8192 * 2);
    u16* Wpn0T = (u16*)alloc(8192 * 2);
    u16* WpeT = (u16*)alloc(8192 * 2);
    u16* Wni1T = (u16*)alloc(4096 * 2);
    u16* Wnj1T = (u16*)alloc(4096 * 2);
    u16* Wnd1T = (u16*)alloc(4096 * 2);
    u16* WfijT1 = (u16*)alloc(4096 * 2);
    u16* Wpn1T = (u16*)alloc(4096 * 2);
    u16* DecT0 = (u16*)alloc(4096 * 2);
    u16* DecT1 = (u16*)alloc(4096 * 2);
    u16* DecT2 = (u16*)alloc(4096 * 2);
    u16* DecT3 = (u16*)alloc(4096 * 2);
    float* STATS = (float*)alloc((size_t)13 * 256 * 4);
    char* zstart = base + ((off + 255) & ~(size_t)255);
    int* DEG = (int*)alloc((size_t)NN * 4);
    float* STATS_RAW = (float*)alloc((size_t)13 * NSLOT * 256 * 4);
    float* RAWEF = (float*)alloc((size_t)NSLOT * 16 * 4);
    char* zend = base + off;
    if (ws_size < off) return;

    u16* NX0 = F128;                    // NN x 64 bf16 (node-enc temp; before layer 0)
    u16* NT = F128 + (size_t)NN * 64;   // NN x 64 bf16 (node-enc temp)
    u16* DT0 = NI;
    u16* DT1 = NJ;

    auto RAW = [&](int idx) { return STATS_RAW + (size_t)idx * NSLOT * 256; };
    float* S_enc1 = STATS + 0 * 256;
    float* S_enc2 = STATS + 1 * 256;
    float* S_ee1r = STATS + 2 * 256;
    float* S_ee2r = STATS + 3 * 256;
    float* S_ee1f = STATS + 4 * 256;
    float* S_ee2f = STATS + 5 * 256;
    float* S_bnn0 = STATS + 6 * 256;
    float* S_bne0 = STATS + 7 * 256;
    float* S_bnn1 = STATS + 8 * 256;
    float* S_d0 = STATS + 9 * 256;
    float* S_d1 = STATS + 10 * 256;
    float* S_d2 = STATS + 11 * 256;
    float* S_d3 = STATS + 12 * 256;

    const float invN = 1.f / (float)NN;
    const float invE = 1.f / (float)NE;
    const int GS = 640;
    const int MFB = NE / 64;          // 6250 (exact)
    const int NNB = (NN + 63) / 64;   // 782 (tail waves skip)
    const int NB = (NN + 255) / 256;  // scan blocks

    hipMemsetAsync(zstart, 0, (size_t)(zend - zstart), stream);
    hipMemsetAsync(POOL, 0, (size_t)NG * 4, stream);

    setup_kernel<<<1, 64, 0, stream>>>(ang_rot, ang_ref, ee_W1, RWrot, RWref);
    {
        WtJobs j;
        const float* Ws[NWT] = {enc_W,  ee_W2,  l0_Wni, l0_Wnj, l0_Wnode, l0_Wfij,
                                l0_Wpn, l0_Wpe, l1_Wni, l1_Wnj, l1_Wnode, l1_Wfij,
                                l1_Wpn, dec_W,  dec_W + 4096, dec_W + 8192, dec_W + 12288};
        u16* Ts[NWT] = {EncWT, W2T, Wni0T, Wnj0T, Wnd0T, WfijT0, Wpn0T, WpeT, Wni1T,
                        Wnj1T, Wnd1T, WfijT1, Wpn1T, DecT0, DecT1, DecT2, DecT3};
        int Ks[NWT] = {64, 64, 64, 64, 64, 64, 128, 128, 64, 64, 64, 64, 64, 64, 64, 64, 64};
        int Cs[NWT] = {64, 64, 128, 128, 128, 128, 64, 64, 64, 64, 64, 64, 64, 64, 64, 64, 64};
        for (int i = 0; i < NWT; ++i) { j.W[i] = Ws[i]; j.WT[i] = Ts[i]; j.K[i] = Ks[i]; j.C[i] = Cs[i]; }
        wt_all_kernel<<<NWT * 32, 256, 0, stream>>>(j);
    }

    // ---- CSR build (+ edge permutation into CSR order) ----
    hist_kernel<<<(NE + 255) / 256, 256, 0, stream>>>(dst, NE, DEG);
    scan_part_kernel<<<NB, 256, 0, stream>>>(DEG, BSUM, NN);
    scan_top_kernel<<<1, 256, 0, stream>>>(BSUM, NB, ROWPTR, NN, NE);
    scan_fill_kernel<<<NB, 256, 0, stream>>>(DEG, BSUM, ROWPTR, CURS, NN);
    fill_kernel<<<(NE + 255) / 256, 256, 0, stream>>>(src, dst, efeats, NE, CURS, ESRC, DSTS,
                                                      EFP);

    // ---- node encoder ----
    gather_emb_kernel<<<(NN * 8 + 255) / 256, 256, 0, stream>>>(ntype, emb, NX0, NN);
    colstats_kernel<64><<<GS, 256, 0, stream>>>(NX0, NN, RAW(0));
    finalize_stats_kernel<<<1, 256, 0, stream>>>(RAW(0), S_enc1, 128);
    mfma_mm_kernel<64, 64, true, false, true, true><<<NNB, 256, 0, stream>>>(
        NX0, EncWT, enc_b, nullptr, NT, NN, 2, S_enc1, enc_bn1_g, enc_bn1_b, invN, nullptr, 0,
        RAW(1));
    finalize_stats_kernel<<<1, 256, 0, stream>>>(RAW(1), S_enc2, 128);
    bn_act_kernel<<<(NN * 8 + 255) / 256, 256, 0, stream>>>(NT, NX, NN, 64, S_enc2, enc_bn2_g,
                                                            enc_bn2_b, invN);

    // ---- edge encoder (CSR order): analytic T1 stats, recompute-stats, recompute-merge ----
    efstats_kernel<<<256, 256, 0, stream>>>(efeats, NE, RAWEF);
    ee_stats_kernel<<<1, 128, 0, stream>>>(RAWEF, RWrot, RWref, ee_b1, S_ee1r, S_ee1f, NE);
    mfma_ee2_kernel<false><<<MFB, 256, 0, stream>>>(
        EFP, RWrot, RWref, ee_b1, W2T, ee_b2, S_ee1r, S_ee1f, nullptr, nullptr, ee_bn1_g,
        ee_bn1_b, nullptr, nullptr, nullptr, NE, invE, RAW(3), RAW(5));
    finalize_stats_kernel<<<1, 256, 0, stream>>>(RAW(3), S_ee2r, 128);
    finalize_stats_kernel<<<1, 256, 0, stream>>>(RAW(5), S_ee2f, 128);
    mfma_ee2_kernel<true><<<MFB, 256, 0, stream>>>(
        EFP, RWrot, RWref, ee_b1, W2T, ee_b2, S_ee1r, S_ee1f, S_ee2r, S_ee2f, ee_bn1_g, ee_bn1_b,
        ee_bn2_g, ee_bn2_b, EH, NE, invE, nullptr, nullptr);

    // ---- layer 0 (H=2) ----
    mfma_mm3_kernel<128, true><<<NNB, 256, 0, stream>>>(NX, Wni0T, Wnj0T, Wnd0T, l0_bnode, NI,
                                                        NJ, NHH, NN);
    mfma_egat_kernel<128, true, true><<<MFB, 256, 0, stream>>>(
        EH, WfijT0, NI, NJ, ESRC, DSTS, l0_attn, F128, EATT, NE, RAW(7));
    finalize_stats_kernel<<<1, 256, 0, stream>>>(RAW(7), S_bne0, 256);
    csr_aggregate_kernel<128, true><<<(NN + 3) / 4, 256, 0, stream>>>(ROWPTR, ESRC, EATT, NHH,
                                                                      HOUT0, NN, RAW(6));
    finalize_stats_kernel<<<1, 256, 0, stream>>>(RAW(6), S_bnn0, 256);
    mfma_mm_kernel<128, 64, false, true, false, false><<<NNB, 256, 0, stream>>>(
        HOUT0, Wpn0T, l0_bpn, NX, H1, NN, 1, S_bnn0, l0_bnn_g, l0_bnn_b, invN, nullptr, 0,
        nullptr);
    mfma_pe_kernel<<<MFB, 256, 0, stream>>>(F128, WpeT, l0_bpe, EH, NE, S_bne0, l0_bne_g,
                                            l0_bne_b, invE);

    // ---- layer 1 (H=1; edge output dead -> skipped) ----
    mfma_mm3_kernel<64, false><<<NNB, 256, 0, stream>>>(H1, Wni1T, Wnj1T, Wnd1T, l1_bnode, NI,
                                                        NJ, NHH, NN);
    mfma_egat_kernel<64, false, false><<<MFB, 256, 0, stream>>>(
        EH, WfijT1, NI, NJ, ESRC, DSTS, l1_attn, nullptr, EATT, NE, nullptr);
    csr_aggregate_kernel<64, true><<<(NN + 7) / 8, 256, 0, stream>>>(ROWPTR, ESRC, EATT, NHH,
                                                                     HOUT1, NN, RAW(8));
    finalize_stats_kernel<<<1, 256, 0, stream>>>(RAW(8), S_bnn1, 128);
    mfma_mm_kernel<64, 64, false, false, false, false><<<NNB, 256, 0, stream>>>(
        HOUT1, Wpn1T, l1_bpn, H1, H2, NN, 1, S_bnn1, l1_bnn_g, l1_bnn_b, invN, nullptr, 0,
        nullptr);

    // ---- decoder ----
    mfma_mm_kernel<64, 64, false, false, true, true><<<NNB, 256, 0, stream>>>(
        H2, DecT0, dec_b, nullptr, DT0, NN, 0, nullptr, nullptr, nullptr, 0.f, nullptr, 0,
        RAW(9));
    finalize_stats_kernel<<<1, 256, 0, stream>>>(RAW(9), S_d0, 128);
    mfma_mm_kernel<64, 64, true, false, true, true><<<NNB, 256, 0, stream>>>(
        DT0, DecT1, dec_b + 64, nullptr, DT1, NN, 3, S_d0, dec_bn_g, dec_bn_b, invN, dec_prelu,
        0, RAW(10));
    finalize_stats_kernel<<<1, 256, 0, stream>>>(RAW(10), S_d1, 128);
    mfma_mm_kernel<64, 64, true, false, true, true><<<NNB, 256, 0, stream>>>(
        DT1, DecT2, dec_b + 128, nullptr, DT0, NN, 3, S_d1, dec_bn_g + 64, dec_bn_b + 64, invN,
        dec_prelu, 1, RAW(11));
    finalize_stats_kernel<<<1, 256, 0, stream>>>(RAW(11), S_d2, 128);
    mfma_mm_kernel<64, 64, true, false, true, true><<<NNB, 256, 0, stream>>>(
        DT0, DecT3, dec_b + 192, nullptr, DT1, NN, 3, S_d2, dec_bn_g + 128, dec_bn_b + 128,
        invN, dec_prelu, 2, RAW(12));
    finalize_stats_kernel<<<1, 256, 0, stream>>>(RAW(12), S_d3, 128);
    decoder_out_kernel<<<(NN + 3) / 4, 256, 0, stream>>>(DT1, S_d3, dec_bn_g + 192,
                                                         dec_bn_b + 192, dec_prelu, dec_Wout,
                                                         dec_bout, gid, POOL, NN, invN);
}

// Round 13
// 809.860 us; speedup vs baseline: 1.2170x; 1.0674x over previous
//
#include <hip/hip_runtime.h>
#include <math.h>

#define NN 50000
#define NE 400000
#define NG 512
#define EPS 1e-5f
#define NSLOT 64  // stats replica slots (atomic contention spreading)

typedef unsigned int u32;
typedef unsigned short u16;

typedef __attribute__((ext_vector_type(8))) short s16x8;  // 8 bf16 (4 VGPRs)
typedef __attribute__((ext_vector_type(4))) float f32x4;

__device__ __forceinline__ float b2f(u16 h) { return __uint_as_float(((u32)h) << 16); }
__device__ __forceinline__ u16 f2b(float f) {
    u32 x = __float_as_uint(f);
    u32 r = x + 0x7fffu + ((x >> 16) & 1u);
    return (u16)(r >> 16);
}
struct alignas(16) U16x8 { u16 s[8]; };
struct alignas(8) U16x4 { u16 s[4]; };
struct alignas(4) U16x2 { u16 s[2]; };

__device__ __forceinline__ void f4add(float4& a, const float4 b) {
    a.x += b.x; a.y += b.y; a.z += b.z; a.w += b.w;
}

// bijective XCD swizzle (guide T1, m204)
__device__ __forceinline__ int xcd_swizzle(int orig, int nwg) {
    int xcd = orig & 7;
    int q = nwg >> 3, r = nwg & 7;
    return (xcd < r ? xcd * (q + 1) : r * (q + 1) + (xcd - r) * q) + (orig >> 3);
}

// ---------------- setup: fold rotation matrices into ee_W1 (fp32) ----------------
__global__ void setup_kernel(const float* __restrict__ ang_rot, const float* __restrict__ ang_ref,
                             const float* __restrict__ W1, float* __restrict__ RWrot,
                             float* __restrict__ RWref) {
    int c = threadIdx.x;  // 64
    for (int which = 0; which < 2; ++which) {
        const float* a = which ? ang_ref : ang_rot;
        float t = a[0], p = a[1], q = a[2];
        float ct = cosf(t), st = sinf(t);
        float cp = cosf(p), sp = sinf(p);
        float cq = cosf(q), sq = sinf(q);
        float Rt[3][3] = {{ct, -st, 0.f}, {st, ct, 0.f}, {0.f, 0.f, 1.f}};
        float Rp[3][3] = {{cp, 0.f, -sp}, {0.f, 1.f, 0.f}, {sp, 0.f, cp}};
        float Rq[3][3] = {{1.f, 0.f, 0.f}, {0.f, cq, -sq}, {0.f, sq, cq}};
        float Rtp[3][3], R[3][3];
        for (int i = 0; i < 3; ++i)
            for (int j = 0; j < 3; ++j) {
                float s = 0.f;
                for (int k = 0; k < 3; ++k) s += Rt[i][k] * Rp[k][j];
                Rtp[i][j] = s;
            }
        for (int i = 0; i < 3; ++i)
            for (int j = 0; j < 3; ++j) {
                float s = 0.f;
                for (int k = 0; k < 3; ++k) s += Rtp[i][k] * Rq[k][j];
                R[i][j] = s;
            }
        float sgn = which ? -1.f : 1.f;  // R_ref = -rotmat(angles_ref)
        float* RW = which ? RWref : RWrot;
        if (c < 64) {
            for (int j = 0; j < 3; ++j) {
                float s = 0.f;
                for (int m = 0; m < 3; ++m) s += sgn * R[j][m] * W1[m * 64 + c];
                RW[j * 64 + c] = s;  // RW = R @ W1  (3 x 64)
            }
        }
    }
}

// ---------------- batched weight transpose: W [K][C] fp32 -> WT [C][K] bf16 ----------------
#define NWT 17
struct WtJobs {
    const float* W[NWT];
    u16* WT[NWT];
    int K[NWT];
    int C[NWT];
};
__global__ __launch_bounds__(256) void wt_all_kernel(WtJobs jobs) {
    int job = blockIdx.x >> 5;
    int idx = ((blockIdx.x & 31) << 8) + threadIdx.x;
    int K = jobs.K[job], C = jobs.C[job];
    if (idx >= K * C) return;
    int k = idx / C, c = idx - k * C;
    jobs.WT[job][c * K + k] = f2b(jobs.W[job][idx]);
}

// ---------------- CSR build: degree hist -> 3-phase scan -> fill ----------------
__global__ __launch_bounds__(256) void hist_kernel(const int* __restrict__ dst, int E,
                                                   int* __restrict__ deg) {
    int e = blockIdx.x * 256 + threadIdx.x;
    if (e < E) atomicAdd(&deg[dst[e]], 1);
}

__global__ __launch_bounds__(256) void scan_part_kernel(const int* __restrict__ deg,
                                                        int* __restrict__ bsum, int n) {
    int i = blockIdx.x * 256 + threadIdx.x;
    int v = (i < n) ? deg[i] : 0;
#pragma unroll
    for (int off = 1; off < 64; off <<= 1) v += __shfl_xor(v, off, 64);
    __shared__ int ws[4];
    if ((threadIdx.x & 63) == 0) ws[threadIdx.x >> 6] = v;
    __syncthreads();
    if (threadIdx.x == 0) bsum[blockIdx.x] = ws[0] + ws[1] + ws[2] + ws[3];
}

__global__ __launch_bounds__(256) void scan_top_kernel(int* __restrict__ bsum, int nb,
                                                       int* __restrict__ rowptr, int n,
                                                       int total) {
    __shared__ int s[256];
    int tid = threadIdx.x;
    s[tid] = (tid < nb) ? bsum[tid] : 0;
    __syncthreads();
    for (int off = 1; off < 256; off <<= 1) {
        int v = (tid >= off) ? s[tid - off] : 0;
        __syncthreads();
        s[tid] += v;
        __syncthreads();
    }
    if (tid < nb) bsum[tid] = (tid == 0) ? 0 : s[tid - 1];
    if (tid == 0) rowptr[n] = total;
}

__global__ __launch_bounds__(256) void scan_fill_kernel(const int* __restrict__ deg,
                                                        const int* __restrict__ bsum,
                                                        int* __restrict__ rowptr,
                                                        int* __restrict__ curs, int n) {
    __shared__ int s[256];
    int tid = threadIdx.x;
    int i = blockIdx.x * 256 + tid;
    int v = (i < n) ? deg[i] : 0;
    s[tid] = v;
    __syncthreads();
    for (int off = 1; off < 256; off <<= 1) {
        int t = (tid >= off) ? s[tid - off] : 0;
        __syncthreads();
        s[tid] += t;
        __syncthreads();
    }
    if (i < n) {
        int excl = s[tid] - v + bsum[blockIdx.x];
        rowptr[i] = excl;
        curs[i] = excl;
    }
}

// fill: scatter edges into CSR slots; emit permuted src/dst/efeats (CSR order everywhere after)
__global__ __launch_bounds__(256) void fill_kernel(const int* __restrict__ src,
                                                   const int* __restrict__ dst,
                                                   const float* __restrict__ ef, int E,
                                                   int* __restrict__ curs,
                                                   int* __restrict__ esrc,
                                                   int* __restrict__ dsts,
                                                   float* __restrict__ efp) {
    int e = blockIdx.x * 256 + threadIdx.x;
    if (e >= E) return;
    int d = dst[e];
    int pos = atomicAdd(&curs[d], 1);
    esrc[pos] = src[e];
    dsts[pos] = d;
    efp[(long)pos * 3 + 0] = ef[(long)e * 3 + 0];
    efp[(long)pos * 3 + 1] = ef[(long)e * 3 + 1];
    efp[(long)pos * 3 + 2] = ef[(long)e * 3 + 2];
}

// ---------------- embedding gather: fp32 table -> bf16 out, fused col-stats ----------------
__global__ __launch_bounds__(256) void gather_emb_kernel(const int* __restrict__ ntype,
                                                         const float* __restrict__ emb,
                                                         u16* __restrict__ out, int n,
                                                         float* __restrict__ raw) {
    __shared__ float ssum[64], ssq[64];
    int tid = threadIdx.x;
    if (tid < 64) { ssum[tid] = 0.f; ssq[tid] = 0.f; }
    __syncthreads();
    long i = (long)blockIdx.x * 256 + tid;  // over n*8
    long e = i >> 3;
    int c0 = (int)(i & 7) * 8;
    float v[8];
    bool act = e < n;
    if (act) {
        int t = ntype[e];
        float4 a = *(const float4*)&emb[(long)t * 64 + c0];
        float4 b = *(const float4*)&emb[(long)t * 64 + c0 + 4];
        v[0] = a.x; v[1] = a.y; v[2] = a.z; v[3] = a.w;
        v[4] = b.x; v[5] = b.y; v[6] = b.z; v[7] = b.w;
        U16x8 o;
#pragma unroll
        for (int j = 0; j < 8; ++j) o.s[j] = f2b(v[j]);
        *(U16x8*)&out[e * 64 + c0] = o;
    } else {
#pragma unroll
        for (int j = 0; j < 8; ++j) v[j] = 0.f;
    }
    float q[8];
#pragma unroll
    for (int j = 0; j < 8; ++j) q[j] = v[j] * v[j];
    // reduce across the 8 rows within each wave (lanes stride 8 share col group)
#pragma unroll
    for (int off = 8; off < 64; off <<= 1)
#pragma unroll
        for (int j = 0; j < 8; ++j) {
            v[j] += __shfl_xor(v[j], off, 64);
            q[j] += __shfl_xor(q[j], off, 64);
        }
    if ((tid & 63) < 8) {
        int c = (tid & 7) * 8;
#pragma unroll
        for (int j = 0; j < 8; ++j) {
            atomicAdd(&ssum[c + j], v[j]);
            atomicAdd(&ssq[c + j], q[j]);
        }
    }
    __syncthreads();
    if (tid < 64) {
        float* slot = raw + (size_t)(blockIdx.x & (NSLOT - 1)) * 256;
        atomicAdd(&slot[tid], ssum[tid]);
        atomicAdd(&slot[64 + tid], ssq[tid]);
    }
}

// ---------------- efeats second moments: 9 scalars -> replica slots ----------------
__global__ __launch_bounds__(256) void efstats_kernel(const float* __restrict__ ef, int E,
                                                      float* __restrict__ raw) {
    int tid = threadIdx.x;
    float a[9];
#pragma unroll
    for (int j = 0; j < 9; ++j) a[j] = 0.f;
    for (long e = (long)blockIdx.x * 256 + tid; e < E; e += (long)gridDim.x * 256) {
        float f0 = ef[e * 3 + 0], f1 = ef[e * 3 + 1], f2 = ef[e * 3 + 2];
        a[0] += f0; a[1] += f1; a[2] += f2;
        a[3] += f0 * f0; a[4] += f1 * f1; a[5] += f2 * f2;
        a[6] += f0 * f1; a[7] += f0 * f2; a[8] += f1 * f2;
    }
#pragma unroll
    for (int off = 1; off < 64; off <<= 1)
#pragma unroll
        for (int j = 0; j < 9; ++j) a[j] += __shfl_xor(a[j], off, 64);
    __shared__ float sred[4][9];
    int wv = tid >> 6, ln = tid & 63;
    if (ln == 0)
#pragma unroll
        for (int j = 0; j < 9; ++j) sred[wv][j] = a[j];
    __syncthreads();
    if (tid < 9) {
        float v = sred[0][tid] + sred[1][tid] + sred[2][tid] + sred[3][tid];
        atomicAdd(&raw[(size_t)(blockIdx.x & (NSLOT - 1)) * 16 + tid], v);
    }
}

// ---------------- analytic T1 column stats for both branches ----------------
__global__ void ee_stats_kernel(const float* __restrict__ efraw, const float* __restrict__ RWrot,
                                const float* __restrict__ RWref, const float* __restrict__ b1,
                                float* __restrict__ S_rot, float* __restrict__ S_ref, int E) {
    __shared__ float m[9];
    int t = threadIdx.x;  // 128
    if (t < 9) {
        float s = 0.f;
        for (int r = 0; r < NSLOT; ++r) s += efraw[r * 16 + t];
        m[t] = s;
    }
    __syncthreads();
    int br = t >> 6, c = t & 63;
    const float* RW = br ? RWref : RWrot;
    float* S = br ? S_ref : S_rot;
    float w0 = RW[c], w1 = RW[64 + c], w2 = RW[128 + c];
    float bb = b1[c];
    float mw = m[0] * w0 + m[1] * w1 + m[2] * w2;
    float sum = mw + (float)E * bb;
    float quad = m[3] * w0 * w0 + m[4] * w1 * w1 + m[5] * w2 * w2 +
                 2.f * (m[6] * w0 * w1 + m[7] * w0 * w2 + m[8] * w1 * w2);
    float ss = quad + 2.f * bb * mw + (float)E * bb * bb;
    S[c] = sum;
    S[64 + c] = ss;
}

// ---------------- reduce NSLOT replica slots -> final stats ----------------
__global__ __launch_bounds__(256) void finalize_stats_kernel(const float* __restrict__ raw,
                                                             float* __restrict__ stats, int n) {
    int i = threadIdx.x;
    if (i >= n) return;
    float s = 0.f;
    for (int r = 0; r < NSLOT; ++r) s += raw[r * 256 + i];
    stats[i] = s;
}

// ---------------- y = relu(bn(x)), bf16 (node-enc bn2) ----------------
__global__ __launch_bounds__(256) void bn_act_kernel(const u16* __restrict__ x,
                                                     u16* __restrict__ y, long rows, int cols,
                                                     const float* __restrict__ acc,
                                                     const float* __restrict__ g,
                                                     const float* __restrict__ b,
                                                     float inv_rows) {
    long i = (long)blockIdx.x * 256 + threadIdx.x;
    long total8 = rows * (long)cols / 8;
    if (i >= total8) return;
    long base = i * 8;
    int c0 = (int)(base % cols);
    U16x8 xv = *(const U16x8*)&x[base];
    U16x8 o;
#pragma unroll
    for (int j = 0; j < 8; ++j) {
        int c = c0 + j;
        float mu = acc[c] * inv_rows;
        float var = acc[cols + c] * inv_rows - mu * mu;
        float al = g[c] * rsqrtf(fmaxf(var, 0.f) + EPS);
        float be = b[c] - mu * al;
        o.s[j] = f2b(fmaxf(al * b2f(xv.s[j]) + be, 0.f));
    }
    *(U16x8*)&y[base] = o;
}

// ================= MFMA kernels =================
// Fragment layout (guide §3, m89/m91/m92 verified):
//   A: lane l holds A[row=l&15][k=(l>>4)*8+j]
//   B: lane l holds B[k=(l>>4)*8+j][col=l&15]  (8 contiguous bf16 from W^T row)
//   D: lane l reg r holds D[row=(l>>4)*4+r][col=l&15]
// Block = 4 waves = 64 rows. NE%64==0; NN%16==0 (tail waves skip).

// ---- generic: Y = preop(X) @ W (+bias)(+res), optional fused col-stats ----
template <int K, int COLS, bool XBF, bool RBF, bool OBF, bool SOUT>
__global__ __launch_bounds__(256) void mfma_mm_kernel(
    const void* __restrict__ Xv, const u16* __restrict__ WT, const float* __restrict__ bias,
    const void* __restrict__ resv, void* __restrict__ Yv, int rows, int preop,
    const float* __restrict__ stats, const float* __restrict__ g, const float* __restrict__ b,
    float inv_rows, const float* __restrict__ prelu, int prelu_idx, float* __restrict__ raw) {
    constexpr int NCT = COLS / 16;
    constexpr int NKK = K / 32;
    __shared__ float al[K], be[K];
    __shared__ float ssum[SOUT ? COLS : 1], ssq[SOUT ? COLS : 1];
    const int tid = threadIdx.x;
    if (preop) {
        for (int k = tid; k < K; k += 256) {
            float mu = stats[k] * inv_rows;
            float var = stats[K + k] * inv_rows - mu * mu;
            float a = g[k] * rsqrtf(fmaxf(var, 0.f) + EPS);
            al[k] = a;
            be[k] = b[k] - mu * a;
        }
    }
    if (SOUT) {
        for (int i = tid; i < COLS; i += 256) { ssum[i] = 0.f; ssq[i] = 0.f; }
    }
    __syncthreads();
    const int lane = tid & 63, wv = tid >> 6;
    const int q = lane >> 4, rr = lane & 15;
    const long r0 = ((long)blockIdx.x * 4 + wv) * 16;
    const bool act = r0 < rows;
    const float pa = (preop == 3) ? prelu[prelu_idx] : 0.f;
    s16x8 afr[NKK];
    if (act) {
#pragma unroll
        for (int kk = 0; kk < NKK; ++kk) {
            float v[8];
            if (XBF) {
                U16x8 t = *(const U16x8*)((const u16*)Xv + (r0 + rr) * K + kk * 32 + q * 8);
#pragma unroll
                for (int j = 0; j < 8; ++j) v[j] = b2f(t.s[j]);
            } else {
                const float* xp = (const float*)Xv + (r0 + rr) * K + kk * 32 + q * 8;
                float4 t0 = *(const float4*)xp;
                float4 t1 = *(const float4*)(xp + 4);
                v[0] = t0.x; v[1] = t0.y; v[2] = t0.z; v[3] = t0.w;
                v[4] = t1.x; v[5] = t1.y; v[6] = t1.z; v[7] = t1.w;
            }
            union { u16 u[8]; s16x8 s; } o;
#pragma unroll
            for (int j = 0; j < 8; ++j) {
                float xx = v[j];
                if (preop) {
                    int k = kk * 32 + q * 8 + j;
                    xx = al[k] * xx + be[k];
                    if (preop == 2) xx = fmaxf(xx, 0.f);
                    else if (preop == 3) xx = (xx >= 0.f) ? xx : pa * xx;
                }
                o.u[j] = f2b(xx);
            }
            afr[kk] = o.s;
        }
#pragma unroll
        for (int ct = 0; ct < NCT; ++ct) {
            f32x4 acc = (f32x4){0.f, 0.f, 0.f, 0.f};
#pragma unroll
            for (int kk = 0; kk < NKK; ++kk) {
                s16x8 bfr = *(const s16x8*)&WT[(size_t)(ct * 16 + rr) * K + kk * 32 + q * 8];
                acc = __builtin_amdgcn_mfma_f32_16x16x32_bf16(afr[kk], bfr, acc, 0, 0, 0);
            }
            int col = ct * 16 + rr;
            float bb = bias ? bias[col] : 0.f;
            float fs = 0.f, fq = 0.f;
#pragma unroll
            for (int r = 0; r < 4; ++r) {
                long orr = r0 + q * 4 + r;
                float vv = acc[r] + bb;
                if (resv) {
                    if (RBF) vv += b2f(((const u16*)resv)[orr * COLS + col]);
                    else vv += ((const float*)resv)[orr * COLS + col];
                }
                if (OBF) ((u16*)Yv)[orr * COLS + col] = f2b(vv);
                else ((float*)Yv)[orr * COLS + col] = vv;
                if (SOUT) { fs += vv; fq += vv * vv; }
            }
            if (SOUT) {
                fs += __shfl_xor(fs, 16, 64); fs += __shfl_xor(fs, 32, 64);
                fq += __shfl_xor(fq, 16, 64); fq += __shfl_xor(fq, 32, 64);
                if (q == 0) {
                    atomicAdd(&ssum[col], fs);
                    atomicAdd(&ssq[col], fq);
                }
            }
        }
    }
    if (SOUT) {
        __syncthreads();
        float* slot = raw + (size_t)(blockIdx.x & (NSLOT - 1)) * 256;
        for (int i = tid; i < COLS; i += 256) {
            atomicAdd(&slot[i], ssum[i]);
            atomicAdd(&slot[COLS + i], ssq[i]);
        }
    }
}

// ---- 3 matmuls sharing the A operand: Y0 = X@W0, Y1 = X@W1, Y2 = X@W2 + bias2 ----
template <int COLS, bool XBF>
__global__ __launch_bounds__(256) void mfma_mm3_kernel(
    const void* __restrict__ Xv, const u16* __restrict__ WT0, const u16* __restrict__ WT1,
    const u16* __restrict__ WT2, const float* __restrict__ bias2, u16* __restrict__ Y0,
    u16* __restrict__ Y1, u16* __restrict__ Y2, int rows) {
    constexpr int NCT = COLS / 16;
    const int tid = threadIdx.x;
    const int lane = tid & 63, wv = tid >> 6;
    const int q = lane >> 4, rr = lane & 15;
    const long r0 = ((long)blockIdx.x * 4 + wv) * 16;
    if (r0 >= rows) return;
    s16x8 afr[2];
#pragma unroll
    for (int kk = 0; kk < 2; ++kk) {
        if (XBF) {
            afr[kk] = *(const s16x8*)((const u16*)Xv + (r0 + rr) * 64 + kk * 32 + q * 8);
        } else {
            const float* xp = (const float*)Xv + (r0 + rr) * 64 + kk * 32 + q * 8;
            float4 t0 = *(const float4*)xp;
            float4 t1 = *(const float4*)(xp + 4);
            union { u16 u[8]; s16x8 s; } o;
            o.u[0] = f2b(t0.x); o.u[1] = f2b(t0.y); o.u[2] = f2b(t0.z); o.u[3] = f2b(t0.w);
            o.u[4] = f2b(t1.x); o.u[5] = f2b(t1.y); o.u[6] = f2b(t1.z); o.u[7] = f2b(t1.w);
            afr[kk] = o.s;
        }
    }
    const u16* wts[3] = {WT0, WT1, WT2};
    u16* ys[3] = {Y0, Y1, Y2};
#pragma unroll
    for (int m = 0; m < 3; ++m) {
#pragma unroll
        for (int ct = 0; ct < NCT; ++ct) {
            f32x4 acc = (f32x4){0.f, 0.f, 0.f, 0.f};
#pragma unroll
            for (int kk = 0; kk < 2; ++kk) {
                s16x8 bfr = *(const s16x8*)&wts[m][(size_t)(ct * 16 + rr) * 64 + kk * 32 + q * 8];
                acc = __builtin_amdgcn_mfma_f32_16x16x32_bf16(afr[kk], bfr, acc, 0, 0, 0);
            }
            int col = ct * 16 + rr;
            float bb = (m == 2) ? bias2[col] : 0.f;
#pragma unroll
            for (int r = 0; r < 4; ++r) {
                long orr = r0 + q * 4 + r;
                ys[m][orr * COLS + col] = f2b(acc[r] + bb);
            }
        }
    }
}

// ---- edge encoder, both branches, in-register from 3 floats/row ----
// STORE=false: emit T2 col-stats only (rawA/rawB). STORE=true: EH = relu(bn2a(T2a)) + relu(bn2b(T2b)).
template <bool STORE>
__global__ __launch_bounds__(256) void mfma_ee2_kernel(
    const float* __restrict__ efp, const float* __restrict__ RWrot,
    const float* __restrict__ RWref, const float* __restrict__ b1v, const u16* __restrict__ W2T,
    const float* __restrict__ b2, const float* __restrict__ S1r, const float* __restrict__ S1f,
    const float* __restrict__ S2r, const float* __restrict__ S2f, const float* __restrict__ g1,
    const float* __restrict__ bn1b, const float* __restrict__ g2, const float* __restrict__ bn2b,
    u16* __restrict__ EH, int E, float inv_rows, float* __restrict__ rawA,
    float* __restrict__ rawB) {
    constexpr int ESTR = 72;  // padded u16 stride for EH staging
    __shared__ float rws[2][192];
    __shared__ float al1[2][64], be1[2][64];
    __shared__ float al2[2][64], be2[2][64];
    __shared__ float ssum[2][64], ssq[2][64];
    __shared__ u16 ets[STORE ? 64 * ESTR : 1];
    const int tid = threadIdx.x;
    if (tid < 192) {
        rws[0][tid] = RWrot[tid];
        rws[1][tid] = RWref[tid];
    }
    if (tid < 128) {
        int br = tid >> 6, k = tid & 63;
        const float* S1 = br ? S1f : S1r;
        float mu = S1[k] * inv_rows;
        float var = S1[64 + k] * inv_rows - mu * mu;
        float a = g1[k] * rsqrtf(fmaxf(var, 0.f) + EPS);
        al1[br][k] = a;
        be1[br][k] = bn1b[k] - mu * a + a * b1v[k];  // fold b1
        if (STORE) {
            const float* S2 = br ? S2f : S2r;
            mu = S2[k] * inv_rows;
            var = S2[64 + k] * inv_rows - mu * mu;
            a = g2[k] * rsqrtf(fmaxf(var, 0.f) + EPS);
            al2[br][k] = a;
            be2[br][k] = bn2b[k] - mu * a + a * b2[k];  // fold b2
        } else {
            ssum[br][k] = 0.f;
            ssq[br][k] = 0.f;
        }
    }
    __syncthreads();
    const int lane = tid & 63, wv = tid >> 6;
    const int q = lane >> 4, rr = lane & 15;
    const long r0 = ((long)blockIdx.x * 4 + wv) * 16;
    const long ar = r0 + rr;
    float e0 = efp[ar * 3], e1 = efp[ar * 3 + 1], e2 = efp[ar * 3 + 2];
    float v0[4][4];  // branch-0 post-bn2 values (STORE path)
#pragma unroll
    for (int br = 0; br < 2; ++br) {
        s16x8 afr[2];
#pragma unroll
        for (int kk = 0; kk < 2; ++kk) {
            union { u16 u[8]; s16x8 v; } t;
#pragma unroll
            for (int j = 0; j < 8; ++j) {
                int k = kk * 32 + q * 8 + j;
                float tv = e0 * rws[br][k] + e1 * rws[br][64 + k] + e2 * rws[br][128 + k];
                t.u[j] = f2b(fmaxf(al1[br][k] * tv + be1[br][k], 0.f));
            }
            afr[kk] = t.v;
        }
#pragma unroll
        for (int ct = 0; ct < 4; ++ct) {
            f32x4 acc = (f32x4){0.f, 0.f, 0.f, 0.f};
#pragma unroll
            for (int kk = 0; kk < 2; ++kk) {
                s16x8 bfr = *(const s16x8*)&W2T[(size_t)(ct * 16 + rr) * 64 + kk * 32 + q * 8];
                acc = __builtin_amdgcn_mfma_f32_16x16x32_bf16(afr[kk], bfr, acc, 0, 0, 0);
            }
            int col = ct * 16 + rr;
            if (STORE) {
#pragma unroll
                for (int r = 0; r < 4; ++r) {
                    float v = fmaxf(al2[br][col] * acc[r] + be2[br][col], 0.f);
                    if (br == 0) {
                        v0[ct][r] = v;
                    } else {
                        ets[(wv * 16 + q * 4 + r) * ESTR + col] = f2b(v0[ct][r] + v);
                    }
                }
            } else {
                float bb = b2[col];
                float s = 0.f, qq = 0.f;
#pragma unroll
                for (int r = 0; r < 4; ++r) {
                    float v = acc[r] + bb;
                    s += v;
                    qq += v * v;
                }
                s += __shfl_xor(s, 16, 64); s += __shfl_xor(s, 32, 64);
                qq += __shfl_xor(qq, 16, 64); qq += __shfl_xor(qq, 32, 64);
                if (q == 0) {
                    atomicAdd(&ssum[br][col], s);
                    atomicAdd(&ssq[br][col], qq);
                }
            }
        }
    }
    __syncthreads();
    if (STORE) {
        const long rb = (long)blockIdx.x * 64;
        for (int i = tid; i < 64 * 8; i += 256) {
            int row = i >> 3, c8 = i & 7;
            U16x8 v = *(const U16x8*)&ets[row * ESTR + c8 * 8];
            *(U16x8*)&EH[(rb + row) * 64 + c8 * 8] = v;
        }
    } else {
        if (tid < 128) {
            int br = tid >> 6, k = tid & 63;
            float* slot = (br ? rawB : rawA) + (size_t)(blockIdx.x & (NSLOT - 1)) * 256;
            atomicAdd(&slot[k], ssum[br][k]);
            atomicAdd(&slot[64 + k], ssq[br][k]);
        }
    }
}

// ---- f = leaky(EH@Wfij + NI[src] + NJ[dst]); att scores (CSR order); opt F store + col-stats ----
// Single-phase (high-MLP scalar gathers) + bijective XCD swizzle.
template <int COLS, bool WRITE_F, bool SOUT>
__global__ __launch_bounds__(256) void mfma_egat_kernel(
    const u16* __restrict__ EH, const u16* __restrict__ WT, const u16* __restrict__ NI,
    const u16* __restrict__ NJ, const int* __restrict__ srcs, const int* __restrict__ dsts,
    const float* __restrict__ attn, u16* __restrict__ Fout, float* __restrict__ eatt, int E,
    float* __restrict__ raw) {
    constexpr int H = COLS / 64;
    constexpr int NCT = COLS / 16;
    constexpr int FSTR = COLS + 8;  // padded LDS row stride
    __shared__ float ssum[SOUT ? COLS : 1];
    __shared__ float ssq[SOUT ? COLS : 1];
    __shared__ u16 fts[WRITE_F ? 64 * FSTR : 1];
    const int tid = threadIdx.x;
    if (SOUT) {
        for (int i = tid; i < COLS; i += 256) { ssum[i] = 0.f; ssq[i] = 0.f; }
        __syncthreads();
    }
    const int bid = xcd_swizzle(blockIdx.x, gridDim.x);
    const int lane = tid & 63, wv = tid >> 6;
    const int q = lane >> 4, rr = lane & 15;
    const long r0 = ((long)bid * 4 + wv) * 16;
    s16x8 afr[2];
#pragma unroll
    for (int kk = 0; kk < 2; ++kk)
        afr[kk] = *(const s16x8*)&EH[(r0 + rr) * 64 + kk * 32 + q * 8];
    int sidx[4], didx[4];
#pragma unroll
    for (int r = 0; r < 4; ++r) {
        long orr = r0 + q * 4 + r;
        sidx[r] = srcs[orr];
        didx[r] = dsts[orr];
    }
    f32x4 acc[NCT];
#pragma unroll
    for (int ct = 0; ct < NCT; ++ct) {
        acc[ct] = (f32x4){0.f, 0.f, 0.f, 0.f};
#pragma unroll
        for (int kk = 0; kk < 2; ++kk) {
            s16x8 bfr = *(const s16x8*)&WT[(size_t)(ct * 16 + rr) * 64 + kk * 32 + q * 8];
            acc[ct] = __builtin_amdgcn_mfma_f32_16x16x32_bf16(afr[kk], bfr, acc[ct], 0, 0, 0);
        }
    }
    float part[H][4];
#pragma unroll
    for (int h = 0; h < H; ++h)
#pragma unroll
        for (int r = 0; r < 4; ++r) part[h][r] = 0.f;
#pragma unroll
    for (int ct = 0; ct < NCT; ++ct) {
        int col = ct * 16 + rr;
        float av = attn[col];
        const int h = (H == 2) ? (ct >> 2) : 0;
        float fs = 0.f, fq = 0.f;
#pragma unroll
        for (int r = 0; r < 4; ++r) {
            float f = acc[ct][r] + b2f(NI[(size_t)sidx[r] * COLS + col]) +
                      b2f(NJ[(size_t)didx[r] * COLS + col]);
            f = (f >= 0.f) ? f : 0.01f * f;
            if (WRITE_F) fts[(wv * 16 + q * 4 + r) * FSTR + col] = f2b(f);
            part[h][r] += f * av;
            if (SOUT) { fs += f; fq += f * f; }
        }
        if (SOUT) {
            fs += __shfl_xor(fs, 16, 64); fs += __shfl_xor(fs, 32, 64);
            fq += __shfl_xor(fq, 16, 64); fq += __shfl_xor(fq, 32, 64);
            if (q == 0) {
                atomicAdd(&ssum[col], fs);
                atomicAdd(&ssq[col], fq);
            }
        }
    }
#pragma unroll
    for (int h = 0; h < H; ++h)
#pragma unroll
        for (int r = 0; r < 4; ++r) {
            float p = part[h][r];
            p += __shfl_xor(p, 1, 64);
            p += __shfl_xor(p, 2, 64);
            p += __shfl_xor(p, 4, 64);
            p += __shfl_xor(p, 8, 64);
            part[h][r] = p;
        }
    if (rr == 0) {
#pragma unroll
        for (int r = 0; r < 4; ++r) {
            long pos = r0 + q * 4 + r;
            if (H == 2) {
                eatt[pos * 2 + 0] = part[0][r];
                eatt[pos * 2 + 1] = part[1][r];
            } else {
                eatt[pos] = part[0][r];
            }
        }
    }
    if (WRITE_F) {
        __syncthreads();
        const long rb = (long)bid * 64;
        constexpr int CH = COLS / 8;
        for (int i = tid; i < 64 * CH; i += 256) {
            int row = i / CH, c8 = i % CH;
            U16x8 v = *(const U16x8*)&fts[row * FSTR + c8 * 8];
            *(U16x8*)&Fout[(rb + row) * COLS + c8 * 8] = v;
        }
    }
    if (SOUT) {
        __syncthreads();
        float* slot = raw + (size_t)(blockIdx.x & (NSLOT - 1)) * 256;
        for (int i = tid; i < COLS; i += 256) {
            atomicAdd(&slot[i], ssum[i]);
            atomicAdd(&slot[COLS + i], ssq[i]);
        }
    }
}

// ---- EH = bn(F128)@Wpe + bpe + EH (K=128, streaming; coalesced residual epilogue) ----
__global__ __launch_bounds__(256) void mfma_pe_kernel(
    const u16* __restrict__ X, const u16* __restrict__ WT, const float* __restrict__ bias,
    u16* __restrict__ EHio, int E, const float* __restrict__ stats, const float* __restrict__ g,
    const float* __restrict__ b, float inv_rows) {
    constexpr int ESTR = 72;
    __shared__ float al[128], be[128];
    __shared__ u16 ets[64 * ESTR];
    const int tid = threadIdx.x;
    if (tid < 128) {
        float mu = stats[tid] * inv_rows;
        float var = stats[128 + tid] * inv_rows - mu * mu;
        float a = g[tid] * rsqrtf(fmaxf(var, 0.f) + EPS);
        al[tid] = a;
        be[tid] = b[tid] - mu * a;
    }
    __syncthreads();
    const int lane = tid & 63, wv = tid >> 6;
    const int q = lane >> 4, rr = lane & 15;
    const long r0 = ((long)blockIdx.x * 4 + wv) * 16;
    s16x8 afr[4];
#pragma unroll
    for (int kk = 0; kk < 4; ++kk) {
        U16x8 t = *(const U16x8*)&X[(r0 + rr) * 128 + kk * 32 + q * 8];
        union { u16 u[8]; s16x8 v; } o;
#pragma unroll
        for (int j = 0; j < 8; ++j) {
            int k = kk * 32 + q * 8 + j;
            o.u[j] = f2b(al[k] * b2f(t.s[j]) + be[k]);
        }
        afr[kk] = o.v;
    }
#pragma unroll
    for (int ct = 0; ct < 4; ++ct) {
        f32x4 acc = (f32x4){0.f, 0.f, 0.f, 0.f};
#pragma unroll
        for (int kk = 0; kk < 4; ++kk) {
            s16x8 bfr = *(const s16x8*)&WT[(size_t)(ct * 16 + rr) * 128 + kk * 32 + q * 8];
            acc = __builtin_amdgcn_mfma_f32_16x16x32_bf16(afr[kk], bfr, acc, 0, 0, 0);
        }
        int col = ct * 16 + rr;
        float bb = bias[col];
#pragma unroll
        for (int r = 0; r < 4; ++r)
            ets[(wv * 16 + q * 4 + r) * ESTR + col] = f2b(acc[r] + bb);
    }
    __syncthreads();
    const long rb = (long)blockIdx.x * 64;
#pragma unroll
    for (int g2 = 0; g2 < 2; ++g2) {
        int i = g2 * 256 + tid;
        int row = i >> 3, c8 = i & 7;
        U16x8 st = *(const U16x8*)&ets[row * ESTR + c8 * 8];
        U16x8 old = *(const U16x8*)&EHio[(rb + row) * 64 + c8 * 8];
        U16x8 o;
#pragma unroll
        for (int j = 0; j < 8; ++j) o.s[j] = f2b(b2f(st.s[j]) + b2f(old.s[j]));
        *(U16x8*)&EHio[(rb + row) * 64 + c8 * 8] = o;
    }
}

// ---------------- CSR gather aggregate: per-node softmax + weighted sum (+col-stats) ----------------
template <int COLS, bool SOUT>
__global__ __launch_bounds__(256) void csr_aggregate_kernel(
    const int* __restrict__ rowptr, const int* __restrict__ esrc,
    const float* __restrict__ eatt, const u16* __restrict__ nodeh, u16* __restrict__ hout,
    int n, float* __restrict__ raw) {
    constexpr int H = COLS / 64;
    constexpr int TPN = COLS / 2;
    constexpr int NPB = 256 / TPN;
    __shared__ float ssum[SOUT ? COLS : 1];
    __shared__ float ssq[SOUT ? COLS : 1];
    int tid = threadIdx.x;
    if (SOUT) {
        for (int i = tid; i < COLS; i += 256) { ssum[i] = 0.f; ssq[i] = 0.f; }
        __syncthreads();
    }
    int node = blockIdx.x * NPB + tid / TPN;
    bool act = node < n;
    int c = (tid % TPN) * 2;
    float a0 = 0.f, a1 = 0.f;
    if (act) {
        int h = (H == 2) ? (c >> 6) : 0;
        int p0 = rowptr[node], p1 = rowptr[node + 1];
        float m = -INFINITY, s = 0.f;
        for (int p = p0; p < p1; ++p) {
            float v = eatt[(long)p * H + h];
            float mn = fmaxf(m, v);
            s = s * expf(m - mn) + expf(v - mn);
            m = mn;
        }
        float inv = (s > 0.f) ? 1.f / s : 0.f;
        for (int p = p0; p < p1; ++p) {
            float w = expf(eatt[(long)p * H + h] - m) * inv;
            U16x2 v = *(const U16x2*)&nodeh[(long)esrc[p] * COLS + c];
            a0 += b2f(v.s[0]) * w;
            a1 += b2f(v.s[1]) * w;
        }
        U16x2 o;
        o.s[0] = f2b(a0);
        o.s[1] = f2b(a1);
        *(U16x2*)&hout[(long)node * COLS + c] = o;
    }
    if (SOUT) {
        if (act) {
            atomicAdd(&ssum[c], a0);
            atomicAdd(&ssum[c + 1], a1);
            atomicAdd(&ssq[c], a0 * a0);
            atomicAdd(&ssq[c + 1], a1 * a1);
        }
        __syncthreads();
        float* slot = raw + (size_t)(blockIdx.x & (NSLOT - 1)) * 256;
        for (int i = tid; i < COLS; i += 256) {
            atomicAdd(&slot[i], ssum[i]);
            atomicAdd(&slot[COLS + i], ssq[i]);
        }
    }
}

// ---------------- decoder tail: prelu(bn(t3)) @ Wout + bout -> pool by graph ----------------
__global__ __launch_bounds__(256) void decoder_out_kernel(
    const u16* __restrict__ t3, const float* __restrict__ stats, const float* __restrict__ g,
    const float* __restrict__ b, const float* __restrict__ prelu, const float* __restrict__ Wout,
    const float* __restrict__ bout, const int* __restrict__ gid, float* __restrict__ pool,
    int rows, float inv_rows) {
    int tid = threadIdx.x;
    long r = (long)blockIdx.x * 4 + (tid >> 6);
    if (r >= rows) return;
    int k = tid & 63;
    float mu = stats[k] * inv_rows;
    float var = stats[64 + k] * inv_rows - mu * mu;
    float al = g[k] * rsqrtf(fmaxf(var, 0.f) + EPS);
    float be = b[k] - mu * al;
    float a = prelu[3];
    float v = al * b2f(t3[r * 64 + k]) + be;
    v = (v >= 0.f) ? v : a * v;
    v *= Wout[k];
#pragma unroll
    for (int off = 1; off < 64; off <<= 1) v += __shfl_xor(v, off, 64);
    if (k == 0) atomicAdd(&pool[gid[r]], v + bout[0]);
}

// =====================================================================================
extern "C" void kernel_launch(void* const* d_in, const int* in_sizes, int n_in, void* d_out,
                              int out_size, void* d_ws, size_t ws_size, hipStream_t stream) {
    if (n_in < 57) return;
    const int* ntype = (const int*)d_in[0];
    const int* src = (const int*)d_in[1];
    const int* dst = (const int*)d_in[2];
    const int* gid = (const int*)d_in[3];
    const float* ang_rot = (const float*)d_in[4];
    const float* ang_ref = (const float*)d_in[5];
    const float* efeats = (const float*)d_in[6];
    const float* emb = (const float*)d_in[7];
    const float* enc_W = (const float*)d_in[8];
    const float* enc_b = (const float*)d_in[9];
    const float* ee_W1 = (const float*)d_in[10];
    const float* ee_b1 = (const float*)d_in[11];
    const float* ee_W2 = (const float*)d_in[12];
    const float* ee_b2 = (const float*)d_in[13];
    const float* enc_bn1_g = (const float*)d_in[14];
    const float* enc_bn1_b = (const float*)d_in[15];
    const float* enc_bn2_g = (const float*)d_in[16];
    const float* enc_bn2_b = (const float*)d_in[17];
    const float* ee_bn1_g = (const float*)d_in[18];
    const float* ee_bn1_b = (const float*)d_in[19];
    const float* ee_bn2_g = (const float*)d_in[20];
    const float* ee_bn2_b = (const float*)d_in[21];
    const float* l0_Wnode = (const float*)d_in[22];
    const float* l0_bnode = (const float*)d_in[23];
    const float* l0_Wni = (const float*)d_in[24];
    const float* l0_Wnj = (const float*)d_in[25];
    const float* l0_Wfij = (const float*)d_in[26];
    const float* l0_attn = (const float*)d_in[27];
    const float* l0_bnn_g = (const float*)d_in[28];
    const float* l0_bnn_b = (const float*)d_in[29];
    const float* l0_bne_g = (const float*)d_in[30];
    const float* l0_bne_b = (const float*)d_in[31];
    const float* l0_Wpn = (const float*)d_in[32];
    const float* l0_bpn = (const float*)d_in[33];
    const float* l0_Wpe = (const float*)d_in[34];
    const float* l0_bpe = (const float*)d_in[35];
    const float* l1_Wnode = (const float*)d_in[36];
    const float* l1_bnode = (const float*)d_in[37];
    const float* l1_Wni = (const float*)d_in[38];
    const float* l1_Wnj = (const float*)d_in[39];
    const float* l1_Wfij = (const float*)d_in[40];
    const float* l1_attn = (const float*)d_in[41];
    const float* l1_bnn_g = (const float*)d_in[42];
    const float* l1_bnn_b = (const float*)d_in[43];
    const float* l1_Wpn = (const float*)d_in[46];
    const float* l1_bpn = (const float*)d_in[47];
    const float* dec_W = (const float*)d_in[50];
    const float* dec_b = (const float*)d_in[51];
    const float* dec_bn_g = (const float*)d_in[52];
    const float* dec_bn_b = (const float*)d_in[53];
    const float* dec_prelu = (const float*)d_in[54];
    const float* dec_Wout = (const float*)d_in[55];
    const float* dec_bout = (const float*)d_in[56];

    float* out = (float*)d_out;
    float* H1 = out;                     // N x 64 (fp32)
    float* H2 = out + (long)NN * 64;     // N x 64 (fp32)
    float* POOL = out + (long)NN * 128;  // G x 1 (fp32)

    char* base = (char*)d_ws;
    size_t off = 0;
    auto alloc = [&](size_t bytes) -> void* {
        off = (off + 255) & ~(size_t)255;
        void* p = base + off;
        off += bytes;
        return p;
    };
    u16* EH = (u16*)alloc((size_t)NE * 64 * 2);
    u16* F128 = (u16*)alloc((size_t)NE * 128 * 2);  // also node-enc temps
    float* EATT = (float*)alloc((size_t)NE * 2 * 4);
    u16* NX = (u16*)alloc((size_t)NN * 64 * 2);
    u16* NI = (u16*)alloc((size_t)NN * 128 * 2);
    u16* NJ = (u16*)alloc((size_t)NN * 128 * 2);
    u16* NHH = (u16*)alloc((size_t)NN * 128 * 2);
    u16* HOUT0 = (u16*)alloc((size_t)NN * 128 * 2);
    u16* HOUT1 = (u16*)alloc((size_t)NN * 64 * 2);
    int* ROWPTR = (int*)alloc((size_t)(NN + 1) * 4);
    int* CURS = (int*)alloc((size_t)NN * 4);
    int* ESRC = (int*)alloc((size_t)NE * 4);
    int* DSTS = (int*)alloc((size_t)NE * 4);
    float* EFP = (float*)alloc((size_t)NE * 3 * 4);
    int* BSUM = (int*)alloc((size_t)256 * 4);
    float* RWrot = (float*)alloc(256 * 4);
    float* RWref = (float*)alloc(256 * 4);
    u16* EncWT = (u16*)alloc(4096 * 2);
    u16* W2T = (u16*)alloc(4096 * 2);
    u16* Wni0T = (u16*)alloc(8192 * 2);
    u16* Wnj0T = (u16*)alloc(8192 * 2);
    u16* Wnd0T = (u16*)alloc(8192 * 2);
    u16* WfijT0 = (u16*)alloc(8192 * 2);
    u16* Wpn0T = (u16*)alloc(8192 * 2);
    u16* WpeT = (u16*)alloc(8192 * 2);
    u16* Wni1T = (u16*)alloc(4096 * 2);
    u16* Wnj1T = (u16*)alloc(4096 * 2);
    u16* Wnd1T = (u16*)alloc(4096 * 2);
    u16* WfijT1 = (u16*)alloc(4096 * 2);
    u16* Wpn1T = (u16*)alloc(4096 * 2);
    u16* DecT0 = (u16*)alloc(4096 * 2);
    u16* DecT1 = (u16*)alloc(4096 * 2);
    u16* DecT2 = (u16*)alloc(4096 * 2);
    u16* DecT3 = (u16*)alloc(4096 * 2);
    float* STATS = (float*)alloc((size_t)13 * 256 * 4);
    char* zstart = base + ((off + 255) & ~(size_t)255);
    int* DEG = (int*)alloc((size_t)NN * 4);
    float* STATS_RAW = (float*)alloc((size_t)13 * NSLOT * 256 * 4);
    float* RAWEF = (float*)alloc((size_t)NSLOT * 16 * 4);
    char* zend = base + off;
    if (ws_size < off) return;

    u16* NX0 = F128;                    // NN x 64 bf16 (node-enc temp; before layer 0)
    u16* NT = F128 + (size_t)NN * 64;   // NN x 64 bf16 (node-enc temp)
    u16* DT0 = NI;
    u16* DT1 = NJ;

    auto RAW = [&](int idx) { return STATS_RAW + (size_t)idx * NSLOT * 256; };
    float* S_enc1 = STATS + 0 * 256;
    float* S_enc2 = STATS + 1 * 256;
    float* S_ee1r = STATS + 2 * 256;
    float* S_ee2r = STATS + 3 * 256;
    float* S_ee1f = STATS + 4 * 256;
    float* S_ee2f = STATS + 5 * 256;
    float* S_bnn0 = STATS + 6 * 256;
    float* S_bne0 = STATS + 7 * 256;
    float* S_bnn1 = STATS + 8 * 256;
    float* S_d0 = STATS + 9 * 256;
    float* S_d1 = STATS + 10 * 256;
    float* S_d2 = STATS + 11 * 256;
    float* S_d3 = STATS + 12 * 256;

    const float invN = 1.f / (float)NN;
    const float invE = 1.f / (float)NE;
    const int MFB = NE / 64;          // 6250 (exact)
    const int NNB = (NN + 63) / 64;   // 782 (tail waves skip)
    const int NB = (NN + 255) / 256;  // scan blocks

    hipMemsetAsync(zstart, 0, (size_t)(zend - zstart), stream);
    hipMemsetAsync(POOL, 0, (size_t)NG * 4, stream);

    setup_kernel<<<1, 64, 0, stream>>>(ang_rot, ang_ref, ee_W1, RWrot, RWref);
    {
        WtJobs j;
        const float* Ws[NWT] = {enc_W,  ee_W2,  l0_Wni, l0_Wnj, l0_Wnode, l0_Wfij,
                                l0_Wpn, l0_Wpe, l1_Wni, l1_Wnj, l1_Wnode, l1_Wfij,
                                l1_Wpn, dec_W,  dec_W + 4096, dec_W + 8192, dec_W + 12288};
        u16* Ts[NWT] = {EncWT, W2T, Wni0T, Wnj0T, Wnd0T, WfijT0, Wpn0T, WpeT, Wni1T,
                        Wnj1T, Wnd1T, WfijT1, Wpn1T, DecT0, DecT1, DecT2, DecT3};
        int Ks[NWT] = {64, 64, 64, 64, 64, 64, 128, 128, 64, 64, 64, 64, 64, 64, 64, 64, 64};
        int Cs[NWT] = {64, 64, 128, 128, 128, 128, 64, 64, 64, 64, 64, 64, 64, 64, 64, 64, 64};
        for (int i = 0; i < NWT; ++i) { j.W[i] = Ws[i]; j.WT[i] = Ts[i]; j.K[i] = Ks[i]; j.C[i] = Cs[i]; }
        wt_all_kernel<<<NWT * 32, 256, 0, stream>>>(j);
    }

    // ---- CSR build (+ edge permutation into CSR order) ----
    hist_kernel<<<(NE + 255) / 256, 256, 0, stream>>>(dst, NE, DEG);
    scan_part_kernel<<<NB, 256, 0, stream>>>(DEG, BSUM, NN);
    scan_top_kernel<<<1, 256, 0, stream>>>(BSUM, NB, ROWPTR, NN, NE);
    scan_fill_kernel<<<NB, 256, 0, stream>>>(DEG, BSUM, ROWPTR, CURS, NN);
    fill_kernel<<<(NE + 255) / 256, 256, 0, stream>>>(src, dst, efeats, NE, CURS, ESRC, DSTS,
                                                      EFP);

    // ---- node encoder ----
    gather_emb_kernel<<<(NN * 8 + 255) / 256, 256, 0, stream>>>(ntype, emb, NX0, NN, RAW(0));
    finalize_stats_kernel<<<1, 256, 0, stream>>>(RAW(0), S_enc1, 128);
    mfma_mm_kernel<64, 64, true, false, true, true><<<NNB, 256, 0, stream>>>(
        NX0, EncWT, enc_b, nullptr, NT, NN, 2, S_enc1, enc_bn1_g, enc_bn1_b, invN, nullptr, 0,
        RAW(1));
    finalize_stats_kernel<<<1, 256, 0, stream>>>(RAW(1), S_enc2, 128);
    bn_act_kernel<<<(NN * 8 + 255) / 256, 256, 0, stream>>>(NT, NX, NN, 64, S_enc2, enc_bn2_g,
                                                            enc_bn2_b, invN);

    // ---- edge encoder (CSR order): analytic T1 stats, recompute-stats, recompute-merge ----
    efstats_kernel<<<256, 256, 0, stream>>>(efeats, NE, RAWEF);
    ee_stats_kernel<<<1, 128, 0, stream>>>(RAWEF, RWrot, RWref, ee_b1, S_ee1r, S_ee1f, NE);
    mfma_ee2_kernel<false><<<MFB, 256, 0, stream>>>(
        EFP, RWrot, RWref, ee_b1, W2T, ee_b2, S_ee1r, S_ee1f, nullptr, nullptr, ee_bn1_g,
        ee_bn1_b, nullptr, nullptr, nullptr, NE, invE, RAW(3), RAW(5));
    finalize_stats_kernel<<<1, 256, 0, stream>>>(RAW(3), S_ee2r, 128);
    finalize_stats_kernel<<<1, 256, 0, stream>>>(RAW(5), S_ee2f, 128);
    mfma_ee2_kernel<true><<<MFB, 256, 0, stream>>>(
        EFP, RWrot, RWref, ee_b1, W2T, ee_b2, S_ee1r, S_ee1f, S_ee2r, S_ee2f, ee_bn1_g, ee_bn1_b,
        ee_bn2_g, ee_bn2_b, EH, NE, invE, nullptr, nullptr);

    // ---- layer 0 (H=2) ----
    mfma_mm3_kernel<128, true><<<NNB, 256, 0, stream>>>(NX, Wni0T, Wnj0T, Wnd0T, l0_bnode, NI,
                                                        NJ, NHH, NN);
    mfma_egat_kernel<128, true, true><<<MFB, 256, 0, stream>>>(
        EH, WfijT0, NI, NJ, ESRC, DSTS, l0_attn, F128, EATT, NE, RAW(7));
    finalize_stats_kernel<<<1, 256, 0, stream>>>(RAW(7), S_bne0, 256);
    csr_aggregate_kernel<128, true><<<(NN + 3) / 4, 256, 0, stream>>>(ROWPTR, ESRC, EATT, NHH,
                                                                      HOUT0, NN, RAW(6));
    finalize_stats_kernel<<<1, 256, 0, stream>>>(RAW(6), S_bnn0, 256);
    mfma_mm_kernel<128, 64, true, true, false, false><<<NNB, 256, 0, stream>>>(
        HOUT0, Wpn0T, l0_bpn, NX, H1, NN, 1, S_bnn0, l0_bnn_g, l0_bnn_b, invN, nullptr, 0,
        nullptr);
    mfma_pe_kernel<<<MFB, 256, 0, stream>>>(F128, WpeT, l0_bpe, EH, NE, S_bne0, l0_bne_g,
                                            l0_bne_b, invE);

    // ---- layer 1 (H=1; edge output dead -> skipped) ----
    mfma_mm3_kernel<64, false><<<NNB, 256, 0, stream>>>(H1, Wni1T, Wnj1T, Wnd1T, l1_bnode, NI,
                                                        NJ, NHH, NN);
    mfma_egat_kernel<64, false, false><<<MFB, 256, 0, stream>>>(
        EH, WfijT1, NI, NJ, ESRC, DSTS, l1_attn, nullptr, EATT, NE, nullptr);
    csr_aggregate_kernel<64, true><<<(NN + 7) / 8, 256, 0, stream>>>(ROWPTR, ESRC, EATT, NHH,
                                                                     HOUT1, NN, RAW(8));
    finalize_stats_kernel<<<1, 256, 0, stream>>>(RAW(8), S_bnn1, 128);
    mfma_mm_kernel<64, 64, true, false, false, false><<<NNB, 256, 0, stream>>>(
        HOUT1, Wpn1T, l1_bpn, H1, H2, NN, 1, S_bnn1, l1_bnn_g, l1_bnn_b, invN, nullptr, 0,
        nullptr);

    // ---- decoder ----
    mfma_mm_kernel<64, 64, false, false, true, true><<<NNB, 256, 0, stream>>>(
        H2, DecT0, dec_b, nullptr, DT0, NN, 0, nullptr, nullptr, nullptr, 0.f, nullptr, 0,
        RAW(9));
    finalize_stats_kernel<<<1, 256, 0, stream>>>(RAW(9), S_d0, 128);
    mfma_mm_kernel<64, 64, true, false, true, true><<<NNB, 256, 0, stream>>>(
        DT0, DecT1, dec_b + 64, nullptr, DT1, NN, 3, S_d0, dec_bn_g, dec_bn_b, invN, dec_prelu,
        0, RAW(10));
    finalize_stats_kernel<<<1, 256, 0, stream>>>(RAW(10), S_d1, 128);
    mfma_mm_kernel<64, 64, true, false, true, true><<<NNB, 256, 0, stream>>>(
        DT1, DecT2, dec_b + 128, nullptr, DT0, NN, 3, S_d1, dec_bn_g + 64, dec_bn_b + 64, invN,
        dec_prelu, 1, RAW(11));
    finalize_stats_kernel<<<1, 256, 0, stream>>>(RAW(11), S_d2, 128);
    mfma_mm_kernel<64, 64, true, false, true, true><<<NNB, 256, 0, stream>>>(
        DT0, DecT3, dec_b + 192, nullptr, DT1, NN, 3, S_d2, dec_bn_g + 128, dec_bn_b + 128,
        invN, dec_prelu, 2, RAW(12));
    finalize_stats_kernel<<<1, 256, 0, stream>>>(RAW(12), S_d3, 128);
    decoder_out_kernel<<<(NN + 3) / 4, 256, 0, stream>>>(DT1, S_d3, dec_bn_g + 192,
                                                         dec_bn_b + 192, dec_prelu, dec_Wout,
                                                         dec_bout, gid, POOL, NN, invN);
}

// Round 14
// 807.067 us; speedup vs baseline: 1.2213x; 1.0035x over previous
//
#include <hip/hip_runtime.h>
#include <math.h>

#define NN 50000
#define NE 400000
#define NG 512
#define EPS 1e-5f
#define NSLOT 64  // stats replica slots (atomic contention spreading)

typedef unsigned int u32;
typedef unsigned short u16;

typedef __attribute__((ext_vector_type(8))) short s16x8;  // 8 bf16 (4 VGPRs)
typedef __attribute__((ext_vector_type(4))) float f32x4;

__device__ __forceinline__ float b2f(u16 h) { return __uint_as_float(((u32)h) << 16); }
__device__ __forceinline__ u16 f2b(float f) {
    u32 x = __float_as_uint(f);
    u32 r = x + 0x7fffu + ((x >> 16) & 1u);
    return (u16)(r >> 16);
}
struct alignas(16) U16x8 { u16 s[8]; };
struct alignas(8) U16x4 { u16 s[4]; };
struct alignas(4) U16x2 { u16 s[2]; };

__device__ __forceinline__ void f4add(float4& a, const float4 b) {
    a.x += b.x; a.y += b.y; a.z += b.z; a.w += b.w;
}

// bijective XCD swizzle (guide T1, m204)
__device__ __forceinline__ int xcd_swizzle(int orig, int nwg) {
    int xcd = orig & 7;
    int q = nwg >> 3, r = nwg & 7;
    return (xcd < r ? xcd * (q + 1) : r * (q + 1) + (xcd - r) * q) + (orig >> 3);
}

// ---------------- setup: fold rotation matrices into ee_W1 (fp32) ----------------
__global__ void setup_kernel(const float* __restrict__ ang_rot, const float* __restrict__ ang_ref,
                             const float* __restrict__ W1, float* __restrict__ RWrot,
                             float* __restrict__ RWref) {
    int c = threadIdx.x;  // 64
    for (int which = 0; which < 2; ++which) {
        const float* a = which ? ang_ref : ang_rot;
        float t = a[0], p = a[1], q = a[2];
        float ct = cosf(t), st = sinf(t);
        float cp = cosf(p), sp = sinf(p);
        float cq = cosf(q), sq = sinf(q);
        float Rt[3][3] = {{ct, -st, 0.f}, {st, ct, 0.f}, {0.f, 0.f, 1.f}};
        float Rp[3][3] = {{cp, 0.f, -sp}, {0.f, 1.f, 0.f}, {sp, 0.f, cp}};
        float Rq[3][3] = {{1.f, 0.f, 0.f}, {0.f, cq, -sq}, {0.f, sq, cq}};
        float Rtp[3][3], R[3][3];
        for (int i = 0; i < 3; ++i)
            for (int j = 0; j < 3; ++j) {
                float s = 0.f;
                for (int k = 0; k < 3; ++k) s += Rt[i][k] * Rp[k][j];
                Rtp[i][j] = s;
            }
        for (int i = 0; i < 3; ++i)
            for (int j = 0; j < 3; ++j) {
                float s = 0.f;
                for (int k = 0; k < 3; ++k) s += Rtp[i][k] * Rq[k][j];
                R[i][j] = s;
            }
        float sgn = which ? -1.f : 1.f;  // R_ref = -rotmat(angles_ref)
        float* RW = which ? RWref : RWrot;
        if (c < 64) {
            for (int j = 0; j < 3; ++j) {
                float s = 0.f;
                for (int m = 0; m < 3; ++m) s += sgn * R[j][m] * W1[m * 64 + c];
                RW[j * 64 + c] = s;  // RW = R @ W1  (3 x 64)
            }
        }
    }
}

// ---------------- batched weight transpose: W [K][C] fp32 -> WT [C][K] bf16 ----------------
#define NWT 17
struct WtJobs {
    const float* W[NWT];
    u16* WT[NWT];
    int K[NWT];
    int C[NWT];
};
__global__ __launch_bounds__(256) void wt_all_kernel(WtJobs jobs) {
    int job = blockIdx.x >> 5;
    int idx = ((blockIdx.x & 31) << 8) + threadIdx.x;
    int K = jobs.K[job], C = jobs.C[job];
    if (idx >= K * C) return;
    int k = idx / C, c = idx - k * C;
    jobs.WT[job][c * K + k] = f2b(jobs.W[job][idx]);
}

// ---------------- CSR build: degree hist -> 3-phase scan -> fill ----------------
__global__ __launch_bounds__(256) void hist_kernel(const int* __restrict__ dst, int E,
                                                   int* __restrict__ deg) {
    int e = blockIdx.x * 256 + threadIdx.x;
    if (e < E) atomicAdd(&deg[dst[e]], 1);
}

__global__ __launch_bounds__(256) void scan_part_kernel(const int* __restrict__ deg,
                                                        int* __restrict__ bsum, int n) {
    int i = blockIdx.x * 256 + threadIdx.x;
    int v = (i < n) ? deg[i] : 0;
#pragma unroll
    for (int off = 1; off < 64; off <<= 1) v += __shfl_xor(v, off, 64);
    __shared__ int ws[4];
    if ((threadIdx.x & 63) == 0) ws[threadIdx.x >> 6] = v;
    __syncthreads();
    if (threadIdx.x == 0) bsum[blockIdx.x] = ws[0] + ws[1] + ws[2] + ws[3];
}

__global__ __launch_bounds__(256) void scan_top_kernel(int* __restrict__ bsum, int nb,
                                                       int* __restrict__ rowptr, int n,
                                                       int total) {
    __shared__ int s[256];
    int tid = threadIdx.x;
    s[tid] = (tid < nb) ? bsum[tid] : 0;
    __syncthreads();
    for (int off = 1; off < 256; off <<= 1) {
        int v = (tid >= off) ? s[tid - off] : 0;
        __syncthreads();
        s[tid] += v;
        __syncthreads();
    }
    if (tid < nb) bsum[tid] = (tid == 0) ? 0 : s[tid - 1];
    if (tid == 0) rowptr[n] = total;
}

__global__ __launch_bounds__(256) void scan_fill_kernel(const int* __restrict__ deg,
                                                        const int* __restrict__ bsum,
                                                        int* __restrict__ rowptr,
                                                        int* __restrict__ curs, int n) {
    __shared__ int s[256];
    int tid = threadIdx.x;
    int i = blockIdx.x * 256 + tid;
    int v = (i < n) ? deg[i] : 0;
    s[tid] = v;
    __syncthreads();
    for (int off = 1; off < 256; off <<= 1) {
        int t = (tid >= off) ? s[tid - off] : 0;
        __syncthreads();
        s[tid] += t;
        __syncthreads();
    }
    if (i < n) {
        int excl = s[tid] - v + bsum[blockIdx.x];
        rowptr[i] = excl;
        curs[i] = excl;
    }
}

// fill: scatter edges into CSR slots; emit permuted src/dst/efeats (CSR order everywhere after)
__global__ __launch_bounds__(256) void fill_kernel(const int* __restrict__ src,
                                                   const int* __restrict__ dst,
                                                   const float* __restrict__ ef, int E,
                                                   int* __restrict__ curs,
                                                   int* __restrict__ esrc,
                                                   int* __restrict__ dsts,
                                                   float* __restrict__ efp) {
    int e = blockIdx.x * 256 + threadIdx.x;
    if (e >= E) return;
    int d = dst[e];
    int pos = atomicAdd(&curs[d], 1);
    esrc[pos] = src[e];
    dsts[pos] = d;
    efp[(long)pos * 3 + 0] = ef[(long)e * 3 + 0];
    efp[(long)pos * 3 + 1] = ef[(long)e * 3 + 1];
    efp[(long)pos * 3 + 2] = ef[(long)e * 3 + 2];
}

// ---------------- embedding gather: fp32 table -> bf16 out, fused col-stats ----------------
__global__ __launch_bounds__(256) void gather_emb_kernel(const int* __restrict__ ntype,
                                                         const float* __restrict__ emb,
                                                         u16* __restrict__ out, int n,
                                                         float* __restrict__ raw) {
    __shared__ float ssum[64], ssq[64];
    int tid = threadIdx.x;
    if (tid < 64) { ssum[tid] = 0.f; ssq[tid] = 0.f; }
    __syncthreads();
    long i = (long)blockIdx.x * 256 + tid;  // over n*8
    long e = i >> 3;
    int c0 = (int)(i & 7) * 8;
    float v[8];
    bool act = e < n;
    if (act) {
        int t = ntype[e];
        float4 a = *(const float4*)&emb[(long)t * 64 + c0];
        float4 b = *(const float4*)&emb[(long)t * 64 + c0 + 4];
        v[0] = a.x; v[1] = a.y; v[2] = a.z; v[3] = a.w;
        v[4] = b.x; v[5] = b.y; v[6] = b.z; v[7] = b.w;
        U16x8 o;
#pragma unroll
        for (int j = 0; j < 8; ++j) o.s[j] = f2b(v[j]);
        *(U16x8*)&out[e * 64 + c0] = o;
    } else {
#pragma unroll
        for (int j = 0; j < 8; ++j) v[j] = 0.f;
    }
    float q[8];
#pragma unroll
    for (int j = 0; j < 8; ++j) q[j] = v[j] * v[j];
#pragma unroll
    for (int off = 8; off < 64; off <<= 1)
#pragma unroll
        for (int j = 0; j < 8; ++j) {
            v[j] += __shfl_xor(v[j], off, 64);
            q[j] += __shfl_xor(q[j], off, 64);
        }
    if ((tid & 63) < 8) {
        int c = (tid & 7) * 8;
#pragma unroll
        for (int j = 0; j < 8; ++j) {
            atomicAdd(&ssum[c + j], v[j]);
            atomicAdd(&ssq[c + j], q[j]);
        }
    }
    __syncthreads();
    if (tid < 64) {
        float* slot = raw + (size_t)(blockIdx.x & (NSLOT - 1)) * 256;
        atomicAdd(&slot[tid], ssum[tid]);
        atomicAdd(&slot[64 + tid], ssq[tid]);
    }
}

// ---------------- efeats second moments: 9 scalars -> replica slots ----------------
__global__ __launch_bounds__(256) void efstats_kernel(const float* __restrict__ ef, int E,
                                                      float* __restrict__ raw) {
    int tid = threadIdx.x;
    float a[9];
#pragma unroll
    for (int j = 0; j < 9; ++j) a[j] = 0.f;
    for (long e = (long)blockIdx.x * 256 + tid; e < E; e += (long)gridDim.x * 256) {
        float f0 = ef[e * 3 + 0], f1 = ef[e * 3 + 1], f2 = ef[e * 3 + 2];
        a[0] += f0; a[1] += f1; a[2] += f2;
        a[3] += f0 * f0; a[4] += f1 * f1; a[5] += f2 * f2;
        a[6] += f0 * f1; a[7] += f0 * f2; a[8] += f1 * f2;
    }
#pragma unroll
    for (int off = 1; off < 64; off <<= 1)
#pragma unroll
        for (int j = 0; j < 9; ++j) a[j] += __shfl_xor(a[j], off, 64);
    __shared__ float sred[4][9];
    int wv = tid >> 6, ln = tid & 63;
    if (ln == 0)
#pragma unroll
        for (int j = 0; j < 9; ++j) sred[wv][j] = a[j];
    __syncthreads();
    if (tid < 9) {
        float v = sred[0][tid] + sred[1][tid] + sred[2][tid] + sred[3][tid];
        atomicAdd(&raw[(size_t)(blockIdx.x & (NSLOT - 1)) * 16 + tid], v);
    }
}

// ---------------- analytic T1 column stats for both branches ----------------
__global__ void ee_stats_kernel(const float* __restrict__ efraw, const float* __restrict__ RWrot,
                                const float* __restrict__ RWref, const float* __restrict__ b1,
                                float* __restrict__ S_rot, float* __restrict__ S_ref, int E) {
    __shared__ float m[9];
    int t = threadIdx.x;  // 128
    if (t < 9) {
        float s = 0.f;
        for (int r = 0; r < NSLOT; ++r) s += efraw[r * 16 + t];
        m[t] = s;
    }
    __syncthreads();
    int br = t >> 6, c = t & 63;
    const float* RW = br ? RWref : RWrot;
    float* S = br ? S_ref : S_rot;
    float w0 = RW[c], w1 = RW[64 + c], w2 = RW[128 + c];
    float bb = b1[c];
    float mw = m[0] * w0 + m[1] * w1 + m[2] * w2;
    float sum = mw + (float)E * bb;
    float quad = m[3] * w0 * w0 + m[4] * w1 * w1 + m[5] * w2 * w2 +
                 2.f * (m[6] * w0 * w1 + m[7] * w0 * w2 + m[8] * w1 * w2);
    float ss = quad + 2.f * bb * mw + (float)E * bb * bb;
    S[c] = sum;
    S[64 + c] = ss;
}

// ---------------- reduce NSLOT replica slots -> final stats ----------------
__global__ __launch_bounds__(256) void finalize_stats_kernel(const float* __restrict__ raw,
                                                             float* __restrict__ stats, int n) {
    int i = threadIdx.x;
    if (i >= n) return;
    float s = 0.f;
    for (int r = 0; r < NSLOT; ++r) s += raw[r * 256 + i];
    stats[i] = s;
}

// two independent finalizes in one launch (grid=2)
__global__ __launch_bounds__(256) void finalize_stats2_kernel(const float* __restrict__ rawA,
                                                              float* __restrict__ statsA, int nA,
                                                              const float* __restrict__ rawB,
                                                              float* __restrict__ statsB, int nB) {
    const float* raw = blockIdx.x ? rawB : rawA;
    float* stats = blockIdx.x ? statsB : statsA;
    int n = blockIdx.x ? nB : nA;
    int i = threadIdx.x;
    if (i >= n) return;
    float s = 0.f;
    for (int r = 0; r < NSLOT; ++r) s += raw[r * 256 + i];
    stats[i] = s;
}

// ---------------- y = relu(bn(x)), bf16 (node-enc bn2) ----------------
__global__ __launch_bounds__(256) void bn_act_kernel(const u16* __restrict__ x,
                                                     u16* __restrict__ y, long rows, int cols,
                                                     const float* __restrict__ acc,
                                                     const float* __restrict__ g,
                                                     const float* __restrict__ b,
                                                     float inv_rows) {
    long i = (long)blockIdx.x * 256 + threadIdx.x;
    long total8 = rows * (long)cols / 8;
    if (i >= total8) return;
    long base = i * 8;
    int c0 = (int)(base % cols);
    U16x8 xv = *(const U16x8*)&x[base];
    U16x8 o;
#pragma unroll
    for (int j = 0; j < 8; ++j) {
        int c = c0 + j;
        float mu = acc[c] * inv_rows;
        float var = acc[cols + c] * inv_rows - mu * mu;
        float al = g[c] * rsqrtf(fmaxf(var, 0.f) + EPS);
        float be = b[c] - mu * al;
        o.s[j] = f2b(fmaxf(al * b2f(xv.s[j]) + be, 0.f));
    }
    *(U16x8*)&y[base] = o;
}

// ================= MFMA kernels =================
// Fragment layout (guide §3, m89/m91/m92 verified):
//   A: lane l holds A[row=l&15][k=(l>>4)*8+j]
//   B: lane l holds B[k=(l>>4)*8+j][col=l&15]  (8 contiguous bf16 from W^T row)
//   D: lane l reg r holds D[row=(l>>4)*4+r][col=l&15]
// Block = 4 waves = 64 rows. NE%64==0; NN%16==0 (tail waves skip).

// ---- generic: Y = preop(X) @ W (+bias)(+res), optional fused col-stats ----
// RAWS: stats points at the NSLOT-replica raw array; prologue sums it (same order as finalize).
template <int K, int COLS, bool XBF, bool RBF, bool OBF, bool SOUT, bool RAWS>
__global__ __launch_bounds__(256) void mfma_mm_kernel(
    const void* __restrict__ Xv, const u16* __restrict__ WT, const float* __restrict__ bias,
    const void* __restrict__ resv, void* __restrict__ Yv, int rows, int preop,
    const float* __restrict__ stats, const float* __restrict__ g, const float* __restrict__ b,
    float inv_rows, const float* __restrict__ prelu, int prelu_idx, float* __restrict__ raw) {
    constexpr int NCT = COLS / 16;
    constexpr int NKK = K / 32;
    __shared__ float al[K], be[K];
    __shared__ float ssum[SOUT ? COLS : 1], ssq[SOUT ? COLS : 1];
    const int tid = threadIdx.x;
    if (preop) {
        for (int k = tid; k < K; k += 256) {
            float sm, sq;
            if (RAWS) {
                sm = 0.f; sq = 0.f;
                for (int r = 0; r < NSLOT; ++r) {
                    sm += stats[r * 256 + k];
                    sq += stats[r * 256 + K + k];
                }
            } else {
                sm = stats[k];
                sq = stats[K + k];
            }
            float mu = sm * inv_rows;
            float var = sq * inv_rows - mu * mu;
            float a = g[k] * rsqrtf(fmaxf(var, 0.f) + EPS);
            al[k] = a;
            be[k] = b[k] - mu * a;
        }
    }
    if (SOUT) {
        for (int i = tid; i < COLS; i += 256) { ssum[i] = 0.f; ssq[i] = 0.f; }
    }
    __syncthreads();
    const int lane = tid & 63, wv = tid >> 6;
    const int q = lane >> 4, rr = lane & 15;
    const long r0 = ((long)blockIdx.x * 4 + wv) * 16;
    const bool act = r0 < rows;
    const float pa = (preop == 3) ? prelu[prelu_idx] : 0.f;
    s16x8 afr[NKK];
    if (act) {
#pragma unroll
        for (int kk = 0; kk < NKK; ++kk) {
            float v[8];
            if (XBF) {
                U16x8 t = *(const U16x8*)((const u16*)Xv + (r0 + rr) * K + kk * 32 + q * 8);
#pragma unroll
                for (int j = 0; j < 8; ++j) v[j] = b2f(t.s[j]);
            } else {
                const float* xp = (const float*)Xv + (r0 + rr) * K + kk * 32 + q * 8;
                float4 t0 = *(const float4*)xp;
                float4 t1 = *(const float4*)(xp + 4);
                v[0] = t0.x; v[1] = t0.y; v[2] = t0.z; v[3] = t0.w;
                v[4] = t1.x; v[5] = t1.y; v[6] = t1.z; v[7] = t1.w;
            }
            union { u16 u[8]; s16x8 s; } o;
#pragma unroll
            for (int j = 0; j < 8; ++j) {
                float xx = v[j];
                if (preop) {
                    int k = kk * 32 + q * 8 + j;
                    xx = al[k] * xx + be[k];
                    if (preop == 2) xx = fmaxf(xx, 0.f);
                    else if (preop == 3) xx = (xx >= 0.f) ? xx : pa * xx;
                }
                o.u[j] = f2b(xx);
            }
            afr[kk] = o.s;
        }
#pragma unroll
        for (int ct = 0; ct < NCT; ++ct) {
            f32x4 acc = (f32x4){0.f, 0.f, 0.f, 0.f};
#pragma unroll
            for (int kk = 0; kk < NKK; ++kk) {
                s16x8 bfr = *(const s16x8*)&WT[(size_t)(ct * 16 + rr) * K + kk * 32 + q * 8];
                acc = __builtin_amdgcn_mfma_f32_16x16x32_bf16(afr[kk], bfr, acc, 0, 0, 0);
            }
            int col = ct * 16 + rr;
            float bb = bias ? bias[col] : 0.f;
            float fs = 0.f, fq = 0.f;
#pragma unroll
            for (int r = 0; r < 4; ++r) {
                long orr = r0 + q * 4 + r;
                float vv = acc[r] + bb;
                if (resv) {
                    if (RBF) vv += b2f(((const u16*)resv)[orr * COLS + col]);
                    else vv += ((const float*)resv)[orr * COLS + col];
                }
                if (OBF) ((u16*)Yv)[orr * COLS + col] = f2b(vv);
                else ((float*)Yv)[orr * COLS + col] = vv;
                if (SOUT) { fs += vv; fq += vv * vv; }
            }
            if (SOUT) {
                fs += __shfl_xor(fs, 16, 64); fs += __shfl_xor(fs, 32, 64);
                fq += __shfl_xor(fq, 16, 64); fq += __shfl_xor(fq, 32, 64);
                if (q == 0) {
                    atomicAdd(&ssum[col], fs);
                    atomicAdd(&ssq[col], fq);
                }
            }
        }
    }
    if (SOUT) {
        __syncthreads();
        float* slot = raw + (size_t)(blockIdx.x & (NSLOT - 1)) * 256;
        for (int i = tid; i < COLS; i += 256) {
            atomicAdd(&slot[i], ssum[i]);
            atomicAdd(&slot[COLS + i], ssq[i]);
        }
    }
}

// ---- 3 matmuls sharing the A operand: Y0 = X@W0, Y1 = X@W1, Y2 = X@W2 + bias2 ----
template <int COLS, bool XBF>
__global__ __launch_bounds__(256) void mfma_mm3_kernel(
    const void* __restrict__ Xv, const u16* __restrict__ WT0, const u16* __restrict__ WT1,
    const u16* __restrict__ WT2, const float* __restrict__ bias2, u16* __restrict__ Y0,
    u16* __restrict__ Y1, u16* __restrict__ Y2, int rows) {
    constexpr int NCT = COLS / 16;
    const int tid = threadIdx.x;
    const int lane = tid & 63, wv = tid >> 6;
    const int q = lane >> 4, rr = lane & 15;
    const long r0 = ((long)blockIdx.x * 4 + wv) * 16;
    if (r0 >= rows) return;
    s16x8 afr[2];
#pragma unroll
    for (int kk = 0; kk < 2; ++kk) {
        if (XBF) {
            afr[kk] = *(const s16x8*)((const u16*)Xv + (r0 + rr) * 64 + kk * 32 + q * 8);
        } else {
            const float* xp = (const float*)Xv + (r0 + rr) * 64 + kk * 32 + q * 8;
            float4 t0 = *(const float4*)xp;
            float4 t1 = *(const float4*)(xp + 4);
            union { u16 u[8]; s16x8 s; } o;
            o.u[0] = f2b(t0.x); o.u[1] = f2b(t0.y); o.u[2] = f2b(t0.z); o.u[3] = f2b(t0.w);
            o.u[4] = f2b(t1.x); o.u[5] = f2b(t1.y); o.u[6] = f2b(t1.z); o.u[7] = f2b(t1.w);
            afr[kk] = o.s;
        }
    }
    const u16* wts[3] = {WT0, WT1, WT2};
    u16* ys[3] = {Y0, Y1, Y2};
#pragma unroll
    for (int m = 0; m < 3; ++m) {
#pragma unroll
        for (int ct = 0; ct < NCT; ++ct) {
            f32x4 acc = (f32x4){0.f, 0.f, 0.f, 0.f};
#pragma unroll
            for (int kk = 0; kk < 2; ++kk) {
                s16x8 bfr = *(const s16x8*)&wts[m][(size_t)(ct * 16 + rr) * 64 + kk * 32 + q * 8];
                acc = __builtin_amdgcn_mfma_f32_16x16x32_bf16(afr[kk], bfr, acc, 0, 0, 0);
            }
            int col = ct * 16 + rr;
            float bb = (m == 2) ? bias2[col] : 0.f;
#pragma unroll
            for (int r = 0; r < 4; ++r) {
                long orr = r0 + q * 4 + r;
                ys[m][orr * COLS + col] = f2b(acc[r] + bb);
            }
        }
    }
}

// ---- edge encoder, both branches, in-register from 3 floats/row ----
// STORE=false: emit T2 col-stats only (rawA/rawB). STORE=true: EH = relu(bn2a(T2a)) + relu(bn2b(T2b)).
template <bool STORE>
__global__ __launch_bounds__(256) void mfma_ee2_kernel(
    const float* __restrict__ efp, const float* __restrict__ RWrot,
    const float* __restrict__ RWref, const float* __restrict__ b1v, const u16* __restrict__ W2T,
    const float* __restrict__ b2, const float* __restrict__ S1r, const float* __restrict__ S1f,
    const float* __restrict__ S2r, const float* __restrict__ S2f, const float* __restrict__ g1,
    const float* __restrict__ bn1b, const float* __restrict__ g2, const float* __restrict__ bn2b,
    u16* __restrict__ EH, int E, float inv_rows, float* __restrict__ rawA,
    float* __restrict__ rawB) {
    constexpr int ESTR = 72;  // padded u16 stride for EH staging
    __shared__ float rws[2][192];
    __shared__ float al1[2][64], be1[2][64];
    __shared__ float al2[2][64], be2[2][64];
    __shared__ float ssum[2][64], ssq[2][64];
    __shared__ u16 ets[STORE ? 64 * ESTR : 1];
    const int tid = threadIdx.x;
    if (tid < 192) {
        rws[0][tid] = RWrot[tid];
        rws[1][tid] = RWref[tid];
    }
    if (tid < 128) {
        int br = tid >> 6, k = tid & 63;
        const float* S1 = br ? S1f : S1r;
        float mu = S1[k] * inv_rows;
        float var = S1[64 + k] * inv_rows - mu * mu;
        float a = g1[k] * rsqrtf(fmaxf(var, 0.f) + EPS);
        al1[br][k] = a;
        be1[br][k] = bn1b[k] - mu * a + a * b1v[k];  // fold b1
        if (STORE) {
            const float* S2 = br ? S2f : S2r;
            mu = S2[k] * inv_rows;
            var = S2[64 + k] * inv_rows - mu * mu;
            a = g2[k] * rsqrtf(fmaxf(var, 0.f) + EPS);
            al2[br][k] = a;
            be2[br][k] = bn2b[k] - mu * a + a * b2[k];  // fold b2
        } else {
            ssum[br][k] = 0.f;
            ssq[br][k] = 0.f;
        }
    }
    __syncthreads();
    const int lane = tid & 63, wv = tid >> 6;
    const int q = lane >> 4, rr = lane & 15;
    const long r0 = ((long)blockIdx.x * 4 + wv) * 16;
    const long ar = r0 + rr;
    float e0 = efp[ar * 3], e1 = efp[ar * 3 + 1], e2 = efp[ar * 3 + 2];
    float v0[4][4];  // branch-0 post-bn2 values (STORE path)
#pragma unroll
    for (int br = 0; br < 2; ++br) {
        s16x8 afr[2];
#pragma unroll
        for (int kk = 0; kk < 2; ++kk) {
            union { u16 u[8]; s16x8 v; } t;
#pragma unroll
            for (int j = 0; j < 8; ++j) {
                int k = kk * 32 + q * 8 + j;
                float tv = e0 * rws[br][k] + e1 * rws[br][64 + k] + e2 * rws[br][128 + k];
                t.u[j] = f2b(fmaxf(al1[br][k] * tv + be1[br][k], 0.f));
            }
            afr[kk] = t.v;
        }
#pragma unroll
        for (int ct = 0; ct < 4; ++ct) {
            f32x4 acc = (f32x4){0.f, 0.f, 0.f, 0.f};
#pragma unroll
            for (int kk = 0; kk < 2; ++kk) {
                s16x8 bfr = *(const s16x8*)&W2T[(size_t)(ct * 16 + rr) * 64 + kk * 32 + q * 8];
                acc = __builtin_amdgcn_mfma_f32_16x16x32_bf16(afr[kk], bfr, acc, 0, 0, 0);
            }
            int col = ct * 16 + rr;
            if (STORE) {
#pragma unroll
                for (int r = 0; r < 4; ++r) {
                    float v = fmaxf(al2[br][col] * acc[r] + be2[br][col], 0.f);
                    if (br == 0) {
                        v0[ct][r] = v;
                    } else {
                        ets[(wv * 16 + q * 4 + r) * ESTR + col] = f2b(v0[ct][r] + v);
                    }
                }
            } else {
                float bb = b2[col];
                float s = 0.f, qq = 0.f;
#pragma unroll
                for (int r = 0; r < 4; ++r) {
                    float v = acc[r] + bb;
                    s += v;
                    qq += v * v;
                }
                s += __shfl_xor(s, 16, 64); s += __shfl_xor(s, 32, 64);
                qq += __shfl_xor(qq, 16, 64); qq += __shfl_xor(qq, 32, 64);
                if (q == 0) {
                    atomicAdd(&ssum[br][col], s);
                    atomicAdd(&ssq[br][col], qq);
                }
            }
        }
    }
    __syncthreads();
    if (STORE) {
        const long rb = (long)blockIdx.x * 64;
        for (int i = tid; i < 64 * 8; i += 256) {
            int row = i >> 3, c8 = i & 7;
            U16x8 v = *(const U16x8*)&ets[row * ESTR + c8 * 8];
            *(U16x8*)&EH[(rb + row) * 64 + c8 * 8] = v;
        }
    } else {
        if (tid < 128) {
            int br = tid >> 6, k = tid & 63;
            float* slot = (br ? rawB : rawA) + (size_t)(blockIdx.x & (NSLOT - 1)) * 256;
            atomicAdd(&slot[k], ssum[br][k]);
            atomicAdd(&slot[64 + k], ssq[br][k]);
        }
    }
}

// ---- f = leaky(EH@Wfij + NI[src] + NJ[dst]); att scores (CSR order); opt F store + col-stats ----
template <int COLS, bool WRITE_F, bool SOUT>
__global__ __launch_bounds__(256) void mfma_egat_kernel(
    const u16* __restrict__ EH, const u16* __restrict__ WT, const u16* __restrict__ NI,
    const u16* __restrict__ NJ, const int* __restrict__ srcs, const int* __restrict__ dsts,
    const float* __restrict__ attn, u16* __restrict__ Fout, float* __restrict__ eatt, int E,
    float* __restrict__ raw) {
    constexpr int H = COLS / 64;
    constexpr int NCT = COLS / 16;
    constexpr int FSTR = COLS + 8;  // padded LDS row stride
    __shared__ float ssum[SOUT ? COLS : 1];
    __shared__ float ssq[SOUT ? COLS : 1];
    __shared__ u16 fts[WRITE_F ? 64 * FSTR : 1];
    const int tid = threadIdx.x;
    if (SOUT) {
        for (int i = tid; i < COLS; i += 256) { ssum[i] = 0.f; ssq[i] = 0.f; }
        __syncthreads();
    }
    const int bid = xcd_swizzle(blockIdx.x, gridDim.x);
    const int lane = tid & 63, wv = tid >> 6;
    const int q = lane >> 4, rr = lane & 15;
    const long r0 = ((long)bid * 4 + wv) * 16;
    s16x8 afr[2];
#pragma unroll
    for (int kk = 0; kk < 2; ++kk)
        afr[kk] = *(const s16x8*)&EH[(r0 + rr) * 64 + kk * 32 + q * 8];
    int sidx[4], didx[4];
#pragma unroll
    for (int r = 0; r < 4; ++r) {
        long orr = r0 + q * 4 + r;
        sidx[r] = srcs[orr];
        didx[r] = dsts[orr];
    }
    f32x4 acc[NCT];
#pragma unroll
    for (int ct = 0; ct < NCT; ++ct) {
        acc[ct] = (f32x4){0.f, 0.f, 0.f, 0.f};
#pragma unroll
        for (int kk = 0; kk < 2; ++kk) {
            s16x8 bfr = *(const s16x8*)&WT[(size_t)(ct * 16 + rr) * 64 + kk * 32 + q * 8];
            acc[ct] = __builtin_amdgcn_mfma_f32_16x16x32_bf16(afr[kk], bfr, acc[ct], 0, 0, 0);
        }
    }
    float part[H][4];
#pragma unroll
    for (int h = 0; h < H; ++h)
#pragma unroll
        for (int r = 0; r < 4; ++r) part[h][r] = 0.f;
#pragma unroll
    for (int ct = 0; ct < NCT; ++ct) {
        int col = ct * 16 + rr;
        float av = attn[col];
        const int h = (H == 2) ? (ct >> 2) : 0;
        float fs = 0.f, fq = 0.f;
#pragma unroll
        for (int r = 0; r < 4; ++r) {
            float f = acc[ct][r] + b2f(NI[(size_t)sidx[r] * COLS + col]) +
                      b2f(NJ[(size_t)didx[r] * COLS + col]);
            f = (f >= 0.f) ? f : 0.01f * f;
            if (WRITE_F) fts[(wv * 16 + q * 4 + r) * FSTR + col] = f2b(f);
            part[h][r] += f * av;
            if (SOUT) { fs += f; fq += f * f; }
        }
        if (SOUT) {
            fs += __shfl_xor(fs, 16, 64); fs += __shfl_xor(fs, 32, 64);
            fq += __shfl_xor(fq, 16, 64); fq += __shfl_xor(fq, 32, 64);
            if (q == 0) {
                atomicAdd(&ssum[col], fs);
                atomicAdd(&ssq[col], fq);
            }
        }
    }
#pragma unroll
    for (int h = 0; h < H; ++h)
#pragma unroll
        for (int r = 0; r < 4; ++r) {
            float p = part[h][r];
            p += __shfl_xor(p, 1, 64);
            p += __shfl_xor(p, 2, 64);
            p += __shfl_xor(p, 4, 64);
            p += __shfl_xor(p, 8, 64);
            part[h][r] = p;
        }
    if (rr == 0) {
#pragma unroll
        for (int r = 0; r < 4; ++r) {
            long pos = r0 + q * 4 + r;
            if (H == 2) {
                eatt[pos * 2 + 0] = part[0][r];
                eatt[pos * 2 + 1] = part[1][r];
            } else {
                eatt[pos] = part[0][r];
            }
        }
    }
    if (WRITE_F) {
        __syncthreads();
        const long rb = (long)bid * 64;
        constexpr int CH = COLS / 8;
        for (int i = tid; i < 64 * CH; i += 256) {
            int row = i / CH, c8 = i % CH;
            U16x8 v = *(const U16x8*)&fts[row * FSTR + c8 * 8];
            *(U16x8*)&Fout[(rb + row) * COLS + c8 * 8] = v;
        }
    }
    if (SOUT) {
        __syncthreads();
        float* slot = raw + (size_t)(blockIdx.x & (NSLOT - 1)) * 256;
        for (int i = tid; i < COLS; i += 256) {
            atomicAdd(&slot[i], ssum[i]);
            atomicAdd(&slot[COLS + i], ssq[i]);
        }
    }
}

// ---- EH = bn(F128)@Wpe + bpe + EH (K=128, streaming; coalesced residual epilogue) ----
__global__ __launch_bounds__(256) void mfma_pe_kernel(
    const u16* __restrict__ X, const u16* __restrict__ WT, const float* __restrict__ bias,
    u16* __restrict__ EHio, int E, const float* __restrict__ stats, const float* __restrict__ g,
    const float* __restrict__ b, float inv_rows) {
    constexpr int ESTR = 72;
    __shared__ float al[128], be[128];
    __shared__ u16 ets[64 * ESTR];
    const int tid = threadIdx.x;
    if (tid < 128) {
        float mu = stats[tid] * inv_rows;
        float var = stats[128 + tid] * inv_rows - mu * mu;
        float a = g[tid] * rsqrtf(fmaxf(var, 0.f) + EPS);
        al[tid] = a;
        be[tid] = b[tid] - mu * a;
    }
    __syncthreads();
    const int lane = tid & 63, wv = tid >> 6;
    const int q = lane >> 4, rr = lane & 15;
    const long r0 = ((long)blockIdx.x * 4 + wv) * 16;
    s16x8 afr[4];
#pragma unroll
    for (int kk = 0; kk < 4; ++kk) {
        U16x8 t = *(const U16x8*)&X[(r0 + rr) * 128 + kk * 32 + q * 8];
        union { u16 u[8]; s16x8 v; } o;
#pragma unroll
        for (int j = 0; j < 8; ++j) {
            int k = kk * 32 + q * 8 + j;
            o.u[j] = f2b(al[k] * b2f(t.s[j]) + be[k]);
        }
        afr[kk] = o.v;
    }
#pragma unroll
    for (int ct = 0; ct < 4; ++ct) {
        f32x4 acc = (f32x4){0.f, 0.f, 0.f, 0.f};
#pragma unroll
        for (int kk = 0; kk < 4; ++kk) {
            s16x8 bfr = *(const s16x8*)&WT[(size_t)(ct * 16 + rr) * 128 + kk * 32 + q * 8];
            acc = __builtin_amdgcn_mfma_f32_16x16x32_bf16(afr[kk], bfr, acc, 0, 0, 0);
        }
        int col = ct * 16 + rr;
        float bb = bias[col];
#pragma unroll
        for (int r = 0; r < 4; ++r)
            ets[(wv * 16 + q * 4 + r) * ESTR + col] = f2b(acc[r] + bb);
    }
    __syncthreads();
    const long rb = (long)blockIdx.x * 64;
#pragma unroll
    for (int g2 = 0; g2 < 2; ++g2) {
        int i = g2 * 256 + tid;
        int row = i >> 3, c8 = i & 7;
        U16x8 st = *(const U16x8*)&ets[row * ESTR + c8 * 8];
        U16x8 old = *(const U16x8*)&EHio[(rb + row) * 64 + c8 * 8];
        U16x8 o;
#pragma unroll
        for (int j = 0; j < 8; ++j) o.s[j] = f2b(b2f(st.s[j]) + b2f(old.s[j]));
        *(U16x8*)&EHio[(rb + row) * 64 + c8 * 8] = o;
    }
}

// ---------------- CSR gather aggregate: per-node softmax + weighted sum (+col-stats) ----------------
template <int COLS, bool SOUT>
__global__ __launch_bounds__(256) void csr_aggregate_kernel(
    const int* __restrict__ rowptr, const int* __restrict__ esrc,
    const float* __restrict__ eatt, const u16* __restrict__ nodeh, u16* __restrict__ hout,
    int n, float* __restrict__ raw) {
    constexpr int H = COLS / 64;
    constexpr int TPN = COLS / 2;
    constexpr int NPB = 256 / TPN;
    __shared__ float ssum[SOUT ? COLS : 1];
    __shared__ float ssq[SOUT ? COLS : 1];
    int tid = threadIdx.x;
    if (SOUT) {
        for (int i = tid; i < COLS; i += 256) { ssum[i] = 0.f; ssq[i] = 0.f; }
        __syncthreads();
    }
    int node = blockIdx.x * NPB + tid / TPN;
    bool act = node < n;
    int c = (tid % TPN) * 2;
    float a0 = 0.f, a1 = 0.f;
    if (act) {
        int h = (H == 2) ? (c >> 6) : 0;
        int p0 = rowptr[node], p1 = rowptr[node + 1];
        float m = -INFINITY, s = 0.f;
        for (int p = p0; p < p1; ++p) {
            float v = eatt[(long)p * H + h];
            float mn = fmaxf(m, v);
            s = s * expf(m - mn) + expf(v - mn);
            m = mn;
        }
        float inv = (s > 0.f) ? 1.f / s : 0.f;
        for (int p = p0; p < p1; ++p) {
            float w = expf(eatt[(long)p * H + h] - m) * inv;
            U16x2 v = *(const U16x2*)&nodeh[(long)esrc[p] * COLS + c];
            a0 += b2f(v.s[0]) * w;
            a1 += b2f(v.s[1]) * w;
        }
        U16x2 o;
        o.s[0] = f2b(a0);
        o.s[1] = f2b(a1);
        *(U16x2*)&hout[(long)node * COLS + c] = o;
    }
    if (SOUT) {
        if (act) {
            atomicAdd(&ssum[c], a0);
            atomicAdd(&ssum[c + 1], a1);
            atomicAdd(&ssq[c], a0 * a0);
            atomicAdd(&ssq[c + 1], a1 * a1);
        }
        __syncthreads();
        float* slot = raw + (size_t)(blockIdx.x & (NSLOT - 1)) * 256;
        for (int i = tid; i < COLS; i += 256) {
            atomicAdd(&slot[i], ssum[i]);
            atomicAdd(&slot[COLS + i], ssq[i]);
        }
    }
}

// ---------------- decoder tail: prelu(bn(t3)) @ Wout + bout -> pool by graph ----------------
__global__ __launch_bounds__(256) void decoder_out_kernel(
    const u16* __restrict__ t3, const float* __restrict__ stats, const float* __restrict__ g,
    const float* __restrict__ b, const float* __restrict__ prelu, const float* __restrict__ Wout,
    const float* __restrict__ bout, const int* __restrict__ gid, float* __restrict__ pool,
    int rows, float inv_rows) {
    int tid = threadIdx.x;
    long r = (long)blockIdx.x * 4 + (tid >> 6);
    if (r >= rows) return;
    int k = tid & 63;
    float mu = stats[k] * inv_rows;
    float var = stats[64 + k] * inv_rows - mu * mu;
    float al = g[k] * rsqrtf(fmaxf(var, 0.f) + EPS);
    float be = b[k] - mu * al;
    float a = prelu[3];
    float v = al * b2f(t3[r * 64 + k]) + be;
    v = (v >= 0.f) ? v : a * v;
    v *= Wout[k];
#pragma unroll
    for (int off = 1; off < 64; off <<= 1) v += __shfl_xor(v, off, 64);
    if (k == 0) atomicAdd(&pool[gid[r]], v + bout[0]);
}

// =====================================================================================
extern "C" void kernel_launch(void* const* d_in, const int* in_sizes, int n_in, void* d_out,
                              int out_size, void* d_ws, size_t ws_size, hipStream_t stream) {
    if (n_in < 57) return;
    const int* ntype = (const int*)d_in[0];
    const int* src = (const int*)d_in[1];
    const int* dst = (const int*)d_in[2];
    const int* gid = (const int*)d_in[3];
    const float* ang_rot = (const float*)d_in[4];
    const float* ang_ref = (const float*)d_in[5];
    const float* efeats = (const float*)d_in[6];
    const float* emb = (const float*)d_in[7];
    const float* enc_W = (const float*)d_in[8];
    const float* enc_b = (const float*)d_in[9];
    const float* ee_W1 = (const float*)d_in[10];
    const float* ee_b1 = (const float*)d_in[11];
    const float* ee_W2 = (const float*)d_in[12];
    const float* ee_b2 = (const float*)d_in[13];
    const float* enc_bn1_g = (const float*)d_in[14];
    const float* enc_bn1_b = (const float*)d_in[15];
    const float* enc_bn2_g = (const float*)d_in[16];
    const float* enc_bn2_b = (const float*)d_in[17];
    const float* ee_bn1_g = (const float*)d_in[18];
    const float* ee_bn1_b = (const float*)d_in[19];
    const float* ee_bn2_g = (const float*)d_in[20];
    const float* ee_bn2_b = (const float*)d_in[21];
    const float* l0_Wnode = (const float*)d_in[22];
    const float* l0_bnode = (const float*)d_in[23];
    const float* l0_Wni = (const float*)d_in[24];
    const float* l0_Wnj = (const float*)d_in[25];
    const float* l0_Wfij = (const float*)d_in[26];
    const float* l0_attn = (const float*)d_in[27];
    const float* l0_bnn_g = (const float*)d_in[28];
    const float* l0_bnn_b = (const float*)d_in[29];
    const float* l0_bne_g = (const float*)d_in[30];
    const float* l0_bne_b = (const float*)d_in[31];
    const float* l0_Wpn = (const float*)d_in[32];
    const float* l0_bpn = (const float*)d_in[33];
    const float* l0_Wpe = (const float*)d_in[34];
    const float* l0_bpe = (const float*)d_in[35];
    const float* l1_Wnode = (const float*)d_in[36];
    const float* l1_bnode = (const float*)d_in[37];
    const float* l1_Wni = (const float*)d_in[38];
    const float* l1_Wnj = (const float*)d_in[39];
    const float* l1_Wfij = (const float*)d_in[40];
    const float* l1_attn = (const float*)d_in[41];
    const float* l1_bnn_g = (const float*)d_in[42];
    const float* l1_bnn_b = (const float*)d_in[43];
    const float* l1_Wpn = (const float*)d_in[46];
    const float* l1_bpn = (const float*)d_in[47];
    const float* dec_W = (const float*)d_in[50];
    const float* dec_b = (const float*)d_in[51];
    const float* dec_bn_g = (const float*)d_in[52];
    const float* dec_bn_b = (const float*)d_in[53];
    const float* dec_prelu = (const float*)d_in[54];
    const float* dec_Wout = (const float*)d_in[55];
    const float* dec_bout = (const float*)d_in[56];

    float* out = (float*)d_out;
    float* H1 = out;                     // N x 64 (fp32)
    float* H2 = out + (long)NN * 64;     // N x 64 (fp32)
    float* POOL = out + (long)NN * 128;  // G x 1 (fp32)

    char* base = (char*)d_ws;
    size_t off = 0;
    auto alloc = [&](size_t bytes) -> void* {
        off = (off + 255) & ~(size_t)255;
        void* p = base + off;
        off += bytes;
        return p;
    };
    u16* EH = (u16*)alloc((size_t)NE * 64 * 2);
    u16* F128 = (u16*)alloc((size_t)NE * 128 * 2);  // also node-enc temps
    float* EATT = (float*)alloc((size_t)NE * 2 * 4);
    u16* NX = (u16*)alloc((size_t)NN * 64 * 2);
    u16* NI = (u16*)alloc((size_t)NN * 128 * 2);
    u16* NJ = (u16*)alloc((size_t)NN * 128 * 2);
    u16* NHH = (u16*)alloc((size_t)NN * 128 * 2);
    u16* HOUT0 = (u16*)alloc((size_t)NN * 128 * 2);
    u16* HOUT1 = (u16*)alloc((size_t)NN * 64 * 2);
    int* ROWPTR = (int*)alloc((size_t)(NN + 1) * 4);
    int* CURS = (int*)alloc((size_t)NN * 4);
    int* ESRC = (int*)alloc((size_t)NE * 4);
    int* DSTS = (int*)alloc((size_t)NE * 4);
    float* EFP = (float*)alloc((size_t)NE * 3 * 4);
    int* BSUM = (int*)alloc((size_t)256 * 4);
    float* RWrot = (float*)alloc(256 * 4);
    float* RWref = (float*)alloc(256 * 4);
    u16* EncWT = (u16*)alloc(4096 * 2);
    u16* W2T = (u16*)alloc(4096 * 2);
    u16* Wni0T = (u16*)alloc(8192 * 2);
    u16* Wnj0T = (u16*)alloc(8192 * 2);
    u16* Wnd0T = (u16*)alloc(8192 * 2);
    u16* WfijT0 = (u16*)alloc(8192 * 2);
    u16* Wpn0T = (u16*)alloc(8192 * 2);
    u16* WpeT = (u16*)alloc(8192 * 2);
    u16* Wni1T = (u16*)alloc(4096 * 2);
    u16* Wnj1T = (u16*)alloc(4096 * 2);
    u16* Wnd1T = (u16*)alloc(4096 * 2);
    u16* WfijT1 = (u16*)alloc(4096 * 2);
    u16* Wpn1T = (u16*)alloc(4096 * 2);
    u16* DecT0 = (u16*)alloc(4096 * 2);
    u16* DecT1 = (u16*)alloc(4096 * 2);
    u16* DecT2 = (u16*)alloc(4096 * 2);
    u16* DecT3 = (u16*)alloc(4096 * 2);
    float* STATS = (float*)alloc((size_t)13 * 256 * 4);
    char* zstart = base + ((off + 255) & ~(size_t)255);
    int* DEG = (int*)alloc((size_t)NN * 4);
    float* STATS_RAW = (float*)alloc((size_t)13 * NSLOT * 256 * 4);
    float* RAWEF = (float*)alloc((size_t)NSLOT * 16 * 4);
    char* zend = base + off;
    if (ws_size < off) return;

    u16* NX0 = F128;                    // NN x 64 bf16 (node-enc temp; before layer 0)
    u16* NT = F128 + (size_t)NN * 64;   // NN x 64 bf16 (node-enc temp)
    u16* DT0 = NI;
    u16* DT1 = NJ;

    auto RAW = [&](int idx) { return STATS_RAW + (size_t)idx * NSLOT * 256; };
    float* S_enc2 = STATS + 1 * 256;
    float* S_ee1r = STATS + 2 * 256;
    float* S_ee2r = STATS + 3 * 256;
    float* S_ee1f = STATS + 4 * 256;
    float* S_ee2f = STATS + 5 * 256;
    float* S_bne0 = STATS + 7 * 256;
    float* S_d3 = STATS + 12 * 256;

    const float invN = 1.f / (float)NN;
    const float invE = 1.f / (float)NE;
    const int MFB = NE / 64;          // 6250 (exact)
    const int NNB = (NN + 63) / 64;   // 782 (tail waves skip)
    const int NB = (NN + 255) / 256;  // scan blocks

    hipMemsetAsync(zstart, 0, (size_t)(zend - zstart), stream);
    hipMemsetAsync(POOL, 0, (size_t)NG * 4, stream);

    setup_kernel<<<1, 64, 0, stream>>>(ang_rot, ang_ref, ee_W1, RWrot, RWref);
    {
        WtJobs j;
        const float* Ws[NWT] = {enc_W,  ee_W2,  l0_Wni, l0_Wnj, l0_Wnode, l0_Wfij,
                                l0_Wpn, l0_Wpe, l1_Wni, l1_Wnj, l1_Wnode, l1_Wfij,
                                l1_Wpn, dec_W,  dec_W + 4096, dec_W + 8192, dec_W + 12288};
        u16* Ts[NWT] = {EncWT, W2T, Wni0T, Wnj0T, Wnd0T, WfijT0, Wpn0T, WpeT, Wni1T,
                        Wnj1T, Wnd1T, WfijT1, Wpn1T, DecT0, DecT1, DecT2, DecT3};
        int Ks[NWT] = {64, 64, 64, 64, 64, 64, 128, 128, 64, 64, 64, 64, 64, 64, 64, 64, 64};
        int Cs[NWT] = {64, 64, 128, 128, 128, 128, 64, 64, 64, 64, 64, 64, 64, 64, 64, 64, 64};
        for (int i = 0; i < NWT; ++i) { j.W[i] = Ws[i]; j.WT[i] = Ts[i]; j.K[i] = Ks[i]; j.C[i] = Cs[i]; }
        wt_all_kernel<<<NWT * 32, 256, 0, stream>>>(j);
    }

    // ---- CSR build (+ edge permutation into CSR order) ----
    hist_kernel<<<(NE + 255) / 256, 256, 0, stream>>>(dst, NE, DEG);
    scan_part_kernel<<<NB, 256, 0, stream>>>(DEG, BSUM, NN);
    scan_top_kernel<<<1, 256, 0, stream>>>(BSUM, NB, ROWPTR, NN, NE);
    scan_fill_kernel<<<NB, 256, 0, stream>>>(DEG, BSUM, ROWPTR, CURS, NN);
    fill_kernel<<<(NE + 255) / 256, 256, 0, stream>>>(src, dst, efeats, NE, CURS, ESRC, DSTS,
                                                      EFP);

    // ---- node encoder ----
    gather_emb_kernel<<<(NN * 8 + 255) / 256, 256, 0, stream>>>(ntype, emb, NX0, NN, RAW(0));
    mfma_mm_kernel<64, 64, true, false, true, true, true><<<NNB, 256, 0, stream>>>(
        NX0, EncWT, enc_b, nullptr, NT, NN, 2, RAW(0), enc_bn1_g, enc_bn1_b, invN, nullptr, 0,
        RAW(1));
    finalize_stats_kernel<<<1, 256, 0, stream>>>(RAW(1), S_enc2, 128);
    bn_act_kernel<<<(NN * 8 + 255) / 256, 256, 0, stream>>>(NT, NX, NN, 64, S_enc2, enc_bn2_g,
                                                            enc_bn2_b, invN);

    // ---- edge encoder (CSR order): analytic T1 stats, recompute-stats, recompute-merge ----
    efstats_kernel<<<256, 256, 0, stream>>>(efeats, NE, RAWEF);
    ee_stats_kernel<<<1, 128, 0, stream>>>(RAWEF, RWrot, RWref, ee_b1, S_ee1r, S_ee1f, NE);
    mfma_ee2_kernel<false><<<MFB, 256, 0, stream>>>(
        EFP, RWrot, RWref, ee_b1, W2T, ee_b2, S_ee1r, S_ee1f, nullptr, nullptr, ee_bn1_g,
        ee_bn1_b, nullptr, nullptr, nullptr, NE, invE, RAW(3), RAW(5));
    finalize_stats2_kernel<<<2, 256, 0, stream>>>(RAW(3), S_ee2r, 128, RAW(5), S_ee2f, 128);
    mfma_ee2_kernel<true><<<MFB, 256, 0, stream>>>(
        EFP, RWrot, RWref, ee_b1, W2T, ee_b2, S_ee1r, S_ee1f, S_ee2r, S_ee2f, ee_bn1_g, ee_bn1_b,
        ee_bn2_g, ee_bn2_b, EH, NE, invE, nullptr, nullptr);

    // ---- layer 0 (H=2) ----
    mfma_mm3_kernel<128, true><<<NNB, 256, 0, stream>>>(NX, Wni0T, Wnj0T, Wnd0T, l0_bnode, NI,
                                                        NJ, NHH, NN);
    mfma_egat_kernel<128, true, true><<<MFB, 256, 0, stream>>>(
        EH, WfijT0, NI, NJ, ESRC, DSTS, l0_attn, F128, EATT, NE, RAW(7));
    csr_aggregate_kernel<128, true><<<(NN + 3) / 4, 256, 0, stream>>>(ROWPTR, ESRC, EATT, NHH,
                                                                      HOUT0, NN, RAW(6));
    finalize_stats_kernel<<<1, 256, 0, stream>>>(RAW(7), S_bne0, 256);
    mfma_mm_kernel<128, 64, true, true, false, false, true><<<NNB, 256, 0, stream>>>(
        HOUT0, Wpn0T, l0_bpn, NX, H1, NN, 1, RAW(6), l0_bnn_g, l0_bnn_b, invN, nullptr, 0,
        nullptr);
    mfma_pe_kernel<<<MFB, 256, 0, stream>>>(F128, WpeT, l0_bpe, EH, NE, S_bne0, l0_bne_g,
                                            l0_bne_b, invE);

    // ---- layer 1 (H=1; edge output dead -> skipped) ----
    mfma_mm3_kernel<64, false><<<NNB, 256, 0, stream>>>(H1, Wni1T, Wnj1T, Wnd1T, l1_bnode, NI,
                                                        NJ, NHH, NN);
    mfma_egat_kernel<64, false, false><<<MFB, 256, 0, stream>>>(
        EH, WfijT1, NI, NJ, ESRC, DSTS, l1_attn, nullptr, EATT, NE, nullptr);
    csr_aggregate_kernel<64, true><<<(NN + 7) / 8, 256, 0, stream>>>(ROWPTR, ESRC, EATT, NHH,
                                                                     HOUT1, NN, RAW(8));
    mfma_mm_kernel<64, 64, true, false, false, false, true><<<NNB, 256, 0, stream>>>(
        HOUT1, Wpn1T, l1_bpn, H1, H2, NN, 1, RAW(8), l1_bnn_g, l1_bnn_b, invN, nullptr, 0,
        nullptr);

    // ---- decoder ----
    mfma_mm_kernel<64, 64, false, false, true, true, false><<<NNB, 256, 0, stream>>>(
        H2, DecT0, dec_b, nullptr, DT0, NN, 0, nullptr, nullptr, nullptr, 0.f, nullptr, 0,
        RAW(9));
    mfma_mm_kernel<64, 64, true, false, true, true, true><<<NNB, 256, 0, stream>>>(
        DT0, DecT1, dec_b + 64, nullptr, DT1, NN, 3, RAW(9), dec_bn_g, dec_bn_b, invN, dec_prelu,
        0, RAW(10));
    mfma_mm_kernel<64, 64, true, false, true, true, true><<<NNB, 256, 0, stream>>>(
        DT1, DecT2, dec_b + 128, nullptr, DT0, NN, 3, RAW(10), dec_bn_g + 64, dec_bn_b + 64,
        invN, dec_prelu, 1, RAW(11));
    mfma_mm_kernel<64, 64, true, false, true, true, true><<<NNB, 256, 0, stream>>>(
        DT0, DecT3, dec_b + 192, nullptr, DT1, NN, 3, RAW(11), dec_bn_g + 128, dec_bn_b + 128,
        invN, dec_prelu, 2, RAW(12));
    finalize_stats_kernel<<<1, 256, 0, stream>>>(RAW(12), S_d3, 128);
    decoder_out_kernel<<<(NN + 3) / 4, 256, 0, stream>>>(DT1, S_d3, dec_bn_g + 192,
                                                         dec_bn_b + 192, dec_prelu, dec_Wout,
                                                         dec_bout, gid, POOL, NN, invN);
}